// Round 5
// baseline (1394.272 us; speedup 1.0000x reference)
//
#include <hip/hip_runtime.h>

typedef unsigned short u16;
typedef unsigned int   u32;

// ---------- bf16 helpers ----------
__device__ __forceinline__ float b2f(u16 h){ return __uint_as_float(((u32)h)<<16); }
__device__ __forceinline__ u16 f2b(float f){
  u32 u = __float_as_uint(f);
  u32 r = (u + 0x7fffu + ((u>>16)&1u)) >> 16;   // RNE
  return (u16)r;
}
__device__ __forceinline__ float leaky(float x, float s){ return x >= 0.f ? x : s*x; }

typedef __bf16 bf16x8 __attribute__((ext_vector_type(8)));
typedef float  f32x4  __attribute__((ext_vector_type(4)));

__device__ __forceinline__ float ldval(const u16* p){ return b2f(*p); }
__device__ __forceinline__ float ldval(const float* p){ return *p; }

__device__ __forceinline__ void load8(const u16* p, u16* h){ *(uint4*)h = *(const uint4*)p; }
__device__ __forceinline__ void load8(const float* p, u16* h){
  float4 a = *(const float4*)p; float4 b = *(const float4*)(p+4);
  h[0]=f2b(a.x); h[1]=f2b(a.y); h[2]=f2b(a.z); h[3]=f2b(a.w);
  h[4]=f2b(b.x); h[5]=f2b(b.y); h[6]=f2b(b.z); h[7]=f2b(b.w);
}

// ---------- int64-vs-int32 detection ----------
__global__ void k_detect(const u32* __restrict__ w, int E, u32* __restrict__ flag){
  u32 acc = 0;
  for (int i = blockIdx.x*256 + threadIdx.x; i < E; i += 256*gridDim.x)
    acc |= w[2*i + 1];
  __shared__ u32 s[256];
  s[threadIdx.x] = acc; __syncthreads();
  for (int o=128;o>0;o>>=1){ if (threadIdx.x<o) s[threadIdx.x] |= s[threadIdx.x+o]; __syncthreads(); }
  if (threadIdx.x==0 && s[0]) atomicOr(flag, 1u);
}

__device__ __forceinline__ void edge_sd(const int* __restrict__ ei, int E, int e, u32 is32,
                                        int& s, int& d){
  if (is32){ s = ei[e];   d = ei[E + e]; }
  else     { s = ei[2*e]; d = ei[2*E + 2*e]; }
}

// ---------- CSR build ----------
__global__ void k_hist(const int* __restrict__ ei, int E, int nN,
                       const u32* __restrict__ flag, int* __restrict__ cnt){
  int e = blockIdx.x*256 + threadIdx.x;
  if (e < E){
    int s,d; edge_sd(ei, E, e, *flag, s, d);
    if ((u32)s < (u32)nN && (u32)d < (u32)nN) atomicAdd(&cnt[d], 1);
  }
}

__global__ void k_scan_a(const int* __restrict__ cnt, int n, int* __restrict__ bsum){
  __shared__ int s[256];
  int base = blockIdx.x*1024, t = threadIdx.x, sum = 0;
  for (int j=0;j<4;j++){ int i = base + t*4 + j; if (i<n) sum += cnt[i]; }
  s[t] = sum; __syncthreads();
  for (int off=128; off>0; off>>=1){ if (t<off) s[t]+=s[t+off]; __syncthreads(); }
  if (t==0) bsum[blockIdx.x] = s[0];
}

__global__ void k_scan_b(int* bsum, int nb){
  if (threadIdx.x==0 && blockIdx.x==0){
    int acc = 0;
    for (int i=0;i<nb;i++){ int v = bsum[i]; bsum[i] = acc; acc += v; }
  }
}

__global__ void k_scan_c(const int* __restrict__ cnt, const int* __restrict__ bsum,
                         int n, int* __restrict__ offs){
  __shared__ int s[256];
  int base = blockIdx.x*1024, t = threadIdx.x;
  int v[4]; int sum=0;
  for (int j=0;j<4;j++){ int i=base+t*4+j; v[j] = (i<n)?cnt[i]:0; sum += v[j]; }
  s[t]=sum; __syncthreads();
  for (int off=1; off<256; off<<=1){
    int add = (t>=off)? s[t-off] : 0;
    __syncthreads();
    s[t] += add;
    __syncthreads();
  }
  int excl = (t ? s[t-1] : 0) + bsum[blockIdx.x];
  for (int j=0;j<4;j++){
    int i = base+t*4+j;
    if (i<n){ offs[i] = excl; excl += v[j]; if (i==n-1) offs[n] = excl; }
  }
}

__global__ void k_dinv2(const int* __restrict__ offs, int n, float* __restrict__ dinv){
  int i = blockIdx.x*256+threadIdx.x;
  if (i<n) dinv[i] = rsqrtf((float)(offs[i+1]-offs[i]) + 1.0f);
}

__global__ void k_scatter(const int* __restrict__ ei, int E, int nN,
                          const u32* __restrict__ flag, const int* __restrict__ offs,
                          int* __restrict__ cursor, int* __restrict__ csr){
  int e = blockIdx.x*256+threadIdx.x;
  if (e<E){
    int s,d; edge_sd(ei, E, e, *flag, s, d);
    if ((u32)s < (u32)nN && (u32)d < (u32)nN){
      int pos = offs[d] + atomicAdd(&cursor[d], 1);
      csr[pos] = s;
    }
  }
}

// ---------- transpose+convert: f32 (K x M) -> bf16 (M x K) ----------
__global__ void k_transpose(const float* __restrict__ in, u16* __restrict__ out, int K, int M){
  int i = blockIdx.x*256 + threadIdx.x;
  if (i < K*M){ int k = i / M, m = i % M; out[m*K + k] = f2b(in[i]); }
}

// interleave attention vectors: asi[c*4+h] = a_s[h*64+c]
__global__ void k_asdt(const float* __restrict__ a_s, const float* __restrict__ a_d,
                       float* __restrict__ asi, float* __restrict__ adi){
  int i = threadIdx.x;
  int h = i>>6, c = i&63;
  asi[c*4+h] = a_s[i];
  adi[c*4+h] = a_d[i];
}

// ---------- MFMA GEMM, M=64 (col-sliced waves: B read ONCE per block) ----------
template<typename AT>
__global__ __launch_bounds__(256) void k_gemm64(
  const AT* __restrict__ A0, const AT* __restrict__ A1,
  const AT* __restrict__ A2, const AT* __restrict__ A3,
  int rsA, const u16* __restrict__ Bt, const float* __restrict__ bias,
  u16* __restrict__ out, int nRows)
{
  alignas(16) __shared__ u16 Al[64*264];   // A staging, then reused as output tile
  const int t = threadIdx.x;
  const int r0 = blockIdx.x*64;
  for (int it=0; it<8; ++it){
    int c = t + it*256;
    int row = c>>5, seg = c&31;
    int gr = r0+row;
    u16 hv[8] = {0,0,0,0,0,0,0,0};
    if (gr < nRows){
      const AT* p = (seg<8)?A0 : (seg<16)?A1 : (seg<24)?A2 : A3;
      load8(p + (size_t)gr*rsA + (seg&7)*8, hv);
    }
    *(uint4*)&Al[row*264 + seg*8] = *(uint4*)hv;
  }
  const int lane=t&63, wid=t>>6, quad=lane>>4, l15=lane&15;
  __syncthreads();
  const int col = wid*16 + l15;
  const u16* Bp = Bt + (size_t)col*256 + quad*8;
  bf16x8 b[8];
  #pragma unroll
  for (int ks=0;ks<8;++ks) b[ks] = *(const bf16x8*)(Bp + ks*32);
  f32x4 acc[4] = {{0.f,0.f,0.f,0.f},{0.f,0.f,0.f,0.f},{0.f,0.f,0.f,0.f},{0.f,0.f,0.f,0.f}};
  #pragma unroll
  for (int rt=0; rt<4; ++rt){
    const int abase = (rt*16 + l15)*264 + quad*8;
    #pragma unroll
    for (int ks=0;ks<8;++ks){
      bf16x8 av = *(const bf16x8*)&Al[abase + ks*32];
      acc[rt] = __builtin_amdgcn_mfma_f32_16x16x32_bf16(av, b[ks], acc[rt], 0,0,0);
    }
  }
  __syncthreads();
  float bv = bias ? bias[col] : 0.f;
  #pragma unroll
  for (int rt=0; rt<4; ++rt){
    #pragma unroll
    for (int reg=0;reg<4;++reg)
      Al[(rt*16 + quad*4 + reg)*264 + col] = f2b(acc[rt][reg]+bv);
  }
  __syncthreads();
  #pragma unroll
  for (int it=0; it<2; ++it){
    int idx = it*256 + t;
    int row = idx>>3, cu = idx&7;
    if (r0+row < nRows)
      *(uint4*)(out + (size_t)(r0+row)*64 + cu*8) = *(const uint4*)&Al[row*264 + cu*8];
  }
}

// ---------- MFMA GEMM, M=256 (col-sliced waves: B read ONCE per block) ----------
template<typename AT, bool PERM>
__global__ __launch_bounds__(256) void k_gemm256(
  const AT* __restrict__ A0, const AT* __restrict__ A1,
  const AT* __restrict__ A2, const AT* __restrict__ A3,
  int rsA, const u16* __restrict__ Bt, const float* __restrict__ bias,
  u16* __restrict__ out, int nRows)
{
  alignas(16) __shared__ u16 Al[64*264];   // A staging, then reused as output tile
  const int t = threadIdx.x;
  const int r0 = blockIdx.x*64;
  for (int it=0; it<8; ++it){
    int c = t + it*256;
    int row = c>>5, seg = c&31;
    int gr = r0+row;
    u16 hv[8] = {0,0,0,0,0,0,0,0};
    if (gr < nRows){
      const AT* p = (seg<8)?A0 : (seg<16)?A1 : (seg<24)?A2 : A3;
      load8(p + (size_t)gr*rsA + (seg&7)*8, hv);
    }
    *(uint4*)&Al[row*264 + seg*8] = *(uint4*)hv;
  }
  const int lane=t&63, wid=t>>6, quad=lane>>4, l15=lane&15;
  __syncthreads();
  f32x4 acc[4][4];   // [ct][rt]
  #pragma unroll
  for (int ct=0; ct<4; ++ct)
    #pragma unroll
    for (int rt=0; rt<4; ++rt) acc[ct][rt] = {0.f,0.f,0.f,0.f};
  #pragma unroll
  for (int ct=0; ct<4; ++ct){
    const u16* Bp = Bt + (size_t)(wid*64 + ct*16 + l15)*256 + quad*8;
    bf16x8 b[8];
    #pragma unroll
    for (int ks=0;ks<8;++ks) b[ks] = *(const bf16x8*)(Bp + ks*32);
    #pragma unroll
    for (int rt=0; rt<4; ++rt){
      const int abase = (rt*16 + l15)*264 + quad*8;
      #pragma unroll
      for (int ks=0;ks<8;++ks){
        bf16x8 av = *(const bf16x8*)&Al[abase + ks*32];
        acc[ct][rt] = __builtin_amdgcn_mfma_f32_16x16x32_bf16(av, b[ks], acc[ct][rt], 0,0,0);
      }
    }
  }
  __syncthreads();
  #pragma unroll
  for (int ct=0; ct<4; ++ct){
    int col = wid*64 + ct*16 + l15;
    float bv = bias ? bias[col] : 0.f;
    int oc = PERM ? ((col&63)*4 + (col>>6)) : col;
    #pragma unroll
    for (int rt=0; rt<4; ++rt){
      #pragma unroll
      for (int reg=0;reg<4;++reg)
        Al[(rt*16 + quad*4 + reg)*264 + oc] = f2b(acc[ct][rt][reg]+bv);
    }
  }
  __syncthreads();
  #pragma unroll
  for (int it=0; it<8; ++it){
    int idx = it*256 + t;
    int row = idx>>5, cu = idx&31;
    if (r0+row < nRows)
      *(uint4*)(out + (size_t)(r0+row)*256 + cu*8) = *(const uint4*)&Al[row*264 + cu*8];
  }
}

// ---------- GCN gather, 64 channels (fallback path) ----------
__global__ void k_gather64(const u16* __restrict__ h, const int* __restrict__ offs,
                           const int* __restrict__ csr, const float* __restrict__ dinv,
                           const float* __restrict__ bias, int n, u16* __restrict__ out){
  int nd = blockIdx.x*4 + (threadIdx.x>>6);
  if (nd>=n) return;
  int lane = threadIdx.x&63;
  float dn = dinv[nd];
  float acc = dn*b2f(h[(size_t)nd*64+lane]);
  int e = offs[nd], end = offs[nd+1];
  for (; e+4<=end; e+=4){
    int s0=csr[e], s1=csr[e+1], s2=csr[e+2], s3=csr[e+3];
    float w0=dinv[s0], w1=dinv[s1], w2=dinv[s2], w3=dinv[s3];
    float p0=b2f(h[(size_t)s0*64+lane]);
    float p1=b2f(h[(size_t)s1*64+lane]);
    float p2=b2f(h[(size_t)s2*64+lane]);
    float p3=b2f(h[(size_t)s3*64+lane]);
    acc += w0*p0 + w1*p1 + w2*p2 + w3*p3;
  }
  for (; e<end; ++e){
    int s=csr[e];
    acc += dinv[s]*b2f(h[(size_t)s*64+lane]);
  }
  out[(size_t)nd*64+lane] = f2b(dn*acc + bias[lane]);
}

// ---------- GCN gather 256ch, channel-sliced + XCD-pinned ----------
// block bid: cg = bid&7 (channel group of 32 bf16 = one 64B line) -> XCD cg.
// Each XCD only touches a 3.2 MB column slice of h -> L2-resident.
__global__ __launch_bounds__(256) void k_gather256x(const u16* __restrict__ h, const int* __restrict__ offs,
                              const int* __restrict__ csr, const float* __restrict__ dinv,
                              const float* __restrict__ bias, int n, u16* __restrict__ out){
  int bid = blockIdx.x;
  int cg = bid & 7, tile = bid >> 3;
  int nd = tile*4 + (threadIdx.x>>6);
  if (nd>=n) return;
  int lane = threadIdx.x & 63;
  int es = lane >> 4, li = lane & 15;   // 4 edge slots x 16 lanes (64B line)
  const u32* H = (const u32*)h;
  const int coff = cg*16 + li;
  float dn = dinv[nd];
  float a0 = 0.f, a1 = 0.f;
  if (es == 0){
    u32 pv = H[(size_t)nd*128 + coff];
    a0 = dn*b2f(pv&0xffff); a1 = dn*b2f(pv>>16);
  }
  int e = offs[nd] + es, end = offs[nd+1];
  for (; e + 4 < end; e += 8){
    int s0 = __builtin_nontemporal_load(&csr[e]);
    int s1 = __builtin_nontemporal_load(&csr[e+4]);
    float w0 = dinv[s0], w1 = dinv[s1];
    u32 q0 = H[(size_t)s0*128 + coff], q1 = H[(size_t)s1*128 + coff];
    a0 += w0*b2f(q0&0xffff) + w1*b2f(q1&0xffff);
    a1 += w0*b2f(q0>>16)    + w1*b2f(q1>>16);
  }
  if (e < end){
    int s = __builtin_nontemporal_load(&csr[e]);
    float w = dinv[s];
    u32 q = H[(size_t)s*128 + coff];
    a0 += w*b2f(q&0xffff); a1 += w*b2f(q>>16);
  }
  a0 += __shfl_xor(a0,16,64); a0 += __shfl_xor(a0,32,64);
  a1 += __shfl_xor(a1,16,64); a1 += __shfl_xor(a1,32,64);
  if (es == 0){
    int c = cg*32 + li*2;
    u32 o = (u32)f2b(a0*dn + bias[c]) | ((u32)f2b(a1*dn + bias[c+1])<<16);
    ((u32*)out)[(size_t)nd*128 + coff] = o;
  }
}

// ---------- GCN gather, 256 channels (kept for reference / unused big path) ----------
__global__ void k_gather256(const u16* __restrict__ h, const int* __restrict__ offs,
                            const int* __restrict__ csr, const float* __restrict__ dinv,
                            const float* __restrict__ bias, int n, u16* __restrict__ out){
  int nd = blockIdx.x*4 + (threadIdx.x>>6);
  if (nd>=n) return;
  int lane = threadIdx.x&63;
  const uint2* H = (const uint2*)h;
  float dn = dinv[nd];
  uint2 pv = H[(size_t)nd*64 + lane];
  float a0=dn*b2f(pv.x&0xffff), a1=dn*b2f(pv.x>>16);
  float a2=dn*b2f(pv.y&0xffff), a3=dn*b2f(pv.y>>16);
  int e=offs[nd], end=offs[nd+1];
  for (; e+2<=end; e+=2){
    int s0=csr[e], s1=csr[e+1];
    float w0=dinv[s0], w1=dinv[s1];
    uint2 q0=H[(size_t)s0*64+lane], q1=H[(size_t)s1*64+lane];
    a0 += w0*b2f(q0.x&0xffff) + w1*b2f(q1.x&0xffff);
    a1 += w0*b2f(q0.x>>16)    + w1*b2f(q1.x>>16);
    a2 += w0*b2f(q0.y&0xffff) + w1*b2f(q1.y&0xffff);
    a3 += w0*b2f(q0.y>>16)    + w1*b2f(q1.y>>16);
  }
  for (; e<end; ++e){
    int s=csr[e]; float w=dinv[s];
    uint2 q=H[(size_t)s*64+lane];
    a0 += w*b2f(q.x&0xffff); a1 += w*b2f(q.x>>16);
    a2 += w*b2f(q.y&0xffff); a3 += w*b2f(q.y>>16);
  }
  float4 bv = *(const float4*)(bias + lane*4);
  uint2 o;
  o.x = (u32)f2b(a0*dn + bv.x) | ((u32)f2b(a1*dn + bv.y)<<16);
  o.y = (u32)f2b(a2*dn + bv.z) | ((u32)f2b(a3*dn + bv.w)<<16);
  ((uint2*)out)[(size_t)nd*64 + lane] = o;
}

// ---------- BN stats partials, vectorized (16B loads, reg partials, LDS tree) ----------
template<typename T, int C>
__global__ __launch_bounds__(256) void k_stats_part(const T* __restrict__ x, int n,
                                                    float* __restrict__ part){
  constexpr int VE = 16/sizeof(T);   // elems per 16B load: 8 (bf16) / 4 (f32)
  constexpr int G  = C/VE;           // vec-groups per row
  constexpr int R  = 256/G;          // rows covered per block pass
  int t = threadIdx.x;
  int g = t % G, sub = t / G;
  int rpb = (n + gridDim.x - 1) / gridDim.x;
  int base = blockIdx.x * rpb;
  int lim  = min(base + rpb, n);
  float s[VE], s2[VE];
  #pragma unroll
  for (int j=0;j<VE;j++){ s[j]=0.f; s2[j]=0.f; }
  #pragma unroll 4
  for (int r = base + sub; r < lim; r += R){
    const T* p = x + (size_t)r*C + g*VE;
    if constexpr (sizeof(T)==2){
      uint4 v = *(const uint4*)p;
      u32 wq[4] = {v.x, v.y, v.z, v.w};
      #pragma unroll
      for (int q=0;q<4;q++){
        float lo = __uint_as_float(wq[q]<<16);
        float hi = __uint_as_float(wq[q]&0xffff0000u);
        s[2*q]  += lo; s2[2*q]  += lo*lo;
        s[2*q+1]+= hi; s2[2*q+1]+= hi*hi;
      }
    } else {
      float4 v = *(const float4*)p;
      float a[4] = {v.x, v.y, v.z, v.w};
      #pragma unroll
      for (int q=0;q<4;q++){ s[q]+=a[q]; s2[q]+=a[q]*a[q]; }
    }
  }
  __shared__ float red[VE][256];
  #pragma unroll
  for (int j=0;j<VE;j++) red[j][t] = s[j];
  __syncthreads();
  for (int off=R/2; off>0; off>>=1){
    if (sub < off){
      #pragma unroll
      for (int j=0;j<VE;j++) red[j][t] += red[j][t + off*G];
    }
    __syncthreads();
  }
  if (t < G){
    #pragma unroll
    for (int j=0;j<VE;j++) part[blockIdx.x*2*C + t*VE + j] = red[j][t];
  }
  __syncthreads();
  #pragma unroll
  for (int j=0;j<VE;j++) red[j][t] = s2[j];
  __syncthreads();
  for (int off=R/2; off>0; off>>=1){
    if (sub < off){
      #pragma unroll
      for (int j=0;j<VE;j++) red[j][t] += red[j][t + off*G];
    }
    __syncthreads();
  }
  if (t < G){
    #pragma unroll
    for (int j=0;j<VE;j++) part[blockIdx.x*2*C + C + t*VE + j] = red[j][t];
  }
}

// ---------- BN finalize: channel-parallel multi-block (32 ch/block, 8 thr/ch) ----------
template<int C>
__global__ __launch_bounds__(256) void k_bnfin3(const float* __restrict__ part, int B,
                         const float* __restrict__ g, const float* __restrict__ be,
                         float n, float* __restrict__ bnp){
  constexpr int CPB = (C < 32) ? C : 32;   // channels per block
  constexpr int TPC = 256 / CPB;           // threads per channel
  int t = threadIdx.x;
  int lc = t % CPB, sub = t / CPB;
  int c = blockIdx.x*CPB + lc;
  float s=0.f, s2=0.f;
  for (int b = sub; b < B; b += TPC){
    s  += part[(size_t)b*2*C + c];
    s2 += part[(size_t)b*2*C + C + c];
  }
  __shared__ float ls[256], lq[256];
  ls[t]=s; lq[t]=s2; __syncthreads();
  for (int off=TPC/2; off>0; off>>=1){
    if (sub < off){ ls[t]+=ls[t+off*CPB]; lq[t]+=lq[t+off*CPB]; }
    __syncthreads();
  }
  if (sub==0){
    float mu = ls[t]/n;
    float var = fmaxf(lq[t]/n - mu*mu, 0.f);
    float sc = g[c] * rsqrtf(var + 1e-5f);
    bnp[c] = sc;
    bnp[C+c] = be[c] - mu*sc;
  }
}

// ---------- elementwise BN+leaky+residual ----------
__global__ void k_ew_b16b16(const u16* __restrict__ agg, const u16* __restrict__ res,
                            const float* __restrict__ bnp, int C, int total, u16* __restrict__ out){
  int i = blockIdx.x*256+threadIdx.x;
  if (i < total){
    int c = i & (C-1);
    float v = b2f(agg[i])*bnp[c] + bnp[C+c];
    out[i] = f2b(leaky(v, 0.01f) + b2f(res[i]));
  }
}

__global__ void k_ew_f32f32(const float* __restrict__ agg, const float* __restrict__ res,
                            const float* __restrict__ bnp, int C, int total, float* __restrict__ out){
  int i = blockIdx.x*256+threadIdx.x;
  if (i < total){
    int c = i & (C-1);
    float v = agg[i]*bnp[c] + bnp[C+c];
    out[i] = leaky(v, 0.01f) + res[i];
  }
}

// ---------- GAT fallback: per-head logit dot ----------
__global__ void k_dot64(const u16* __restrict__ h2t, const float* __restrict__ asg,
                        const float* __restrict__ adg, int head, int n,
                        float* __restrict__ als, float* __restrict__ ald){
  int nd = blockIdx.x*4 + (threadIdx.x>>6);
  if (nd>=n) return;
  int lane = threadIdx.x&63;
  float p = b2f(h2t[(size_t)nd*64+lane]);
  float ss = p*asg[lane];
  float sd = p*adg[lane];
  for (int m=1;m<64;m<<=1){ ss += __shfl_xor(ss,m,64); sd += __shfl_xor(sd,m,64); }
  if (lane==0){ als[nd*4+head]=ss; ald[nd*4+head]=sd; }
}

// ---------- GAT fallback: per-head softmax gather (online softmax) ----------
__global__ void k_gat_head(const u16* __restrict__ h2t, const int* __restrict__ offs,
                           const int* __restrict__ csr, const float* __restrict__ als,
                           const float* __restrict__ ald, const float* __restrict__ bg,
                           int head, int n, u16* __restrict__ O2){
  int nd = blockIdx.x*4 + (threadIdx.x>>6);
  if (nd>=n) return;
  int lane = threadIdx.x&63;
  float aldn = ald[nd*4+head];
  float m = leaky(als[nd*4+head] + aldn, 0.2f);
  float denom = 1.f;
  float acc = b2f(h2t[(size_t)nd*64+lane]);
  int e = offs[nd], end = offs[nd+1];
  for (; e+4<=end; e+=4){
    int s0=csr[e], s1=csr[e+1], s2=csr[e+2], s3=csr[e+3];
    float l0=als[s0*4+head], l1=als[s1*4+head], l2=als[s2*4+head], l3=als[s3*4+head];
    float p0=b2f(h2t[(size_t)s0*64+lane]);
    float p1=b2f(h2t[(size_t)s1*64+lane]);
    float p2=b2f(h2t[(size_t)s2*64+lane]);
    float p3=b2f(h2t[(size_t)s3*64+lane]);
    float g0=leaky(l0+aldn,0.2f), g1=leaky(l1+aldn,0.2f);
    float g2=leaky(l2+aldn,0.2f), g3=leaky(l3+aldn,0.2f);
    float mc = fmaxf(fmaxf(g0,g1), fmaxf(g2,g3));
    float mn = fmaxf(m, mc);
    float sc = __expf(m - mn);
    float w0 = __expf(g0-mn), w1 = __expf(g1-mn), w2 = __expf(g2-mn), w3 = __expf(g3-mn);
    denom = denom*sc + (w0+w1+w2+w3);
    acc   = acc*sc   + (w0*p0 + w1*p1 + w2*p2 + w3*p3);
    m = mn;
  }
  for (; e<end; ++e){
    int s = csr[e];
    float g = leaky(als[s*4+head]+aldn, 0.2f);
    float p = b2f(h2t[(size_t)s*64+lane]);
    float mn = fmaxf(m, g);
    float sc = __expf(m - mn);
    float w = __expf(g - mn);
    denom = denom*sc + w;
    acc   = acc*sc   + w*p;
    m = mn;
  }
  float v = 0.25f * acc / fmaxf(denom, 1e-20f);
  size_t oi = (size_t)nd*64+lane;
  if (head==0) O2[oi] = f2b(v + bg[lane]);
  else         O2[oi] = f2b(b2f(O2[oi]) + v);
}

// ---------- GAT big path: all-head logit dots (h2 interleaved) ----------
__global__ void k_dot_all(const u16* __restrict__ h2i, const float* __restrict__ asi,
                          const float* __restrict__ adi, int n,
                          float* __restrict__ als, float* __restrict__ ald){
  int nd = blockIdx.x*4 + (threadIdx.x>>6);
  if (nd>=n) return;
  int lane = threadIdx.x&63;
  uint2 pv = ((const uint2*)h2i)[(size_t)nd*64+lane];
  float p0=b2f(pv.x&0xffff), p1=b2f(pv.x>>16), p2=b2f(pv.y&0xffff), p3=b2f(pv.y>>16);
  float4 as4 = *(const float4*)(asi + lane*4);
  float4 ad4 = *(const float4*)(adi + lane*4);
  float s0=p0*as4.x, s1=p1*as4.y, s2=p2*as4.z, s3=p3*as4.w;
  float d0=p0*ad4.x, d1=p1*ad4.y, d2=p2*ad4.z, d3=p3*ad4.w;
  for (int m=1;m<64;m<<=1){
    s0+=__shfl_xor(s0,m,64); s1+=__shfl_xor(s1,m,64);
    s2+=__shfl_xor(s2,m,64); s3+=__shfl_xor(s3,m,64);
    d0+=__shfl_xor(d0,m,64); d1+=__shfl_xor(d1,m,64);
    d2+=__shfl_xor(d2,m,64); d3+=__shfl_xor(d3,m,64);
  }
  if (lane==0){
    float4 sv = {s0,s1,s2,s3}; float4 dv = {d0,d1,d2,d3};
    ((float4*)als)[nd] = sv;
    ((float4*)ald)[nd] = dv;
  }
}

// ---------- GAT gather, channel-sliced + XCD-pinned ----------
// cg = bid&7 covers interleaved idx [cg*32, cg*32+32) = one 64B line per row.
// 4 edge slots x 16 lanes; weights computed once per (edge,head) on li<4 lanes,
// broadcast via shfl. Output channels c = cg*8 .. cg*8+7 (all 4 heads local).
__global__ __launch_bounds__(256) void k_gat_allx(const u16* __restrict__ h2i, const int* __restrict__ offs,
                           const int* __restrict__ csr, const float* __restrict__ als,
                           const float* __restrict__ ald, const float* __restrict__ bg,
                           int n, u16* __restrict__ O2){
  int bid = blockIdx.x;
  int cg = bid & 7, tile = bid >> 3;
  int nd = tile*4 + (threadIdx.x>>6);
  if (nd>=n) return;
  int lane = threadIdx.x & 63;
  int es = lane >> 4, li = lane & 15;
  int hh = lane & 3;
  int h0 = (li & 1) << 1, h1 = h0 + 1;
  float4 alv = ((const float4*)als)[nd];
  float4 adv = ((const float4*)ald)[nd];
  float adh = (hh&2) ? ((hh&1)?adv.w:adv.z) : ((hh&1)?adv.y:adv.x);
  float alh = (hh&2) ? ((hh&1)?alv.w:alv.z) : ((hh&1)?alv.y:alv.x);
  float gsh = leaky(alh+adh, 0.2f);
  int beg = offs[nd], end = offs[nd+1];
  // pass 1: per-head max (lane tracks head hh over edge slot es)
  float m = gsh;
  for (int e = beg+es; e < end; e += 4){
    int s = __builtin_nontemporal_load(&csr[e]);
    m = fmaxf(m, leaky(als[s*4+hh]+adh, 0.2f));
  }
  #pragma unroll
  for (int off=4; off<64; off<<=1) m = fmaxf(m, __shfl_xor(m, off, 64));
  float wsh = __expf(gsh - m);
  // pass 2: weighted gather, exp once per (edge,head)
  const u32* H = (const u32*)h2i;
  const int coff = cg*16 + li;
  float a0 = 0.f, a1 = 0.f, dpart = 0.f;
  int e = beg + es;
  for (; e + 4 < end; e += 8){
    int sA = __builtin_nontemporal_load(&csr[e]);
    int sB = __builtin_nontemporal_load(&csr[e+4]);
    float wEa = 0.f, wEb = 0.f;
    if (li < 4){
      wEa = __expf(leaky(als[sA*4+li]+adh, 0.2f) - m);
      wEb = __expf(leaky(als[sB*4+li]+adh, 0.2f) - m);
    }
    dpart += wEa + wEb;
    float wa0 = __shfl(wEa, es*16 + h0, 64), wa1 = __shfl(wEa, es*16 + h1, 64);
    float wb0 = __shfl(wEb, es*16 + h0, 64), wb1 = __shfl(wEb, es*16 + h1, 64);
    u32 qa = H[(size_t)sA*128 + coff], qb = H[(size_t)sB*128 + coff];
    a0 += wa0*b2f(qa&0xffff) + wb0*b2f(qb&0xffff);
    a1 += wa1*b2f(qa>>16)    + wb1*b2f(qb>>16);
  }
  if (e < end){
    int s = __builtin_nontemporal_load(&csr[e]);
    float wE = 0.f;
    if (li < 4) wE = __expf(leaky(als[s*4+li]+adh, 0.2f) - m);
    dpart += wE;
    float w0 = __shfl(wE, es*16 + h0, 64), w1 = __shfl(wE, es*16 + h1, 64);
    u32 q = H[(size_t)s*128 + coff];
    a0 += w0*b2f(q&0xffff);
    a1 += w1*b2f(q>>16);
  }
  #pragma unroll
  for (int off=4; off<64; off<<=1) dpart += __shfl_xor(dpart, off, 64);
  a0 += __shfl_xor(a0,16,64); a0 += __shfl_xor(a0,32,64);
  a1 += __shfl_xor(a1,16,64); a1 += __shfl_xor(a1,32,64);
  float d = dpart + wsh;                      // per-head denom (head = lane&3)
  float dv0 = __shfl(d, h0, 64),  dv1 = __shfl(d, h1, 64);
  float ws0 = __shfl(wsh, h0, 64), ws1 = __shfl(wsh, h1, 64);
  u32 qs = H[(size_t)nd*128 + coff];          // self row line
  float r = (a0 + ws0*b2f(qs&0xffff))/dv0 + (a1 + ws1*b2f(qs>>16))/dv1;
  r += __shfl_xor(r, 1, 64);                  // combine head pairs -> all 4 heads
  if (es==0 && (li&1)==0){
    int c = cg*8 + (li>>1);
    O2[(size_t)nd*64 + c] = f2b(0.25f*r + bg[c]);
  }
}

// ---------- GAT big path v3 (kept for fallback-size cases; unused in big path) ----------
__global__ void k_gat_all(const u16* __restrict__ h2i, const int* __restrict__ offs,
                          const int* __restrict__ csr, const float* __restrict__ als,
                          const float* __restrict__ ald, const float* __restrict__ bg,
                          int n, u16* __restrict__ O2){
  alignas(16) __shared__ float shm[4][80];
  int wv = threadIdx.x>>6;
  int nd = blockIdx.x*4 + wv;
  if (nd>=n) return;
  int lane = threadIdx.x&63;
  int eg = lane>>2, hh = lane&3;
  float4 alv = ((const float4*)als)[nd];
  float4 adv = ((const float4*)ald)[nd];
  float adh = (hh&2) ? ((hh&1)?adv.w:adv.z) : ((hh&1)?adv.y:adv.x);
  float alh = (hh&2) ? ((hh&1)?alv.w:alv.z) : ((hh&1)?alv.y:alv.x);
  float gsh = leaky(alh+adh, 0.2f);
  int beg=offs[nd], end=offs[nd+1];
  float m = gsh;
  for (int e=beg+eg; e<end; e+=16){
    int s = csr[e];
    m = fmaxf(m, leaky(als[s*4+hh]+adh, 0.2f));
  }
  #pragma unroll
  for (int off=4; off<64; off<<=1) m = fmaxf(m, __shfl_xor(m, off, 64));
  float wsh = __expf(gsh - m);
  if (eg==0) shm[wv][4+hh] = wsh;
  float4 ws4 = *(const float4*)&shm[wv][4];
  uint2 pv = ((const uint2*)h2i)[(size_t)nd*64+lane];
  float a0 = ws4.x*__uint_as_float(pv.x<<16);
  float a1 = ws4.y*__uint_as_float(pv.x&0xffff0000u);
  float a2 = ws4.z*__uint_as_float(pv.y<<16);
  float a3 = ws4.w*__uint_as_float(pv.y&0xffff0000u);
  float dpart = 0.f;
  const uint2* H = (const uint2*)h2i;
  for (int e0=beg; e0<end; e0+=16){
    int e = e0+eg;
    int sA = 0; float wE = 0.f;
    if (e<end){
      sA = csr[e];
      wE = __expf(leaky(als[sA*4+hh]+adh, 0.2f) - m);
    }
    dpart += wE;
    shm[wv][8+lane] = wE;
    int cnt = min(16, end-e0);
    int k=0;
    for (; k+4<=cnt; k+=4){
      int sa=__shfl(sA,(k  )*4,64), sb=__shfl(sA,(k+1)*4,64);
      int sc=__shfl(sA,(k+2)*4,64), sd=__shfl(sA,(k+3)*4,64);
      float4 wa=*(const float4*)&shm[wv][8+(k  )*4];
      float4 wb=*(const float4*)&shm[wv][8+(k+1)*4];
      float4 wc=*(const float4*)&shm[wv][8+(k+2)*4];
      float4 wd=*(const float4*)&shm[wv][8+(k+3)*4];
      uint2 qa=H[(size_t)sa*64+lane], qb=H[(size_t)sb*64+lane];
      uint2 qc=H[(size_t)sc*64+lane], qd=H[(size_t)sd*64+lane];
      a0 += wa.x*__uint_as_float(qa.x<<16) + wb.x*__uint_as_float(qb.x<<16)
          + wc.x*__uint_as_float(qc.x<<16) + wd.x*__uint_as_float(qd.x<<16);
      a1 += wa.y*__uint_as_float(qa.x&0xffff0000u) + wb.y*__uint_as_float(qb.x&0xffff0000u)
          + wc.y*__uint_as_float(qc.x&0xffff0000u) + wd.y*__uint_as_float(qd.x&0xffff0000u);
      a2 += wa.z*__uint_as_float(qa.y<<16) + wb.z*__uint_as_float(qb.y<<16)
          + wc.z*__uint_as_float(qc.y<<16) + wd.z*__uint_as_float(qd.y<<16);
      a3 += wa.w*__uint_as_float(qa.y&0xffff0000u) + wb.w*__uint_as_float(qb.y&0xffff0000u)
          + wc.w*__uint_as_float(qc.y&0xffff0000u) + wd.w*__uint_as_float(qd.y&0xffff0000u);
    }
    for (; k<cnt; ++k){
      int s = __shfl(sA, k*4, 64);
      float4 w4 = *(const float4*)&shm[wv][8+k*4];
      uint2 q = H[(size_t)s*64+lane];
      a0 += w4.x*__uint_as_float(q.x<<16);
      a1 += w4.y*__uint_as_float(q.x&0xffff0000u);
      a2 += w4.z*__uint_as_float(q.y<<16);
      a3 += w4.w*__uint_as_float(q.y&0xffff0000u);
    }
  }
  #pragma unroll
  for (int off=4; off<64; off<<=1) dpart += __shfl_xor(dpart, off, 64);
  float dh = dpart + wsh;
  if (eg==0) shm[wv][hh] = dh;
  float4 d4 = *(const float4*)&shm[wv][0];
  float v = 0.25f*(a0/d4.x + a1/d4.y + a2/d4.z + a3/d4.w);
  O2[(size_t)nd*64+lane] = f2b(v + bg[lane]);
}

// ---------- GCN aggregation, C=16, f32 ----------
__global__ void k_gcn_agg16(const float* __restrict__ h, const int* __restrict__ offs,
                            const int* __restrict__ csr, const float* __restrict__ dinv,
                            const float* __restrict__ bias, float* __restrict__ out, int n){
  int t = threadIdx.x;
  int nd = blockIdx.x*16 + (t>>4);
  if (nd>=n) return;
  int c = t&15;
  float dn = dinv[nd];
  float acc = dn*h[(size_t)nd*16+c];
  int e=offs[nd], end=offs[nd+1];
  for (; e+4<=end; e+=4){
    int s0=csr[e], s1=csr[e+1], s2=csr[e+2], s3=csr[e+3];
    float w0=dinv[s0], w1=dinv[s1], w2=dinv[s2], w3=dinv[s3];
    float p0=h[(size_t)s0*16+c], p1=h[(size_t)s1*16+c];
    float p2=h[(size_t)s2*16+c], p3=h[(size_t)s3*16+c];
    acc += w0*p0 + w1*p1 + w2*p2 + w3*p3;
  }
  for (; e<end; ++e){
    int s = csr[e];
    acc += dinv[s]*h[(size_t)s*16+c];
  }
  out[(size_t)nd*16+c] = dn*acc + bias[c];
}

// ---------- GCN aggregation 64ch f32, channel-sliced (4 groups of 16ch=64B) ----------
__global__ __launch_bounds__(256) void k_gcn_agg64fx(const float* __restrict__ h, const int* __restrict__ offs,
                              const int* __restrict__ csr, const float* __restrict__ dinv,
                              const float* __restrict__ bias, float* __restrict__ out, int n){
  int bid = blockIdx.x;
  int cg = bid & 3, tile = bid >> 2;
  int nd = tile*4 + (threadIdx.x>>6);
  if (nd>=n) return;
  int lane = threadIdx.x&63;
  int es = lane>>4, li = lane&15;
  int ch = cg*16 + li;
  float dn = dinv[nd];
  float a = (es==0) ? dn*h[(size_t)nd*64+ch] : 0.f;
  int e = offs[nd]+es, end = offs[nd+1];
  for (; e+4 < end; e += 8){
    int s0 = __builtin_nontemporal_load(&csr[e]);
    int s1 = __builtin_nontemporal_load(&csr[e+4]);
    a += dinv[s0]*h[(size_t)s0*64+ch] + dinv[s1]*h[(size_t)s1*64+ch];
  }
  if (e < end){
    int s = __builtin_nontemporal_load(&csr[e]);
    a += dinv[s]*h[(size_t)s*64+ch];
  }
  a += __shfl_xor(a,16,64); a += __shfl_xor(a,32,64);
  if (es==0) out[(size_t)nd*64+ch] = dn*a + bias[ch];
}

// ---------- GCN aggregation, C=64, f32 (fallback path) ----------
__global__ void k_gcn_agg64f(const float* __restrict__ h, const int* __restrict__ offs,
                             const int* __restrict__ csr, const float* __restrict__ dinv,
                             const float* __restrict__ bias, float* __restrict__ out, int n){
  int nd = blockIdx.x*4 + (threadIdx.x>>6);
  if (nd>=n) return;
  int lane = threadIdx.x&63;
  float dn = dinv[nd];
  float acc = dn*h[(size_t)nd*64+lane];
  int e=offs[nd], end=offs[nd+1];
  for (; e+4<=end; e+=4){
    int s0=csr[e], s1=csr[e+1], s2=csr[e+2], s3=csr[e+3];
    float w0=dinv[s0], w1=dinv[s1], w2=dinv[s2], w3=dinv[s3];
    float p0=h[(size_t)s0*64+lane], p1=h[(size_t)s1*64+lane];
    float p2=h[(size_t)s2*64+lane], p3=h[(size_t)s3*64+lane];
    acc += w0*p0 + w1*p1 + w2*p2 + w3*p3;
  }
  for (; e<end; ++e){
    int s=csr[e];
    acc += dinv[s]*h[(size_t)s*64+lane];
  }
  out[(size_t)nd*64+lane] = dn*acc + bias[lane];
}

// ---------- small VALU GEMMs ----------
__global__ void k_gemm64_16x2(const u16* __restrict__ x, const float* __restrict__ W1_,
                              const float* __restrict__ W2_, const float* __restrict__ b2_,
                              int n, float* __restrict__ o1, float* __restrict__ o2){
  __shared__ float w1[64*16], w2[64*16];
  int t = threadIdx.x;
  for (int i=t; i<1024; i+=256){ w1[i]=W1_[i]; w2[i]=W2_[i]; }
  __syncthreads();
  int nd = blockIdx.x*8 + (t>>5);
  if (nd>=n) return;
  int j = t & 31;
  const u16* xr = x + (size_t)nd*64;
  if (j<16){
    float s=0.f;
    #pragma unroll 8
    for (int k=0;k<64;k++) s += b2f(xr[k])*w1[k*16+j];
    o1[(size_t)nd*16+j]=s;
  } else {
    int jj=j-16;
    float s = b2_[jj];
    #pragma unroll 8
    for (int k=0;k<64;k++) s += b2f(xr[k])*w2[k*16+jj];
    o2[(size_t)nd*16+jj]=s;
  }
}

__global__ void k_gemm16_64(const float* __restrict__ x, const float* __restrict__ W,
                            int n, float* __restrict__ o){
  __shared__ float w[16*64];
  int t = threadIdx.x;
  for (int i=t;i<1024;i+=256) w[i]=W[i];
  __syncthreads();
  int nd = blockIdx.x*4 + (t>>6);
  if (nd>=n) return;
  int j = t&63;
  const float* xr = x + (size_t)nd*16;
  float s=0.f;
  #pragma unroll
  for (int k=0;k<16;k++) s += xr[k]*w[k*64+j];
  o[(size_t)nd*64+j]=s;
}

// out(N,64) = x(N,64)@pW + pb, f32 out (safe in-place per-wave)
__global__ void k_final(const float* __restrict__ x, const float* __restrict__ W,
                        const float* __restrict__ b, int n, float* __restrict__ out){
  __shared__ float w[64*64];
  int t=threadIdx.x;
  for (int i=t;i<4096;i+=256) w[i]=W[i];
  __syncthreads();
  int nd = blockIdx.x*4 + (t>>6);
  if (nd>=n) return;
  int j=t&63;
  const float* xr = x + (size_t)nd*64;
  float s=b[j];
  #pragma unroll 8
  for (int k=0;k<64;k++) s += xr[k]*w[k*64+j];
  out[(size_t)nd*64+j]=s;
}

// =======================================================================
extern "C" void kernel_launch(void* const* d_in, const int* in_sizes, int n_in,
                              void* d_out, int out_size, void* d_ws, size_t ws_size,
                              hipStream_t stream) {
  const float* x   = (const float*)d_in[0];
  const int*   ei  = (const int*)d_in[1];
  const float* W1  = (const float*)d_in[2];
  const float* b1  = (const float*)d_in[3];
  const float* g1  = (const float*)d_in[4];
  const float* be1 = (const float*)d_in[5];
  const float* Wg  = (const float*)d_in[6];
  const float* a_s = (const float*)d_in[7];
  const float* a_d = (const float*)d_in[8];
  const float* bg  = (const float*)d_in[9];
  const float* g2  = (const float*)d_in[10];
  const float* be2 = (const float*)d_in[11];
  const float* W3  = (const float*)d_in[12];
  const float* b3  = (const float*)d_in[13];
  const float* g3  = (const float*)d_in[14];
  const float* be3 = (const float*)d_in[15];
  const float* W4  = (const float*)d_in[16];
  const float* b4  = (const float*)d_in[17];
  const float* r1W = (const float*)d_in[18];
  const float* r1b = (const float*)d_in[19];
  const float* r2W = (const float*)d_in[20];
  const float* r2b = (const float*)d_in[21];
  const float* r3W = (const float*)d_in[22];
  const float* r3b = (const float*)d_in[23];
  const float* pW  = (const float*)d_in[24];
  const float* pb  = (const float*)d_in[25];

  const int N = in_sizes[0] / 256;
  const int E = in_sizes[1] / 2;

  // ---- common misc carve-out ----
  char* w = (char*)d_ws;
  auto alloc = [&](size_t b)->void*{ void* p=(void*)w; w += (b+255)&~(size_t)255; return p; };
  u32*   flag   = (u32*)  alloc(4);
  float* part   = (float*)alloc(256*512*4);       // stats partials (256 blocks x 2C, C<=256)
  float* bnp1   = (float*)alloc(512*4);
  float* bnp2   = (float*)alloc(128*4);
  float* bnp3   = (float*)alloc(32*4);
  int*   bsum   = (int*)  alloc(256*4);
  int*   cur    = (int*)  alloc((size_t)N*4);
  int*   offs   = (int*)  alloc((size_t)(N+1)*4);
  float* dinv   = (float*)alloc((size_t)N*4);
  int*   csr    = (int*)  alloc((size_t)E*4);
  float* als    = (float*)alloc((size_t)N*16);
  float* ald    = (float*)alloc((size_t)N*16);
  float* asi    = (float*)alloc(256*4);
  float* adi    = (float*)alloc(256*4);
  u16*   W1t    = (u16*)  alloc(65536*2);
  u16*   r1Wt   = (u16*)  alloc(65536*2);
  u16*   Wgt    = (u16*)  alloc(65536*2);
  u16*   r2Wt   = (u16*)  alloc(16384*2);

  auto cdiv = [](int a, int b){ return (a+b-1)/b; };
  const int nb1024 = cdiv(N, 1024);
  const int statsGrid = 256;
  const int gemmGrid = cdiv(N,64);
  const int nodeGrid = cdiv(N,4);

  hipMemsetAsync(flag,   0, 4, stream);
  hipMemsetAsync(cur,    0, (size_t)N*4, stream);

  k_detect<<<64,256,0,stream>>>((const u32*)ei, E, flag);

  k_transpose<<<cdiv(65536,256),256,0,stream>>>(W1,  W1t,  256,256);
  k_transpose<<<cdiv(65536,256),256,0,stream>>>(r1W, r1Wt, 256,256);
  k_transpose<<<cdiv(65536,256),256,0,stream>>>(Wg,  Wgt,  256,256);
  k_transpose<<<cdiv(16384,256),256,0,stream>>>(r2W, r2Wt, 256,64);
  k_asdt<<<1,256,0,stream>>>(a_s, a_d, asi, adi);

  // ---- CSR build (edge_index fully consumed here) ----
  k_hist  <<<cdiv(E,256),256,0,stream>>>(ei, E, N, flag, cur);
  k_scan_a<<<nb1024,256,0,stream>>>(cur, N, bsum);
  k_scan_b<<<1,64,0,stream>>>(bsum, nb1024);
  k_scan_c<<<nb1024,256,0,stream>>>(cur, bsum, N, offs);
  k_dinv2 <<<cdiv(N,256),256,0,stream>>>(offs, N, dinv);
  hipMemsetAsync(cur, 0, (size_t)N*4, stream);
  k_scatter<<<cdiv(E,256),256,0,stream>>>(ei, E, N, flag, offs, cur, csr);

  size_t miscUsed = (size_t)(w - (char*)d_ws);
  size_t bigNeed  = miscUsed + 2*((size_t)N*512) + 1024;  // two N*256 bf16 regions

  if (ws_size >= bigNeed){
    // ================= BIG PATH (fused full-width) =================
    u16* RA = (u16*)alloc((size_t)N*512);   // H1 -> R1 -> H2i ; then h3/r3/agg3/x4 (f32)
    u16* RB = (u16*)alloc((size_t)N*512);   // AGG1 -> X2 ; then h4 (f32)
    u16* tAe = (u16*)d_in[1];               // edge buffer: O2 -> x3 (N*64 bf16)
    u16* r2d = (u16*)d_out;                 // r2 (N*64 bf16), later agg4 f32

    float* h3   = (float*)RA;
    float* r3   = (float*)(RA + (size_t)N*32);
    float* agg3 = (float*)(RA + (size_t)N*64);
    float* x4   = (float*)(RA + (size_t)N*96);
    float* h4   = (float*)RB;
    float* agg4 = (float*)d_out;

    // Layer 1: GCN(256->256)
    k_gemm256<float,false><<<gemmGrid,256,0,stream>>>(x, x+64, x+128, x+192, 256,
                                                      W1t, nullptr, RA, N);          // H1
    k_gather256x<<<nodeGrid*8,256,0,stream>>>(RA, offs, csr, dinv, b1, N, RB);       // AGG1
    k_stats_part<u16,256><<<statsGrid,256,0,stream>>>(RB, N, part);
    k_bnfin3<256><<<8,256,0,stream>>>(part, statsGrid, g1, be1, (float)N, bnp1);
    k_gemm256<float,false><<<gemmGrid,256,0,stream>>>(x, x+64, x+128, x+192, 256,
                                                      r1Wt, r1b, RA, N);             // R1
    k_ew_b16b16<<<cdiv(N*256,256),256,0,stream>>>(RB, RA, bnp1, 256, N*256, RB);     // X2

    // Layer 2: GAT fused
    k_gemm256<u16,true><<<gemmGrid,256,0,stream>>>(RB, RB+64, RB+128, RB+192, 256,
                                                   Wgt, nullptr, RA, N);             // H2 interleaved
    k_gemm64<u16><<<gemmGrid,256,0,stream>>>(RB, RB+64, RB+128, RB+192, 256,
                                             r2Wt, r2b, r2d, N);                     // r2
    k_dot_all<<<nodeGrid,256,0,stream>>>(RA, asi, adi, N, als, ald);
    k_gat_allx<<<nodeGrid*8,256,0,stream>>>(RA, offs, csr, als, ald, bg, N, tAe);    // O2
    k_stats_part<u16,64><<<statsGrid,256,0,stream>>>(tAe, N, part);
    k_bnfin3<64><<<2,256,0,stream>>>(part, statsGrid, g2, be2, (float)N, bnp2);
    k_ew_b16b16<<<cdiv(N*64,256),256,0,stream>>>(tAe, r2d, bnp2, 64, N*64, tAe);     // x3

    // Layer 3
    k_gemm64_16x2<<<cdiv(N,8),256,0,stream>>>(tAe, W3, r3W, r3b, N, h3, r3);
    k_gcn_agg16<<<cdiv(N,16),256,0,stream>>>(h3, offs, csr, dinv, b3, agg3, N);
    k_stats_part<float,16><<<statsGrid,256,0,stream>>>(agg3, N, part);
    k_bnfin3<16><<<1,256,0,stream>>>(part, statsGrid, g3, be3, (float)N, bnp3);
    k_ew_f32f32<<<cdiv(N*16,256),256,0,stream>>>(agg3, r3, bnp3, 16, N*16, x4);

    // Layer 4
    k_gemm16_64<<<nodeGrid,256,0,stream>>>(x4, W4, N, h4);
    k_gcn_agg64fx<<<nodeGrid*4,256,0,stream>>>(h4, offs, csr, dinv, b4, agg4, N);
    k_final<<<nodeGrid,256,0,stream>>>(agg4, pW, pb, N, (float*)d_out);
  } else {
    // ================= FALLBACK (round-8 structure) =================
    u16* X0 = (u16*)alloc((size_t)N*64*2);
    u16* X1 = (u16*)alloc((size_t)N*64*2);
    u16* tA = (u16*)alloc((size_t)N*64*2);
    u16* tB = (u16*)alloc((size_t)N*64*2);
    u16* X2 = (u16*)d_in[1];
    u16* X3 = (u16*)d_out;
    const u16* XP[4] = {X0, X1, X2, X3};

    float* h3   = (float*)X1;
    float* r3   = (float*)(X1 + (size_t)N*32);
    float* agg3 = (float*)tA;
    float* x4   = (float*)(tA + (size_t)N*32);
    float* h4   = (float*)X0;
    float* agg4 = (float*)tA;

    for (int tau=0; tau<4; ++tau){
      u16* Xt = (u16*)XP[tau];
      k_gemm64<float><<<gemmGrid,256,0,stream>>>(x, x+64, x+128, x+192, 256,
                                                 W1t + (size_t)tau*64*256, nullptr, tA, N);
      k_gather64<<<nodeGrid,256,0,stream>>>(tA, offs, csr, dinv, b1 + tau*64, N, tB);
      k_stats_part<u16,64><<<statsGrid,256,0,stream>>>(tB, N, part);
      k_bnfin3<64><<<2,256,0,stream>>>(part, statsGrid, g1 + tau*64, be1 + tau*64, (float)N, bnp1 + tau*128);
      k_gemm64<float><<<gemmGrid,256,0,stream>>>(x, x+64, x+128, x+192, 256,
                                                 r1Wt + (size_t)tau*64*256, r1b + tau*64, tA, N);
      k_ew_b16b16<<<cdiv(N*64,256),256,0,stream>>>(tB, tA, bnp1 + tau*128, 64, N*64, Xt);
    }

    for (int head=0; head<4; ++head){
      k_gemm64<u16><<<gemmGrid,256,0,stream>>>(XP[0], XP[1], XP[2], XP[3], 64,
                                               Wgt + (size_t)head*64*256, nullptr, tA, N);
      k_dot64<<<nodeGrid,256,0,stream>>>(tA, a_s + head*64, a_d + head*64, head, N, als, ald);
      k_gat_head<<<nodeGrid,256,0,stream>>>(tA, offs, csr, als, ald, bg, head, N, tB);
    }
    k_gemm64<u16><<<gemmGrid,256,0,stream>>>(XP[0], XP[1], XP[2], XP[3], 64,
                                             r2Wt, r2b, tA, N);
    k_stats_part<u16,64><<<statsGrid,256,0,stream>>>(tB, N, part);
    k_bnfin3<64><<<2,256,0,stream>>>(part, statsGrid, g2, be2, (float)N, bnp2);
    k_ew_b16b16<<<cdiv(N*64,256),256,0,stream>>>(tB, tA, bnp2, 64, N*64, X0);

    k_gemm64_16x2<<<cdiv(N,8),256,0,stream>>>(X0, W3, r3W, r3b, N, h3, r3);
    k_gcn_agg16<<<cdiv(N,16),256,0,stream>>>(h3, offs, csr, dinv, b3, agg3, N);
    k_stats_part<float,16><<<statsGrid,256,0,stream>>>(agg3, N, part);
    k_bnfin3<16><<<1,256,0,stream>>>(part, statsGrid, g3, be3, (float)N, bnp3);
    k_ew_f32f32<<<cdiv(N*16,256),256,0,stream>>>(agg3, r3, bnp3, 16, N*16, x4);

    k_gemm16_64<<<nodeGrid,256,0,stream>>>(x4, W4, N, h4);
    k_gcn_agg64f<<<nodeGrid,256,0,stream>>>(h4, offs, csr, dinv, b4, agg4, N);
    k_final<<<nodeGrid,256,0,stream>>>(agg4, pW, pb, N, (float*)d_out);
  }
}

// Round 6
// 727.891 us; speedup vs baseline: 1.9155x; 1.9155x over previous
//
#include <hip/hip_runtime.h>

typedef unsigned short u16;
typedef unsigned int   u32;

// ---------- bf16 helpers ----------
__device__ __forceinline__ float b2f(u16 h){ return __uint_as_float(((u32)h)<<16); }
__device__ __forceinline__ u16 f2b(float f){
  u32 u = __float_as_uint(f);
  u32 r = (u + 0x7fffu + ((u>>16)&1u)) >> 16;   // RNE
  return (u16)r;
}
__device__ __forceinline__ float leaky(float x, float s){ return x >= 0.f ? x : s*x; }

typedef __bf16 bf16x8 __attribute__((ext_vector_type(8)));
typedef float  f32x4  __attribute__((ext_vector_type(4)));

__device__ __forceinline__ float ldval(const u16* p){ return b2f(*p); }
__device__ __forceinline__ float ldval(const float* p){ return *p; }

__device__ __forceinline__ void load8(const u16* p, u16* h){ *(uint4*)h = *(const uint4*)p; }
__device__ __forceinline__ void load8(const float* p, u16* h){
  float4 a = *(const float4*)p; float4 b = *(const float4*)(p+4);
  h[0]=f2b(a.x); h[1]=f2b(a.y); h[2]=f2b(a.z); h[3]=f2b(a.w);
  h[4]=f2b(b.x); h[5]=f2b(b.y); h[6]=f2b(b.z); h[7]=f2b(b.w);
}

// ---------- int64-vs-int32 detection ----------
__global__ void k_detect(const u32* __restrict__ w, int E, u32* __restrict__ flag){
  u32 acc = 0;
  for (int i = blockIdx.x*256 + threadIdx.x; i < E; i += 256*gridDim.x)
    acc |= w[2*i + 1];
  __shared__ u32 s[256];
  s[threadIdx.x] = acc; __syncthreads();
  for (int o=128;o>0;o>>=1){ if (threadIdx.x<o) s[threadIdx.x] |= s[threadIdx.x+o]; __syncthreads(); }
  if (threadIdx.x==0 && s[0]) atomicOr(flag, 1u);
}

__device__ __forceinline__ void edge_sd(const int* __restrict__ ei, int E, int e, u32 is32,
                                        int& s, int& d){
  if (is32){ s = ei[e];   d = ei[E + e]; }
  else     { s = ei[2*e]; d = ei[2*E + 2*e]; }
}

// ---------- CSR build ----------
__global__ void k_hist(const int* __restrict__ ei, int E, int nN,
                       const u32* __restrict__ flag, int* __restrict__ cnt){
  int e = blockIdx.x*256 + threadIdx.x;
  if (e < E){
    int s,d; edge_sd(ei, E, e, *flag, s, d);
    if ((u32)s < (u32)nN && (u32)d < (u32)nN) atomicAdd(&cnt[d], 1);
  }
}

__global__ void k_scan_a(const int* __restrict__ cnt, int n, int* __restrict__ bsum){
  __shared__ int s[256];
  int base = blockIdx.x*1024, t = threadIdx.x, sum = 0;
  for (int j=0;j<4;j++){ int i = base + t*4 + j; if (i<n) sum += cnt[i]; }
  s[t] = sum; __syncthreads();
  for (int off=128; off>0; off>>=1){ if (t<off) s[t]+=s[t+off]; __syncthreads(); }
  if (t==0) bsum[blockIdx.x] = s[0];
}

__global__ void k_scan_b(int* bsum, int nb){
  if (threadIdx.x==0 && blockIdx.x==0){
    int acc = 0;
    for (int i=0;i<nb;i++){ int v = bsum[i]; bsum[i] = acc; acc += v; }
  }
}

__global__ void k_scan_c(const int* __restrict__ cnt, const int* __restrict__ bsum,
                         int n, int* __restrict__ offs){
  __shared__ int s[256];
  int base = blockIdx.x*1024, t = threadIdx.x;
  int v[4]; int sum=0;
  for (int j=0;j<4;j++){ int i=base+t*4+j; v[j] = (i<n)?cnt[i]:0; sum += v[j]; }
  s[t]=sum; __syncthreads();
  for (int off=1; off<256; off<<=1){
    int add = (t>=off)? s[t-off] : 0;
    __syncthreads();
    s[t] += add;
    __syncthreads();
  }
  int excl = (t ? s[t-1] : 0) + bsum[blockIdx.x];
  for (int j=0;j<4;j++){
    int i = base+t*4+j;
    if (i<n){ offs[i] = excl; excl += v[j]; if (i==n-1) offs[n] = excl; }
  }
}

__global__ void k_dinv2(const int* __restrict__ offs, int n, float* __restrict__ dinv){
  int i = blockIdx.x*256+threadIdx.x;
  if (i<n) dinv[i] = rsqrtf((float)(offs[i+1]-offs[i]) + 1.0f);
}

__global__ void k_scatter(const int* __restrict__ ei, int E, int nN,
                          const u32* __restrict__ flag, const int* __restrict__ offs,
                          int* __restrict__ cursor, int* __restrict__ csr){
  int e = blockIdx.x*256+threadIdx.x;
  if (e<E){
    int s,d; edge_sd(ei, E, e, *flag, s, d);
    if ((u32)s < (u32)nN && (u32)d < (u32)nN){
      int pos = offs[d] + atomicAdd(&cursor[d], 1);
      csr[pos] = s;
    }
  }
}

// ---------- transpose+convert: f32 (K x M) -> bf16 (M x K) ----------
__global__ void k_transpose(const float* __restrict__ in, u16* __restrict__ out, int K, int M){
  int i = blockIdx.x*256 + threadIdx.x;
  if (i < K*M){ int k = i / M, m = i % M; out[m*K + k] = f2b(in[i]); }
}

// interleave attention vectors: asi[c*4+h] = a_s[h*64+c]
__global__ void k_asdt(const float* __restrict__ a_s, const float* __restrict__ a_d,
                       float* __restrict__ asi, float* __restrict__ adi){
  int i = threadIdx.x;
  int h = i>>6, c = i&63;
  asi[c*4+h] = a_s[i];
  adi[c*4+h] = a_d[i];
}

// ---------- MFMA GEMM, M=64 (col-sliced waves: B read ONCE per block) ----------
template<typename AT>
__global__ __launch_bounds__(256) void k_gemm64(
  const AT* __restrict__ A0, const AT* __restrict__ A1,
  const AT* __restrict__ A2, const AT* __restrict__ A3,
  int rsA, const u16* __restrict__ Bt, const float* __restrict__ bias,
  u16* __restrict__ out, int nRows)
{
  alignas(16) __shared__ u16 Al[64*264];   // A staging, then reused as output tile
  const int t = threadIdx.x;
  const int r0 = blockIdx.x*64;
  for (int it=0; it<8; ++it){
    int c = t + it*256;
    int row = c>>5, seg = c&31;
    int gr = r0+row;
    u16 hv[8] = {0,0,0,0,0,0,0,0};
    if (gr < nRows){
      const AT* p = (seg<8)?A0 : (seg<16)?A1 : (seg<24)?A2 : A3;
      load8(p + (size_t)gr*rsA + (seg&7)*8, hv);
    }
    *(uint4*)&Al[row*264 + seg*8] = *(uint4*)hv;
  }
  const int lane=t&63, wid=t>>6, quad=lane>>4, l15=lane&15;
  __syncthreads();
  const int col = wid*16 + l15;
  const u16* Bp = Bt + (size_t)col*256 + quad*8;
  bf16x8 b[8];
  #pragma unroll
  for (int ks=0;ks<8;++ks) b[ks] = *(const bf16x8*)(Bp + ks*32);
  f32x4 acc[4] = {{0.f,0.f,0.f,0.f},{0.f,0.f,0.f,0.f},{0.f,0.f,0.f,0.f},{0.f,0.f,0.f,0.f}};
  #pragma unroll
  for (int rt=0; rt<4; ++rt){
    const int abase = (rt*16 + l15)*264 + quad*8;
    #pragma unroll
    for (int ks=0;ks<8;++ks){
      bf16x8 av = *(const bf16x8*)&Al[abase + ks*32];
      acc[rt] = __builtin_amdgcn_mfma_f32_16x16x32_bf16(av, b[ks], acc[rt], 0,0,0);
    }
  }
  __syncthreads();
  float bv = bias ? bias[col] : 0.f;
  #pragma unroll
  for (int rt=0; rt<4; ++rt){
    #pragma unroll
    for (int reg=0;reg<4;++reg)
      Al[(rt*16 + quad*4 + reg)*264 + col] = f2b(acc[rt][reg]+bv);
  }
  __syncthreads();
  #pragma unroll
  for (int it=0; it<2; ++it){
    int idx = it*256 + t;
    int row = idx>>3, cu = idx&7;
    if (r0+row < nRows)
      *(uint4*)(out + (size_t)(r0+row)*64 + cu*8) = *(const uint4*)&Al[row*264 + cu*8];
  }
}

// ---------- MFMA GEMM, M=256 (col-sliced waves; optional fused EW / fused DOT) ----------
// EW:  out = leaky(agg*bnp_sc + bnp_sh) + (acc+bias)   (coalesced agg read in copy-out)
// DOT: after epilogue, compute per-node attention dots from the interleaved LDS tile
template<typename AT, bool PERM, bool EW, bool DOT>
__global__ __launch_bounds__(256) void k_gemm256(
  const AT* __restrict__ A0, const AT* __restrict__ A1,
  const AT* __restrict__ A2, const AT* __restrict__ A3,
  int rsA, const u16* __restrict__ Bt, const float* __restrict__ bias,
  const u16* __restrict__ agg, const float* __restrict__ bnp,
  const float* __restrict__ asi, const float* __restrict__ adi,
  float* __restrict__ als, float* __restrict__ ald,
  u16* __restrict__ out, int nRows)
{
  alignas(16) __shared__ u16 Al[64*264];   // A staging, then reused as output tile
  const int t = threadIdx.x;
  const int r0 = blockIdx.x*64;
  for (int it=0; it<8; ++it){
    int c = t + it*256;
    int row = c>>5, seg = c&31;
    int gr = r0+row;
    u16 hv[8] = {0,0,0,0,0,0,0,0};
    if (gr < nRows){
      const AT* p = (seg<8)?A0 : (seg<16)?A1 : (seg<24)?A2 : A3;
      load8(p + (size_t)gr*rsA + (seg&7)*8, hv);
    }
    *(uint4*)&Al[row*264 + seg*8] = *(uint4*)hv;
  }
  const int lane=t&63, wid=t>>6, quad=lane>>4, l15=lane&15;
  __syncthreads();
  f32x4 acc[4][4];   // [ct][rt]
  #pragma unroll
  for (int ct=0; ct<4; ++ct)
    #pragma unroll
    for (int rt=0; rt<4; ++rt) acc[ct][rt] = {0.f,0.f,0.f,0.f};
  #pragma unroll
  for (int ct=0; ct<4; ++ct){
    const u16* Bp = Bt + (size_t)(wid*64 + ct*16 + l15)*256 + quad*8;
    bf16x8 b[8];
    #pragma unroll
    for (int ks=0;ks<8;++ks) b[ks] = *(const bf16x8*)(Bp + ks*32);
    #pragma unroll
    for (int rt=0; rt<4; ++rt){
      const int abase = (rt*16 + l15)*264 + quad*8;
      #pragma unroll
      for (int ks=0;ks<8;++ks){
        bf16x8 av = *(const bf16x8*)&Al[abase + ks*32];
        acc[ct][rt] = __builtin_amdgcn_mfma_f32_16x16x32_bf16(av, b[ks], acc[ct][rt], 0,0,0);
      }
    }
  }
  __syncthreads();   // all waves done reading Al before epilogue overwrite
  #pragma unroll
  for (int ct=0; ct<4; ++ct){
    int col = wid*64 + ct*16 + l15;
    float bv = bias ? bias[col] : 0.f;
    int oc = PERM ? ((col&63)*4 + (col>>6)) : col;
    #pragma unroll
    for (int rt=0; rt<4; ++rt){
      #pragma unroll
      for (int reg=0;reg<4;++reg)
        Al[(rt*16 + quad*4 + reg)*264 + oc] = f2b(acc[ct][rt][reg]+bv);
    }
  }
  __syncthreads();
  if constexpr (DOT){
    // 4 threads per row, 64 interleaved entries each; entry ii -> head ii&3
    int row = t>>2, q = t&3;
    int nd = r0 + row;
    if (nd < nRows){
      float s0=0.f,s1=0.f,s2=0.f,s3=0.f,d0=0.f,d1=0.f,d2=0.f,d3=0.f;
      const u16* ar = &Al[row*264 + q*64];
      const float* as = asi + q*64;
      const float* ad = adi + q*64;
      #pragma unroll 4
      for (int k=0;k<64;k+=4){
        uint2 wv = *(const uint2*)&ar[k];
        float v0=b2f((u16)(wv.x&0xffff)), v1=b2f((u16)(wv.x>>16));
        float v2=b2f((u16)(wv.y&0xffff)), v3=b2f((u16)(wv.y>>16));
        s0 += v0*as[k];   d0 += v0*ad[k];
        s1 += v1*as[k+1]; d1 += v1*ad[k+1];
        s2 += v2*as[k+2]; d2 += v2*ad[k+2];
        s3 += v3*as[k+3]; d3 += v3*ad[k+3];
      }
      s0 += __shfl_xor(s0,1,64); s0 += __shfl_xor(s0,2,64);
      s1 += __shfl_xor(s1,1,64); s1 += __shfl_xor(s1,2,64);
      s2 += __shfl_xor(s2,1,64); s2 += __shfl_xor(s2,2,64);
      s3 += __shfl_xor(s3,1,64); s3 += __shfl_xor(s3,2,64);
      d0 += __shfl_xor(d0,1,64); d0 += __shfl_xor(d0,2,64);
      d1 += __shfl_xor(d1,1,64); d1 += __shfl_xor(d1,2,64);
      d2 += __shfl_xor(d2,1,64); d2 += __shfl_xor(d2,2,64);
      d3 += __shfl_xor(d3,1,64); d3 += __shfl_xor(d3,2,64);
      if (q==0){
        float4 sv = {s0,s1,s2,s3}; float4 dv = {d0,d1,d2,d3};
        ((float4*)als)[nd] = sv;
        ((float4*)ald)[nd] = dv;
      }
    }
  }
  #pragma unroll
  for (int it=0; it<8; ++it){
    int idx = it*256 + t;
    int row = idx>>5, cu = idx&31;
    int r = r0+row;
    if (r < nRows){
      if constexpr (EW){
        uint4 hv = *(const uint4*)&Al[row*264 + cu*8];
        uint4 av = *(const uint4*)(agg + (size_t)r*256 + cu*8);
        const u16* hp = (const u16*)&hv; const u16* ap = (const u16*)&av;
        uint4 ov; u16* op = (u16*)&ov;
        #pragma unroll
        for (int j=0;j<8;++j){
          int c = cu*8+j;
          float v = b2f(ap[j])*bnp[c] + bnp[256+c];
          op[j] = f2b(leaky(v, 0.01f) + b2f(hp[j]));
        }
        *(uint4*)(out + (size_t)r*256 + cu*8) = ov;
      } else {
        *(uint4*)(out + (size_t)r*256 + cu*8) = *(const uint4*)&Al[row*264 + cu*8];
      }
    }
  }
}

// ---------- GCN gather, 64 channels (fallback path) ----------
__global__ void k_gather64(const u16* __restrict__ h, const int* __restrict__ offs,
                           const int* __restrict__ csr, const float* __restrict__ dinv,
                           const float* __restrict__ bias, int n, u16* __restrict__ out){
  int nd = blockIdx.x*4 + (threadIdx.x>>6);
  if (nd>=n) return;
  int lane = threadIdx.x&63;
  float dn = dinv[nd];
  float acc = dn*b2f(h[(size_t)nd*64+lane]);
  int e = offs[nd], end = offs[nd+1];
  for (; e+4<=end; e+=4){
    int s0=csr[e], s1=csr[e+1], s2=csr[e+2], s3=csr[e+3];
    float w0=dinv[s0], w1=dinv[s1], w2=dinv[s2], w3=dinv[s3];
    float p0=b2f(h[(size_t)s0*64+lane]);
    float p1=b2f(h[(size_t)s1*64+lane]);
    float p2=b2f(h[(size_t)s2*64+lane]);
    float p3=b2f(h[(size_t)s3*64+lane]);
    acc += w0*p0 + w1*p1 + w2*p2 + w3*p3;
  }
  for (; e<end; ++e){
    int s=csr[e];
    acc += dinv[s]*b2f(h[(size_t)s*64+lane]);
  }
  out[(size_t)nd*64+lane] = f2b(dn*acc + bias[lane]);
}

// ---------- GCN gather, 256 channels (big path, one edge walk) ----------
__global__ void k_gather256(const u16* __restrict__ h, const int* __restrict__ offs,
                            const int* __restrict__ csr, const float* __restrict__ dinv,
                            const float* __restrict__ bias, int n, u16* __restrict__ out){
  int nd = blockIdx.x*4 + (threadIdx.x>>6);
  if (nd>=n) return;
  int lane = threadIdx.x&63;
  const uint2* H = (const uint2*)h;
  float dn = dinv[nd];
  uint2 pv = H[(size_t)nd*64 + lane];
  float a0=dn*b2f(pv.x&0xffff), a1=dn*b2f(pv.x>>16);
  float a2=dn*b2f(pv.y&0xffff), a3=dn*b2f(pv.y>>16);
  int e=offs[nd], end=offs[nd+1];
  for (; e+2<=end; e+=2){
    int s0=csr[e], s1=csr[e+1];
    float w0=dinv[s0], w1=dinv[s1];
    uint2 q0=H[(size_t)s0*64+lane], q1=H[(size_t)s1*64+lane];
    a0 += w0*b2f(q0.x&0xffff) + w1*b2f(q1.x&0xffff);
    a1 += w0*b2f(q0.x>>16)    + w1*b2f(q1.x>>16);
    a2 += w0*b2f(q0.y&0xffff) + w1*b2f(q1.y&0xffff);
    a3 += w0*b2f(q0.y>>16)    + w1*b2f(q1.y>>16);
  }
  for (; e<end; ++e){
    int s=csr[e]; float w=dinv[s];
    uint2 q=H[(size_t)s*64+lane];
    a0 += w*b2f(q.x&0xffff); a1 += w*b2f(q.x>>16);
    a2 += w*b2f(q.y&0xffff); a3 += w*b2f(q.y>>16);
  }
  float4 bv = *(const float4*)(bias + lane*4);
  uint2 o;
  o.x = (u32)f2b(a0*dn + bv.x) | ((u32)f2b(a1*dn + bv.y)<<16);
  o.y = (u32)f2b(a2*dn + bv.z) | ((u32)f2b(a3*dn + bv.w)<<16);
  ((uint2*)out)[(size_t)nd*64 + lane] = o;
}

// ---------- BN stats partials, vectorized (16B loads, reg partials, LDS tree) ----------
template<typename T, int C>
__global__ __launch_bounds__(256) void k_stats_part(const T* __restrict__ x, int n,
                                                    float* __restrict__ part){
  constexpr int VE = 16/sizeof(T);   // elems per 16B load: 8 (bf16) / 4 (f32)
  constexpr int G  = C/VE;           // vec-groups per row
  constexpr int R  = 256/G;          // rows covered per block pass
  int t = threadIdx.x;
  int g = t % G, sub = t / G;
  int rpb = (n + gridDim.x - 1) / gridDim.x;
  int base = blockIdx.x * rpb;
  int lim  = min(base + rpb, n);
  float s[VE], s2[VE];
  #pragma unroll
  for (int j=0;j<VE;j++){ s[j]=0.f; s2[j]=0.f; }
  #pragma unroll 4
  for (int r = base + sub; r < lim; r += R){
    const T* p = x + (size_t)r*C + g*VE;
    if constexpr (sizeof(T)==2){
      uint4 v = *(const uint4*)p;
      u32 wq[4] = {v.x, v.y, v.z, v.w};
      #pragma unroll
      for (int q=0;q<4;q++){
        float lo = __uint_as_float(wq[q]<<16);
        float hi = __uint_as_float(wq[q]&0xffff0000u);
        s[2*q]  += lo; s2[2*q]  += lo*lo;
        s[2*q+1]+= hi; s2[2*q+1]+= hi*hi;
      }
    } else {
      float4 v = *(const float4*)p;
      float a[4] = {v.x, v.y, v.z, v.w};
      #pragma unroll
      for (int q=0;q<4;q++){ s[q]+=a[q]; s2[q]+=a[q]*a[q]; }
    }
  }
  __shared__ float red[VE][256];
  #pragma unroll
  for (int j=0;j<VE;j++) red[j][t] = s[j];
  __syncthreads();
  for (int off=R/2; off>0; off>>=1){
    if (sub < off){
      #pragma unroll
      for (int j=0;j<VE;j++) red[j][t] += red[j][t + off*G];
    }
    __syncthreads();
  }
  if (t < G){
    #pragma unroll
    for (int j=0;j<VE;j++) part[blockIdx.x*2*C + t*VE + j] = red[j][t];
  }
  __syncthreads();
  #pragma unroll
  for (int j=0;j<VE;j++) red[j][t] = s2[j];
  __syncthreads();
  for (int off=R/2; off>0; off>>=1){
    if (sub < off){
      #pragma unroll
      for (int j=0;j<VE;j++) red[j][t] += red[j][t + off*G];
    }
    __syncthreads();
  }
  if (t < G){
    #pragma unroll
    for (int j=0;j<VE;j++) part[blockIdx.x*2*C + C + t*VE + j] = red[j][t];
  }
}

// ---------- BN finalize: channel-parallel multi-block (32 ch/block, 8 thr/ch) ----------
template<int C>
__global__ __launch_bounds__(256) void k_bnfin3(const float* __restrict__ part, int B,
                         const float* __restrict__ g, const float* __restrict__ be,
                         float n, float* __restrict__ bnp){
  constexpr int CPB = (C < 32) ? C : 32;   // channels per block
  constexpr int TPC = 256 / CPB;           // threads per channel
  int t = threadIdx.x;
  int lc = t % CPB, sub = t / CPB;
  int c = blockIdx.x*CPB + lc;
  float s=0.f, s2=0.f;
  for (int b = sub; b < B; b += TPC){
    s  += part[(size_t)b*2*C + c];
    s2 += part[(size_t)b*2*C + C + c];
  }
  __shared__ float ls[256], lq[256];
  ls[t]=s; lq[t]=s2; __syncthreads();
  for (int off=TPC/2; off>0; off>>=1){
    if (sub < off){ ls[t]+=ls[t+off*CPB]; lq[t]+=lq[t+off*CPB]; }
    __syncthreads();
  }
  if (sub==0){
    float mu = ls[t]/n;
    float var = fmaxf(lq[t]/n - mu*mu, 0.f);
    float sc = g[c] * rsqrtf(var + 1e-5f);
    bnp[c] = sc;
    bnp[C+c] = be[c] - mu*sc;
  }
}

// ---------- elementwise BN+leaky+residual ----------
__global__ void k_ew_b16b16(const u16* __restrict__ agg, const u16* __restrict__ res,
                            const float* __restrict__ bnp, int C, int total, u16* __restrict__ out){
  int i = blockIdx.x*256+threadIdx.x;
  if (i < total){
    int c = i & (C-1);
    float v = b2f(agg[i])*bnp[c] + bnp[C+c];
    out[i] = f2b(leaky(v, 0.01f) + b2f(res[i]));
  }
}

__global__ void k_ew_f32f32(const float* __restrict__ agg, const float* __restrict__ res,
                            const float* __restrict__ bnp, int C, int total, float* __restrict__ out){
  int i = blockIdx.x*256+threadIdx.x;
  if (i < total){
    int c = i & (C-1);
    float v = agg[i]*bnp[c] + bnp[C+c];
    out[i] = leaky(v, 0.01f) + res[i];
  }
}

// ---------- GAT fallback: per-head logit dot ----------
__global__ void k_dot64(const u16* __restrict__ h2t, const float* __restrict__ asg,
                        const float* __restrict__ adg, int head, int n,
                        float* __restrict__ als, float* __restrict__ ald){
  int nd = blockIdx.x*4 + (threadIdx.x>>6);
  if (nd>=n) return;
  int lane = threadIdx.x&63;
  float p = b2f(h2t[(size_t)nd*64+lane]);
  float ss = p*asg[lane];
  float sd = p*adg[lane];
  for (int m=1;m<64;m<<=1){ ss += __shfl_xor(ss,m,64); sd += __shfl_xor(sd,m,64); }
  if (lane==0){ als[nd*4+head]=ss; ald[nd*4+head]=sd; }
}

// ---------- GAT fallback: per-head softmax gather (online softmax) ----------
__global__ void k_gat_head(const u16* __restrict__ h2t, const int* __restrict__ offs,
                           const int* __restrict__ csr, const float* __restrict__ als,
                           const float* __restrict__ ald, const float* __restrict__ bg,
                           int head, int n, u16* __restrict__ O2){
  int nd = blockIdx.x*4 + (threadIdx.x>>6);
  if (nd>=n) return;
  int lane = threadIdx.x&63;
  float aldn = ald[nd*4+head];
  float m = leaky(als[nd*4+head] + aldn, 0.2f);
  float denom = 1.f;
  float acc = b2f(h2t[(size_t)nd*64+lane]);
  int e = offs[nd], end = offs[nd+1];
  for (; e+4<=end; e+=4){
    int s0=csr[e], s1=csr[e+1], s2=csr[e+2], s3=csr[e+3];
    float l0=als[s0*4+head], l1=als[s1*4+head], l2=als[s2*4+head], l3=als[s3*4+head];
    float p0=b2f(h2t[(size_t)s0*64+lane]);
    float p1=b2f(h2t[(size_t)s1*64+lane]);
    float p2=b2f(h2t[(size_t)s2*64+lane]);
    float p3=b2f(h2t[(size_t)s3*64+lane]);
    float g0=leaky(l0+aldn,0.2f), g1=leaky(l1+aldn,0.2f);
    float g2=leaky(l2+aldn,0.2f), g3=leaky(l3+aldn,0.2f);
    float mc = fmaxf(fmaxf(g0,g1), fmaxf(g2,g3));
    float mn = fmaxf(m, mc);
    float sc = __expf(m - mn);
    float w0 = __expf(g0-mn), w1 = __expf(g1-mn), w2 = __expf(g2-mn), w3 = __expf(g3-mn);
    denom = denom*sc + (w0+w1+w2+w3);
    acc   = acc*sc   + (w0*p0 + w1*p1 + w2*p2 + w3*p3);
    m = mn;
  }
  for (; e<end; ++e){
    int s = csr[e];
    float g = leaky(als[s*4+head]+aldn, 0.2f);
    float p = b2f(h2t[(size_t)s*64+lane]);
    float mn = fmaxf(m, g);
    float sc = __expf(m - mn);
    float w = __expf(g - mn);
    denom = denom*sc + w;
    acc   = acc*sc   + w*p;
    m = mn;
  }
  float v = 0.25f * acc / fmaxf(denom, 1e-20f);
  size_t oi = (size_t)nd*64+lane;
  if (head==0) O2[oi] = f2b(v + bg[lane]);
  else         O2[oi] = f2b(b2f(O2[oi]) + v);
}

// ---------- GAT big path: fused, distributed weights via intra-wave LDS ----------
__global__ void k_gat_all(const u16* __restrict__ h2i, const int* __restrict__ offs,
                          const int* __restrict__ csr, const float* __restrict__ als,
                          const float* __restrict__ ald, const float* __restrict__ bg,
                          int n, u16* __restrict__ O2){
  alignas(16) __shared__ float shm[4][80];  // per wave: [0..3] denoms, [4..7] self-w, [8..71] edge wts
  int wv = threadIdx.x>>6;
  int nd = blockIdx.x*4 + wv;
  if (nd>=n) return;
  int lane = threadIdx.x&63;
  int eg = lane>>2, hh = lane&3;
  float4 alv = ((const float4*)als)[nd];
  float4 adv = ((const float4*)ald)[nd];
  float adh = (hh&2) ? ((hh&1)?adv.w:adv.z) : ((hh&1)?adv.y:adv.x);
  float alh = (hh&2) ? ((hh&1)?alv.w:alv.z) : ((hh&1)?alv.y:alv.x);
  float gsh = leaky(alh+adh, 0.2f);
  int beg=offs[nd], end=offs[nd+1];
  // pass 1: distributed per-head max (incl. self)
  float m = gsh;
  for (int e=beg+eg; e<end; e+=16){
    int s = csr[e];
    m = fmaxf(m, leaky(als[s*4+hh]+adh, 0.2f));
  }
  #pragma unroll
  for (int off=4; off<64; off<<=1) m = fmaxf(m, __shfl_xor(m, off, 64));
  float wsh = __expf(gsh - m);
  if (eg==0) shm[wv][4+hh] = wsh;
  float4 ws4 = *(const float4*)&shm[wv][4];
  uint2 pv = ((const uint2*)h2i)[(size_t)nd*64+lane];
  float a0 = ws4.x*__uint_as_float(pv.x<<16);
  float a1 = ws4.y*__uint_as_float(pv.x&0xffff0000u);
  float a2 = ws4.z*__uint_as_float(pv.y<<16);
  float a3 = ws4.w*__uint_as_float(pv.y&0xffff0000u);
  float dpart = 0.f;
  const uint2* H = (const uint2*)h2i;
  // pass 2: chunks of 16 edges; phase A computes 64 weights (1 exp/lane),
  // phase B does the all-lane weighted gather with LDS-broadcast weights
  for (int e0=beg; e0<end; e0+=16){
    int e = e0+eg;
    int sA = 0; float wE = 0.f;
    if (e<end){
      sA = csr[e];
      wE = __expf(leaky(als[sA*4+hh]+adh, 0.2f) - m);
    }
    dpart += wE;
    shm[wv][8+lane] = wE;
    int cnt = min(16, end-e0);
    int k=0;
    for (; k+4<=cnt; k+=4){
      int sa=__shfl(sA,(k  )*4,64), sb=__shfl(sA,(k+1)*4,64);
      int sc=__shfl(sA,(k+2)*4,64), sd=__shfl(sA,(k+3)*4,64);
      float4 wa=*(const float4*)&shm[wv][8+(k  )*4];
      float4 wb=*(const float4*)&shm[wv][8+(k+1)*4];
      float4 wc=*(const float4*)&shm[wv][8+(k+2)*4];
      float4 wd=*(const float4*)&shm[wv][8+(k+3)*4];
      uint2 qa=H[(size_t)sa*64+lane], qb=H[(size_t)sb*64+lane];
      uint2 qc=H[(size_t)sc*64+lane], qd=H[(size_t)sd*64+lane];
      a0 += wa.x*__uint_as_float(qa.x<<16) + wb.x*__uint_as_float(qb.x<<16)
          + wc.x*__uint_as_float(qc.x<<16) + wd.x*__uint_as_float(qd.x<<16);
      a1 += wa.y*__uint_as_float(qa.x&0xffff0000u) + wb.y*__uint_as_float(qb.x&0xffff0000u)
          + wc.y*__uint_as_float(qc.x&0xffff0000u) + wd.y*__uint_as_float(qd.x&0xffff0000u);
      a2 += wa.z*__uint_as_float(qa.y<<16) + wb.z*__uint_as_float(qb.y<<16)
          + wc.z*__uint_as_float(qc.y<<16) + wd.z*__uint_as_float(qd.y<<16);
      a3 += wa.w*__uint_as_float(qa.y&0xffff0000u) + wb.w*__uint_as_float(qb.y&0xffff0000u)
          + wc.w*__uint_as_float(qc.y&0xffff0000u) + wd.w*__uint_as_float(qd.y&0xffff0000u);
    }
    for (; k<cnt; ++k){
      int s = __shfl(sA, k*4, 64);
      float4 w4 = *(const float4*)&shm[wv][8+k*4];
      uint2 q = H[(size_t)s*64+lane];
      a0 += w4.x*__uint_as_float(q.x<<16);
      a1 += w4.y*__uint_as_float(q.x&0xffff0000u);
      a2 += w4.z*__uint_as_float(q.y<<16);
      a3 += w4.w*__uint_as_float(q.y&0xffff0000u);
    }
  }
  #pragma unroll
  for (int off=4; off<64; off<<=1) dpart += __shfl_xor(dpart, off, 64);
  float dh = dpart + wsh;
  if (eg==0) shm[wv][hh] = dh;
  float4 d4 = *(const float4*)&shm[wv][0];
  float v = 0.25f*(a0/d4.x + a1/d4.y + a2/d4.z + a3/d4.w);
  O2[(size_t)nd*64+lane] = f2b(v + bg[lane]);
}

// ---------- GCN aggregation, C=16, f32 ----------
__global__ void k_gcn_agg16(const float* __restrict__ h, const int* __restrict__ offs,
                            const int* __restrict__ csr, const float* __restrict__ dinv,
                            const float* __restrict__ bias, float* __restrict__ out, int n){
  int t = threadIdx.x;
  int nd = blockIdx.x*16 + (t>>4);
  if (nd>=n) return;
  int c = t&15;
  float dn = dinv[nd];
  float acc = dn*h[(size_t)nd*16+c];
  int e=offs[nd], end=offs[nd+1];
  for (; e+4<=end; e+=4){
    int s0=csr[e], s1=csr[e+1], s2=csr[e+2], s3=csr[e+3];
    float w0=dinv[s0], w1=dinv[s1], w2=dinv[s2], w3=dinv[s3];
    float p0=h[(size_t)s0*16+c], p1=h[(size_t)s1*16+c];
    float p2=h[(size_t)s2*16+c], p3=h[(size_t)s3*16+c];
    acc += w0*p0 + w1*p1 + w2*p2 + w3*p3;
  }
  for (; e<end; ++e){
    int s = csr[e];
    acc += dinv[s]*h[(size_t)s*16+c];
  }
  out[(size_t)nd*16+c] = dn*acc + bias[c];
}

// ---------- GCN aggregation, C=64, f32 ----------
__global__ void k_gcn_agg64f(const float* __restrict__ h, const int* __restrict__ offs,
                             const int* __restrict__ csr, const float* __restrict__ dinv,
                             const float* __restrict__ bias, float* __restrict__ out, int n){
  int nd = blockIdx.x*4 + (threadIdx.x>>6);
  if (nd>=n) return;
  int lane = threadIdx.x&63;
  float dn = dinv[nd];
  float acc = dn*h[(size_t)nd*64+lane];
  int e=offs[nd], end=offs[nd+1];
  for (; e+4<=end; e+=4){
    int s0=csr[e], s1=csr[e+1], s2=csr[e+2], s3=csr[e+3];
    float w0=dinv[s0], w1=dinv[s1], w2=dinv[s2], w3=dinv[s3];
    float p0=h[(size_t)s0*64+lane], p1=h[(size_t)s1*64+lane];
    float p2=h[(size_t)s2*64+lane], p3=h[(size_t)s3*64+lane];
    acc += w0*p0 + w1*p1 + w2*p2 + w3*p3;
  }
  for (; e<end; ++e){
    int s=csr[e];
    acc += dinv[s]*h[(size_t)s*64+lane];
  }
  out[(size_t)nd*64+lane] = dn*acc + bias[lane];
}

// ---------- small VALU GEMMs ----------
__global__ void k_gemm64_16x2(const u16* __restrict__ x, const float* __restrict__ W1_,
                              const float* __restrict__ W2_, const float* __restrict__ b2_,
                              int n, float* __restrict__ o1, float* __restrict__ o2){
  __shared__ float w1[64*16], w2[64*16];
  int t = threadIdx.x;
  for (int i=t; i<1024; i+=256){ w1[i]=W1_[i]; w2[i]=W2_[i]; }
  __syncthreads();
  int nd = blockIdx.x*8 + (t>>5);
  if (nd>=n) return;
  int j = t & 31;
  const u16* xr = x + (size_t)nd*64;
  if (j<16){
    float s=0.f;
    #pragma unroll 8
    for (int k=0;k<64;k++) s += b2f(xr[k])*w1[k*16+j];
    o1[(size_t)nd*16+j]=s;
  } else {
    int jj=j-16;
    float s = b2_[jj];
    #pragma unroll 8
    for (int k=0;k<64;k++) s += b2f(xr[k])*w2[k*16+jj];
    o2[(size_t)nd*16+jj]=s;
  }
}

__global__ void k_gemm16_64(const float* __restrict__ x, const float* __restrict__ W,
                            int n, float* __restrict__ o){
  __shared__ float w[16*64];
  int t = threadIdx.x;
  for (int i=t;i<1024;i+=256) w[i]=W[i];
  __syncthreads();
  int nd = blockIdx.x*4 + (t>>6);
  if (nd>=n) return;
  int j = t&63;
  const float* xr = x + (size_t)nd*16;
  float s=0.f;
  #pragma unroll
  for (int k=0;k<16;k++) s += xr[k]*w[k*64+j];
  o[(size_t)nd*64+j]=s;
}

// out(N,64) = x(N,64)@pW + pb, f32 out (safe in-place per-wave)
__global__ void k_final(const float* __restrict__ x, const float* __restrict__ W,
                        const float* __restrict__ b, int n, float* __restrict__ out){
  __shared__ float w[64*64];
  int t=threadIdx.x;
  for (int i=t;i<4096;i+=256) w[i]=W[i];
  __syncthreads();
  int nd = blockIdx.x*4 + (t>>6);
  if (nd>=n) return;
  int j=t&63;
  const float* xr = x + (size_t)nd*64;
  float s=b[j];
  #pragma unroll 8
  for (int k=0;k<64;k++) s += xr[k]*w[k*64+j];
  out[(size_t)nd*64+j]=s;
}

// =======================================================================
extern "C" void kernel_launch(void* const* d_in, const int* in_sizes, int n_in,
                              void* d_out, int out_size, void* d_ws, size_t ws_size,
                              hipStream_t stream) {
  const float* x   = (const float*)d_in[0];
  const int*   ei  = (const int*)d_in[1];
  const float* W1  = (const float*)d_in[2];
  const float* b1  = (const float*)d_in[3];
  const float* g1  = (const float*)d_in[4];
  const float* be1 = (const float*)d_in[5];
  const float* Wg  = (const float*)d_in[6];
  const float* a_s = (const float*)d_in[7];
  const float* a_d = (const float*)d_in[8];
  const float* bg  = (const float*)d_in[9];
  const float* g2  = (const float*)d_in[10];
  const float* be2 = (const float*)d_in[11];
  const float* W3  = (const float*)d_in[12];
  const float* b3  = (const float*)d_in[13];
  const float* g3  = (const float*)d_in[14];
  const float* be3 = (const float*)d_in[15];
  const float* W4  = (const float*)d_in[16];
  const float* b4  = (const float*)d_in[17];
  const float* r1W = (const float*)d_in[18];
  const float* r1b = (const float*)d_in[19];
  const float* r2W = (const float*)d_in[20];
  const float* r2b = (const float*)d_in[21];
  const float* r3W = (const float*)d_in[22];
  const float* r3b = (const float*)d_in[23];
  const float* pW  = (const float*)d_in[24];
  const float* pb  = (const float*)d_in[25];

  const int N = in_sizes[0] / 256;
  const int E = in_sizes[1] / 2;

  // ---- common misc carve-out ----
  char* w = (char*)d_ws;
  auto alloc = [&](size_t b)->void*{ void* p=(void*)w; w += (b+255)&~(size_t)255; return p; };
  u32*   flag   = (u32*)  alloc(4);
  float* part   = (float*)alloc(256*512*4);       // stats partials (256 blocks x 2C, C<=256)
  float* bnp1   = (float*)alloc(512*4);
  float* bnp2   = (float*)alloc(128*4);
  float* bnp3   = (float*)alloc(32*4);
  int*   bsum   = (int*)  alloc(256*4);
  int*   cur    = (int*)  alloc((size_t)N*4);
  int*   offs   = (int*)  alloc((size_t)(N+1)*4);
  float* dinv   = (float*)alloc((size_t)N*4);
  int*   csr    = (int*)  alloc((size_t)E*4);
  float* als    = (float*)alloc((size_t)N*16);
  float* ald    = (float*)alloc((size_t)N*16);
  float* asi    = (float*)alloc(256*4);
  float* adi    = (float*)alloc(256*4);
  u16*   W1t    = (u16*)  alloc(65536*2);
  u16*   r1Wt   = (u16*)  alloc(65536*2);
  u16*   Wgt    = (u16*)  alloc(65536*2);
  u16*   r2Wt   = (u16*)  alloc(16384*2);

  auto cdiv = [](int a, int b){ return (a+b-1)/b; };
  const int nb1024 = cdiv(N, 1024);
  const int statsGrid = 256;
  const int gemmGrid = cdiv(N,64);
  const int nodeGrid = cdiv(N,4);

  hipMemsetAsync(flag,   0, 4, stream);
  hipMemsetAsync(cur,    0, (size_t)N*4, stream);

  k_detect<<<64,256,0,stream>>>((const u32*)ei, E, flag);

  k_transpose<<<cdiv(65536,256),256,0,stream>>>(W1,  W1t,  256,256);
  k_transpose<<<cdiv(65536,256),256,0,stream>>>(r1W, r1Wt, 256,256);
  k_transpose<<<cdiv(65536,256),256,0,stream>>>(Wg,  Wgt,  256,256);
  k_transpose<<<cdiv(16384,256),256,0,stream>>>(r2W, r2Wt, 256,64);
  k_asdt<<<1,256,0,stream>>>(a_s, a_d, asi, adi);

  // ---- CSR build (edge_index fully consumed here) ----
  k_hist  <<<cdiv(E,256),256,0,stream>>>(ei, E, N, flag, cur);
  k_scan_a<<<nb1024,256,0,stream>>>(cur, N, bsum);
  k_scan_b<<<1,64,0,stream>>>(bsum, nb1024);
  k_scan_c<<<nb1024,256,0,stream>>>(cur, bsum, N, offs);
  k_dinv2 <<<cdiv(N,256),256,0,stream>>>(offs, N, dinv);
  hipMemsetAsync(cur, 0, (size_t)N*4, stream);
  k_scatter<<<cdiv(E,256),256,0,stream>>>(ei, E, N, flag, offs, cur, csr);

  size_t miscUsed = (size_t)(w - (char*)d_ws);
  size_t bigNeed  = miscUsed + 2*((size_t)N*512) + 1024;  // two N*256 bf16 regions

  if (ws_size >= bigNeed){
    // ================= BIG PATH (fused full-width) =================
    u16* RA = (u16*)alloc((size_t)N*512);   // H1 -> H2i ; then h3/r3/agg3/x4 (f32)
    u16* RB = (u16*)alloc((size_t)N*512);   // AGG1 -> X2 (fused in R1 gemm) ; then h4 (f32)
    u16* tAe = (u16*)d_in[1];               // edge buffer: O2 -> x3 (N*64 bf16)
    u16* r2d = (u16*)d_out;                 // r2 (N*64 bf16), later agg4 f32

    float* h3   = (float*)RA;
    float* r3   = (float*)(RA + (size_t)N*32);
    float* agg3 = (float*)(RA + (size_t)N*64);
    float* x4   = (float*)(RA + (size_t)N*96);
    float* h4   = (float*)RB;
    float* agg4 = (float*)d_out;

    // Layer 1: GCN(256->256)
    k_gemm256<float,false,false,false><<<gemmGrid,256,0,stream>>>(
        x, x+64, x+128, x+192, 256, W1t, nullptr,
        nullptr, nullptr, nullptr, nullptr, nullptr, nullptr, RA, N);                // H1
    k_gather256<<<nodeGrid,256,0,stream>>>(RA, offs, csr, dinv, b1, N, RB);          // AGG1
    k_stats_part<u16,256><<<statsGrid,256,0,stream>>>(RB, N, part);
    k_bnfin3<256><<<8,256,0,stream>>>(part, statsGrid, g1, be1, (float)N, bnp1);
    // R1 gemm with fused BN+leaky+residual: X2 = leaky(BN(AGG1)) + R1, in-place in RB
    k_gemm256<float,false,true,false><<<gemmGrid,256,0,stream>>>(
        x, x+64, x+128, x+192, 256, r1Wt, r1b,
        RB, bnp1, nullptr, nullptr, nullptr, nullptr, RB, N);                        // X2

    // Layer 2: GAT fused (H2 gemm also emits attention logit dots)
    k_gemm256<u16,true,false,true><<<gemmGrid,256,0,stream>>>(
        RB, RB+64, RB+128, RB+192, 256, Wgt, nullptr,
        nullptr, nullptr, asi, adi, als, ald, RA, N);                                // H2i + als/ald
    k_gemm64<u16><<<gemmGrid,256,0,stream>>>(RB, RB+64, RB+128, RB+192, 256,
                                             r2Wt, r2b, r2d, N);                     // r2
    k_gat_all<<<nodeGrid,256,0,stream>>>(RA, offs, csr, als, ald, bg, N, tAe);       // O2
    k_stats_part<u16,64><<<statsGrid,256,0,stream>>>(tAe, N, part);
    k_bnfin3<64><<<2,256,0,stream>>>(part, statsGrid, g2, be2, (float)N, bnp2);
    k_ew_b16b16<<<cdiv(N*64,256),256,0,stream>>>(tAe, r2d, bnp2, 64, N*64, tAe);     // x3

    // Layer 3
    k_gemm64_16x2<<<cdiv(N,8),256,0,stream>>>(tAe, W3, r3W, r3b, N, h3, r3);
    k_gcn_agg16<<<cdiv(N,16),256,0,stream>>>(h3, offs, csr, dinv, b3, agg3, N);
    k_stats_part<float,16><<<statsGrid,256,0,stream>>>(agg3, N, part);
    k_bnfin3<16><<<1,256,0,stream>>>(part, statsGrid, g3, be3, (float)N, bnp3);
    k_ew_f32f32<<<cdiv(N*16,256),256,0,stream>>>(agg3, r3, bnp3, 16, N*16, x4);

    // Layer 4
    k_gemm16_64<<<nodeGrid,256,0,stream>>>(x4, W4, N, h4);
    k_gcn_agg64f<<<nodeGrid,256,0,stream>>>(h4, offs, csr, dinv, b4, agg4, N);
    k_final<<<nodeGrid,256,0,stream>>>(agg4, pW, pb, N, (float*)d_out);
  } else {
    // ================= FALLBACK (round-8 structure) =================
    u16* X0 = (u16*)alloc((size_t)N*64*2);
    u16* X1 = (u16*)alloc((size_t)N*64*2);
    u16* tA = (u16*)alloc((size_t)N*64*2);
    u16* tB = (u16*)alloc((size_t)N*64*2);
    u16* X2 = (u16*)d_in[1];
    u16* X3 = (u16*)d_out;
    const u16* XP[4] = {X0, X1, X2, X3};

    float* h3   = (float*)X1;
    float* r3   = (float*)(X1 + (size_t)N*32);
    float* agg3 = (float*)tA;
    float* x4   = (float*)(tA + (size_t)N*32);
    float* h4   = (float*)X0;
    float* agg4 = (float*)tA;

    for (int tau=0; tau<4; ++tau){
      u16* Xt = (u16*)XP[tau];
      k_gemm64<float><<<gemmGrid,256,0,stream>>>(x, x+64, x+128, x+192, 256,
                                                 W1t + (size_t)tau*64*256, nullptr, tA, N);
      k_gather64<<<nodeGrid,256,0,stream>>>(tA, offs, csr, dinv, b1 + tau*64, N, tB);
      k_stats_part<u16,64><<<statsGrid,256,0,stream>>>(tB, N, part);
      k_bnfin3<64><<<2,256,0,stream>>>(part, statsGrid, g1 + tau*64, be1 + tau*64, (float)N, bnp1 + tau*128);
      k_gemm64<float><<<gemmGrid,256,0,stream>>>(x, x+64, x+128, x+192, 256,
                                                 r1Wt + (size_t)tau*64*256, r1b + tau*64, tA, N);
      k_ew_b16b16<<<cdiv(N*64,256),256,0,stream>>>(tB, tA, bnp1 + tau*128, 64, N*64, Xt);
    }

    for (int head=0; head<4; ++head){
      k_gemm64<u16><<<gemmGrid,256,0,stream>>>(XP[0], XP[1], XP[2], XP[3], 64,
                                               Wgt + (size_t)head*64*256, nullptr, tA, N);
      k_dot64<<<nodeGrid,256,0,stream>>>(tA, a_s + head*64, a_d + head*64, head, N, als, ald);
      k_gat_head<<<nodeGrid,256,0,stream>>>(tA, offs, csr, als, ald, bg, head, N, tB);
    }
    k_gemm64<u16><<<gemmGrid,256,0,stream>>>(XP[0], XP[1], XP[2], XP[3], 64,
                                             r2Wt, r2b, tA, N);
    k_stats_part<u16,64><<<statsGrid,256,0,stream>>>(tB, N, part);
    k_bnfin3<64><<<2,256,0,stream>>>(part, statsGrid, g2, be2, (float)N, bnp2);
    k_ew_b16b16<<<cdiv(N*64,256),256,0,stream>>>(tB, tA, bnp2, 64, N*64, X0);

    k_gemm64_16x2<<<cdiv(N,8),256,0,stream>>>(X0, W3, r3W, r3b, N, h3, r3);
    k_gcn_agg16<<<cdiv(N,16),256,0,stream>>>(h3, offs, csr, dinv, b3, agg3, N);
    k_stats_part<float,16><<<statsGrid,256,0,stream>>>(agg3, N, part);
    k_bnfin3<16><<<1,256,0,stream>>>(part, statsGrid, g3, be3, (float)N, bnp3);
    k_ew_f32f32<<<cdiv(N*16,256),256,0,stream>>>(agg3, r3, bnp3, 16, N*16, x4);

    k_gemm16_64<<<nodeGrid,256,0,stream>>>(x4, W4, N, h4);
    k_gcn_agg64f<<<nodeGrid,256,0,stream>>>(h4, offs, csr, dinv, b4, agg4, N);
    k_final<<<nodeGrid,256,0,stream>>>(agg4, pW, pb, N, (float*)d_out);
  }
}

// Round 8
// 701.260 us; speedup vs baseline: 1.9882x; 1.0380x over previous
//
#include <hip/hip_runtime.h>

typedef unsigned short u16;
typedef unsigned int   u32;

// ---------- bf16 helpers ----------
__device__ __forceinline__ float b2f(u16 h){ return __uint_as_float(((u32)h)<<16); }
__device__ __forceinline__ u16 f2b(float f){
  u32 u = __float_as_uint(f);
  u32 r = (u + 0x7fffu + ((u>>16)&1u)) >> 16;   // RNE
  return (u16)r;
}
__device__ __forceinline__ float leaky(float x, float s){ return x >= 0.f ? x : s*x; }

typedef __bf16 bf16x8 __attribute__((ext_vector_type(8)));
typedef float  f32x4  __attribute__((ext_vector_type(4)));

__device__ __forceinline__ float ldval(const u16* p){ return b2f(*p); }
__device__ __forceinline__ float ldval(const float* p){ return *p; }

__device__ __forceinline__ void load8(const u16* p, u16* h){ *(uint4*)h = *(const uint4*)p; }
__device__ __forceinline__ void load8(const float* p, u16* h){
  float4 a = *(const float4*)p; float4 b = *(const float4*)(p+4);
  h[0]=f2b(a.x); h[1]=f2b(a.y); h[2]=f2b(a.z); h[3]=f2b(a.w);
  h[4]=f2b(b.x); h[5]=f2b(b.y); h[6]=f2b(b.z); h[7]=f2b(b.w);
}

// ---------- int64-vs-int32 detection ----------
__global__ void k_detect(const u32* __restrict__ w, int E, u32* __restrict__ flag){
  u32 acc = 0;
  for (int i = blockIdx.x*256 + threadIdx.x; i < E; i += 256*gridDim.x)
    acc |= w[2*i + 1];
  __shared__ u32 s[256];
  s[threadIdx.x] = acc; __syncthreads();
  for (int o=128;o>0;o>>=1){ if (threadIdx.x<o) s[threadIdx.x] |= s[threadIdx.x+o]; __syncthreads(); }
  if (threadIdx.x==0 && s[0]) atomicOr(flag, 1u);
}

__device__ __forceinline__ void edge_sd(const int* __restrict__ ei, int E, int e, u32 is32,
                                        int& s, int& d){
  if (is32){ s = ei[e];   d = ei[E + e]; }
  else     { s = ei[2*e]; d = ei[2*E + 2*e]; }
}

// ---------- CSR build ----------
__global__ void k_hist(const int* __restrict__ ei, int E, int nN,
                       const u32* __restrict__ flag, int* __restrict__ cnt){
  int e = blockIdx.x*256 + threadIdx.x;
  if (e < E){
    int s,d; edge_sd(ei, E, e, *flag, s, d);
    if ((u32)s < (u32)nN && (u32)d < (u32)nN) atomicAdd(&cnt[d], 1);
  }
}

__global__ void k_scan_a(const int* __restrict__ cnt, int n, int* __restrict__ bsum){
  __shared__ int s[256];
  int base = blockIdx.x*1024, t = threadIdx.x, sum = 0;
  for (int j=0;j<4;j++){ int i = base + t*4 + j; if (i<n) sum += cnt[i]; }
  s[t] = sum; __syncthreads();
  for (int off=128; off>0; off>>=1){ if (t<off) s[t]+=s[t+off]; __syncthreads(); }
  if (t==0) bsum[blockIdx.x] = s[0];
}

__global__ void k_scan_b(int* bsum, int nb){
  if (threadIdx.x==0 && blockIdx.x==0){
    int acc = 0;
    for (int i=0;i<nb;i++){ int v = bsum[i]; bsum[i] = acc; acc += v; }
  }
}

__global__ void k_scan_c(const int* __restrict__ cnt, const int* __restrict__ bsum,
                         int n, int* __restrict__ offs){
  __shared__ int s[256];
  int base = blockIdx.x*1024, t = threadIdx.x;
  int v[4]; int sum=0;
  for (int j=0;j<4;j++){ int i=base+t*4+j; v[j] = (i<n)?cnt[i]:0; sum += v[j]; }
  s[t]=sum; __syncthreads();
  for (int off=1; off<256; off<<=1){
    int add = (t>=off)? s[t-off] : 0;
    __syncthreads();
    s[t] += add;
    __syncthreads();
  }
  int excl = (t ? s[t-1] : 0) + bsum[blockIdx.x];
  for (int j=0;j<4;j++){
    int i = base+t*4+j;
    if (i<n){ offs[i] = excl; excl += v[j]; if (i==n-1) offs[n] = excl; }
  }
}

__global__ void k_dinv2(const int* __restrict__ offs, int n, float* __restrict__ dinv){
  int i = blockIdx.x*256+threadIdx.x;
  if (i<n) dinv[i] = rsqrtf((float)(offs[i+1]-offs[i]) + 1.0f);
}

__global__ void k_scatter(const int* __restrict__ ei, int E, int nN,
                          const u32* __restrict__ flag, const int* __restrict__ offs,
                          int* __restrict__ cursor, int* __restrict__ csr){
  int e = blockIdx.x*256+threadIdx.x;
  if (e<E){
    int s,d; edge_sd(ei, E, e, *flag, s, d);
    if ((u32)s < (u32)nN && (u32)d < (u32)nN){
      int pos = offs[d] + atomicAdd(&cursor[d], 1);
      csr[pos] = s;
    }
  }
}

// ---------- transpose+convert: f32 (K x M) -> bf16 (M x K) ----------
__global__ void k_transpose(const float* __restrict__ in, u16* __restrict__ out, int K, int M){
  int i = blockIdx.x*256 + threadIdx.x;
  if (i < K*M){ int k = i / M, m = i % M; out[m*K + k] = f2b(in[i]); }
}

// interleave attention vectors: asi[c*4+h] = a_s[h*64+c]
__global__ void k_asdt(const float* __restrict__ a_s, const float* __restrict__ a_d,
                       float* __restrict__ asi, float* __restrict__ adi){
  int i = threadIdx.x;
  int h = i>>6, c = i&63;
  asi[c*4+h] = a_s[i];
  adi[c*4+h] = a_d[i];
}

// ---------- MFMA GEMM, M=64 (col-sliced waves: B read ONCE per block) ----------
template<typename AT>
__global__ __launch_bounds__(256) void k_gemm64(
  const AT* __restrict__ A0, const AT* __restrict__ A1,
  const AT* __restrict__ A2, const AT* __restrict__ A3,
  int rsA, const u16* __restrict__ Bt, const float* __restrict__ bias,
  u16* __restrict__ out, int nRows)
{
  alignas(16) __shared__ u16 Al[64*264];   // A staging, then reused as output tile
  const int t = threadIdx.x;
  const int r0 = blockIdx.x*64;
  for (int it=0; it<8; ++it){
    int c = t + it*256;
    int row = c>>5, seg = c&31;
    int gr = r0+row;
    u16 hv[8] = {0,0,0,0,0,0,0,0};
    if (gr < nRows){
      const AT* p = (seg<8)?A0 : (seg<16)?A1 : (seg<24)?A2 : A3;
      load8(p + (size_t)gr*rsA + (seg&7)*8, hv);
    }
    *(uint4*)&Al[row*264 + seg*8] = *(uint4*)hv;
  }
  const int lane=t&63, wid=t>>6, quad=lane>>4, l15=lane&15;
  __syncthreads();
  const int col = wid*16 + l15;
  const u16* Bp = Bt + (size_t)col*256 + quad*8;
  bf16x8 b[8];
  #pragma unroll
  for (int ks=0;ks<8;++ks) b[ks] = *(const bf16x8*)(Bp + ks*32);
  f32x4 acc[4] = {{0.f,0.f,0.f,0.f},{0.f,0.f,0.f,0.f},{0.f,0.f,0.f,0.f},{0.f,0.f,0.f,0.f}};
  #pragma unroll
  for (int rt=0; rt<4; ++rt){
    const int abase = (rt*16 + l15)*264 + quad*8;
    #pragma unroll
    for (int ks=0;ks<8;++ks){
      bf16x8 av = *(const bf16x8*)&Al[abase + ks*32];
      acc[rt] = __builtin_amdgcn_mfma_f32_16x16x32_bf16(av, b[ks], acc[rt], 0,0,0);
    }
  }
  __syncthreads();
  float bv = bias ? bias[col] : 0.f;
  #pragma unroll
  for (int rt=0; rt<4; ++rt){
    #pragma unroll
    for (int reg=0;reg<4;++reg)
      Al[(rt*16 + quad*4 + reg)*264 + col] = f2b(acc[rt][reg]+bv);
  }
  __syncthreads();
  #pragma unroll
  for (int it=0; it<2; ++it){
    int idx = it*256 + t;
    int row = idx>>3, cu = idx&7;
    if (r0+row < nRows)
      *(uint4*)(out + (size_t)(r0+row)*64 + cu*8) = *(const uint4*)&Al[row*264 + cu*8];
  }
}

// ---------- MFMA GEMM, M=256 (col-sliced waves; fused EW / DOT / row-scale) ----------
// EW:  out = leaky(agg*bnp_sc + bnp_sh) + (acc+bias)
// DOT: after epilogue, compute per-node attention dots from the interleaved LDS tile
// RS:  scale output rows by rowscale[r] (pre-applied dinv for downstream gathers)
template<typename AT, bool PERM, bool EW, bool DOT, bool RS>
__global__ __launch_bounds__(256) void k_gemm256(
  const AT* __restrict__ A0, const AT* __restrict__ A1,
  const AT* __restrict__ A2, const AT* __restrict__ A3,
  int rsA, const u16* __restrict__ Bt, const float* __restrict__ bias,
  const u16* __restrict__ agg, const float* __restrict__ bnp,
  const float* __restrict__ asi, const float* __restrict__ adi,
  float* __restrict__ als, float* __restrict__ ald,
  const float* __restrict__ rowscale,
  u16* __restrict__ out, int nRows)
{
  alignas(16) __shared__ u16 Al[64*264];   // A staging, then reused as output tile
  const int t = threadIdx.x;
  const int r0 = blockIdx.x*64;
  for (int it=0; it<8; ++it){
    int c = t + it*256;
    int row = c>>5, seg = c&31;
    int gr = r0+row;
    u16 hv[8] = {0,0,0,0,0,0,0,0};
    if (gr < nRows){
      const AT* p = (seg<8)?A0 : (seg<16)?A1 : (seg<24)?A2 : A3;
      load8(p + (size_t)gr*rsA + (seg&7)*8, hv);
    }
    *(uint4*)&Al[row*264 + seg*8] = *(uint4*)hv;
  }
  const int lane=t&63, wid=t>>6, quad=lane>>4, l15=lane&15;
  __syncthreads();
  f32x4 acc[4][4];   // [ct][rt]
  #pragma unroll
  for (int ct=0; ct<4; ++ct)
    #pragma unroll
    for (int rt=0; rt<4; ++rt) acc[ct][rt] = {0.f,0.f,0.f,0.f};
  #pragma unroll
  for (int ct=0; ct<4; ++ct){
    const u16* Bp = Bt + (size_t)(wid*64 + ct*16 + l15)*256 + quad*8;
    bf16x8 b[8];
    #pragma unroll
    for (int ks=0;ks<8;++ks) b[ks] = *(const bf16x8*)(Bp + ks*32);
    #pragma unroll
    for (int rt=0; rt<4; ++rt){
      const int abase = (rt*16 + l15)*264 + quad*8;
      #pragma unroll
      for (int ks=0;ks<8;++ks){
        bf16x8 av = *(const bf16x8*)&Al[abase + ks*32];
        acc[ct][rt] = __builtin_amdgcn_mfma_f32_16x16x32_bf16(av, b[ks], acc[ct][rt], 0,0,0);
      }
    }
  }
  __syncthreads();   // all waves done reading Al before epilogue overwrite
  float rsv[4][4];
  if constexpr (RS){
    #pragma unroll
    for (int rt=0; rt<4; ++rt)
      #pragma unroll
      for (int reg=0; reg<4; ++reg){
        int r = r0 + rt*16 + quad*4 + reg;
        rsv[rt][reg] = (r < nRows) ? rowscale[r] : 1.f;
      }
  }
  #pragma unroll
  for (int ct=0; ct<4; ++ct){
    int col = wid*64 + ct*16 + l15;
    float bv = bias ? bias[col] : 0.f;
    int oc = PERM ? ((col&63)*4 + (col>>6)) : col;
    #pragma unroll
    for (int rt=0; rt<4; ++rt){
      #pragma unroll
      for (int reg=0;reg<4;++reg){
        float v = acc[ct][rt][reg] + bv;
        if constexpr (RS) v *= rsv[rt][reg];
        Al[(rt*16 + quad*4 + reg)*264 + oc] = f2b(v);
      }
    }
  }
  __syncthreads();
  if constexpr (DOT){
    // 4 threads per row, 64 interleaved entries each; entry ii -> head ii&3
    int row = t>>2, q = t&3;
    int nd = r0 + row;
    if (nd < nRows){
      float s0=0.f,s1=0.f,s2=0.f,s3=0.f,d0=0.f,d1=0.f,d2=0.f,d3=0.f;
      const u16* ar = &Al[row*264 + q*64];
      const float* as = asi + q*64;
      const float* ad = adi + q*64;
      #pragma unroll 4
      for (int k=0;k<64;k+=4){
        uint2 wv = *(const uint2*)&ar[k];
        float v0=b2f((u16)(wv.x&0xffff)), v1=b2f((u16)(wv.x>>16));
        float v2=b2f((u16)(wv.y&0xffff)), v3=b2f((u16)(wv.y>>16));
        s0 += v0*as[k];   d0 += v0*ad[k];
        s1 += v1*as[k+1]; d1 += v1*ad[k+1];
        s2 += v2*as[k+2]; d2 += v2*ad[k+2];
        s3 += v3*as[k+3]; d3 += v3*ad[k+3];
      }
      s0 += __shfl_xor(s0,1,64); s0 += __shfl_xor(s0,2,64);
      s1 += __shfl_xor(s1,1,64); s1 += __shfl_xor(s1,2,64);
      s2 += __shfl_xor(s2,1,64); s2 += __shfl_xor(s2,2,64);
      s3 += __shfl_xor(s3,1,64); s3 += __shfl_xor(s3,2,64);
      d0 += __shfl_xor(d0,1,64); d0 += __shfl_xor(d0,2,64);
      d1 += __shfl_xor(d1,1,64); d1 += __shfl_xor(d1,2,64);
      d2 += __shfl_xor(d2,1,64); d2 += __shfl_xor(d2,2,64);
      d3 += __shfl_xor(d3,1,64); d3 += __shfl_xor(d3,2,64);
      if (q==0){
        float4 sv = {s0,s1,s2,s3}; float4 dv = {d0,d1,d2,d3};
        ((float4*)als)[nd] = sv;
        ((float4*)ald)[nd] = dv;
      }
    }
  }
  #pragma unroll
  for (int it=0; it<8; ++it){
    int idx = it*256 + t;
    int row = idx>>5, cu = idx&31;
    int r = r0+row;
    if (r < nRows){
      if constexpr (EW){
        uint4 hv = *(const uint4*)&Al[row*264 + cu*8];
        uint4 av = *(const uint4*)(agg + (size_t)r*256 + cu*8);
        const u16* hp = (const u16*)&hv; const u16* ap = (const u16*)&av;
        uint4 ov; u16* op = (u16*)&ov;
        #pragma unroll
        for (int j=0;j<8;++j){
          int c = cu*8+j;
          float v = b2f(ap[j])*bnp[c] + bnp[256+c];
          op[j] = f2b(leaky(v, 0.01f) + b2f(hp[j]));
        }
        *(uint4*)(out + (size_t)r*256 + cu*8) = ov;
      } else {
        *(uint4*)(out + (size_t)r*256 + cu*8) = *(const uint4*)&Al[row*264 + cu*8];
      }
    }
  }
}

// ---------- GCN gather, 64 channels (fallback path; h unscaled, uses dinv[s]) ----------
__global__ void k_gather64(const u16* __restrict__ h, const int* __restrict__ offs,
                           const int* __restrict__ csr, const float* __restrict__ dinv,
                           const float* __restrict__ bias, int n, u16* __restrict__ out){
  int nd = blockIdx.x*4 + (threadIdx.x>>6);
  if (nd>=n) return;
  int lane = threadIdx.x&63;
  float dn = dinv[nd];
  float acc = dn*b2f(h[(size_t)nd*64+lane]);
  int e = offs[nd], end = offs[nd+1];
  for (; e+4<=end; e+=4){
    int s0=csr[e], s1=csr[e+1], s2=csr[e+2], s3=csr[e+3];
    float w0=dinv[s0], w1=dinv[s1], w2=dinv[s2], w3=dinv[s3];
    float p0=b2f(h[(size_t)s0*64+lane]);
    float p1=b2f(h[(size_t)s1*64+lane]);
    float p2=b2f(h[(size_t)s2*64+lane]);
    float p3=b2f(h[(size_t)s3*64+lane]);
    acc += w0*p0 + w1*p1 + w2*p2 + w3*p3;
  }
  for (; e<end; ++e){
    int s=csr[e];
    acc += dinv[s]*b2f(h[(size_t)s*64+lane]);
  }
  out[(size_t)nd*64+lane] = f2b(dn*acc + bias[lane]);
}

// ---------- GCN gather, 256 channels (h pre-scaled by dinv; 4-deep unroll) ----------
__global__ void k_gather256(const u16* __restrict__ h, const int* __restrict__ offs,
                            const int* __restrict__ csr, const float* __restrict__ dinv,
                            const float* __restrict__ bias, int n, u16* __restrict__ out){
  int nd = blockIdx.x*4 + (threadIdx.x>>6);
  if (nd>=n) return;
  int lane = threadIdx.x&63;
  const uint2* H = (const uint2*)h;
  float dn = dinv[nd];
  uint2 pv = H[(size_t)nd*64 + lane];        // self term: h'[d] = dinv[d]*h[d]
  float a0=b2f(pv.x&0xffff), a1=b2f(pv.x>>16);
  float a2=b2f(pv.y&0xffff), a3=b2f(pv.y>>16);
  int e=offs[nd], end=offs[nd+1];
  for (; e+4<=end; e+=4){
    int s0=csr[e], s1=csr[e+1], s2=csr[e+2], s3=csr[e+3];
    uint2 q0=H[(size_t)s0*64+lane], q1=H[(size_t)s1*64+lane];
    uint2 q2=H[(size_t)s2*64+lane], q3=H[(size_t)s3*64+lane];
    a0 += b2f(q0.x&0xffff) + b2f(q1.x&0xffff) + b2f(q2.x&0xffff) + b2f(q3.x&0xffff);
    a1 += b2f(q0.x>>16)    + b2f(q1.x>>16)    + b2f(q2.x>>16)    + b2f(q3.x>>16);
    a2 += b2f(q0.y&0xffff) + b2f(q1.y&0xffff) + b2f(q2.y&0xffff) + b2f(q3.y&0xffff);
    a3 += b2f(q0.y>>16)    + b2f(q1.y>>16)    + b2f(q2.y>>16)    + b2f(q3.y>>16);
  }
  for (; e<end; ++e){
    int s=csr[e];
    uint2 q=H[(size_t)s*64+lane];
    a0 += b2f(q.x&0xffff); a1 += b2f(q.x>>16);
    a2 += b2f(q.y&0xffff); a3 += b2f(q.y>>16);
  }
  float4 bv = *(const float4*)(bias + lane*4);
  uint2 o;
  o.x = (u32)f2b(a0*dn + bv.x) | ((u32)f2b(a1*dn + bv.y)<<16);
  o.y = (u32)f2b(a2*dn + bv.z) | ((u32)f2b(a3*dn + bv.w)<<16);
  ((uint2*)out)[(size_t)nd*64 + lane] = o;
}

// ---------- BN stats partials, vectorized (16B loads, reg partials, LDS tree) ----------
template<typename T, int C>
__global__ __launch_bounds__(256) void k_stats_part(const T* __restrict__ x, int n,
                                                    float* __restrict__ part){
  constexpr int VE = 16/sizeof(T);   // elems per 16B load: 8 (bf16) / 4 (f32)
  constexpr int G  = C/VE;           // vec-groups per row
  constexpr int R  = 256/G;          // rows covered per block pass
  int t = threadIdx.x;
  int g = t % G, sub = t / G;
  int rpb = (n + gridDim.x - 1) / gridDim.x;
  int base = blockIdx.x * rpb;
  int lim  = min(base + rpb, n);
  float s[VE], s2[VE];
  #pragma unroll
  for (int j=0;j<VE;j++){ s[j]=0.f; s2[j]=0.f; }
  #pragma unroll 4
  for (int r = base + sub; r < lim; r += R){
    const T* p = x + (size_t)r*C + g*VE;
    if constexpr (sizeof(T)==2){
      uint4 v = *(const uint4*)p;
      u32 wq[4] = {v.x, v.y, v.z, v.w};
      #pragma unroll
      for (int q=0;q<4;q++){
        float lo = __uint_as_float(wq[q]<<16);
        float hi = __uint_as_float(wq[q]&0xffff0000u);
        s[2*q]  += lo; s2[2*q]  += lo*lo;
        s[2*q+1]+= hi; s2[2*q+1]+= hi*hi;
      }
    } else {
      float4 v = *(const float4*)p;
      float a[4] = {v.x, v.y, v.z, v.w};
      #pragma unroll
      for (int q=0;q<4;q++){ s[q]+=a[q]; s2[q]+=a[q]*a[q]; }
    }
  }
  __shared__ float red[VE][256];
  #pragma unroll
  for (int j=0;j<VE;j++) red[j][t] = s[j];
  __syncthreads();
  for (int off=R/2; off>0; off>>=1){
    if (sub < off){
      #pragma unroll
      for (int j=0;j<VE;j++) red[j][t] += red[j][t + off*G];
    }
    __syncthreads();
  }
  if (t < G){
    #pragma unroll
    for (int j=0;j<VE;j++) part[blockIdx.x*2*C + t*VE + j] = red[j][t];
  }
  __syncthreads();
  #pragma unroll
  for (int j=0;j<VE;j++) red[j][t] = s2[j];
  __syncthreads();
  for (int off=R/2; off>0; off>>=1){
    if (sub < off){
      #pragma unroll
      for (int j=0;j<VE;j++) red[j][t] += red[j][t + off*G];
    }
    __syncthreads();
  }
  if (t < G){
    #pragma unroll
    for (int j=0;j<VE;j++) part[blockIdx.x*2*C + C + t*VE + j] = red[j][t];
  }
}

// ---------- BN finalize: channel-parallel multi-block (32 ch/block, 8 thr/ch) ----------
template<int C>
__global__ __launch_bounds__(256) void k_bnfin3(const float* __restrict__ part, int B,
                         const float* __restrict__ g, const float* __restrict__ be,
                         float n, float* __restrict__ bnp){
  constexpr int CPB = (C < 32) ? C : 32;   // channels per block
  constexpr int TPC = 256 / CPB;           // threads per channel
  int t = threadIdx.x;
  int lc = t % CPB, sub = t / CPB;
  int c = blockIdx.x*CPB + lc;
  float s=0.f, s2=0.f;
  for (int b = sub; b < B; b += TPC){
    s  += part[(size_t)b*2*C + c];
    s2 += part[(size_t)b*2*C + C + c];
  }
  __shared__ float ls[256], lq[256];
  ls[t]=s; lq[t]=s2; __syncthreads();
  for (int off=TPC/2; off>0; off>>=1){
    if (sub < off){ ls[t]+=ls[t+off*CPB]; lq[t]+=lq[t+off*CPB]; }
    __syncthreads();
  }
  if (sub==0){
    float mu = ls[t]/n;
    float var = fmaxf(lq[t]/n - mu*mu, 0.f);
    float sc = g[c] * rsqrtf(var + 1e-5f);
    bnp[c] = sc;
    bnp[C+c] = be[c] - mu*sc;
  }
}

// ---------- elementwise BN+leaky+residual ----------
__global__ void k_ew_b16b16(const u16* __restrict__ agg, const u16* __restrict__ res,
                            const float* __restrict__ bnp, int C, int total, u16* __restrict__ out){
  int i = blockIdx.x*256+threadIdx.x;
  if (i < total){
    int c = i & (C-1);
    float v = b2f(agg[i])*bnp[c] + bnp[C+c];
    out[i] = f2b(leaky(v, 0.01f) + b2f(res[i]));
  }
}

__global__ void k_ew_f32f32(const float* __restrict__ agg, const float* __restrict__ res,
                            const float* __restrict__ bnp, int C, int total, float* __restrict__ out){
  int i = blockIdx.x*256+threadIdx.x;
  if (i < total){
    int c = i & (C-1);
    float v = agg[i]*bnp[c] + bnp[C+c];
    out[i] = leaky(v, 0.01f) + res[i];
  }
}

// ---------- GAT fallback: per-head logit dot ----------
__global__ void k_dot64(const u16* __restrict__ h2t, const float* __restrict__ asg,
                        const float* __restrict__ adg, int head, int n,
                        float* __restrict__ als, float* __restrict__ ald){
  int nd = blockIdx.x*4 + (threadIdx.x>>6);
  if (nd>=n) return;
  int lane = threadIdx.x&63;
  float p = b2f(h2t[(size_t)nd*64+lane]);
  float ss = p*asg[lane];
  float sd = p*adg[lane];
  for (int m=1;m<64;m<<=1){ ss += __shfl_xor(ss,m,64); sd += __shfl_xor(sd,m,64); }
  if (lane==0){ als[nd*4+head]=ss; ald[nd*4+head]=sd; }
}

// ---------- GAT fallback: per-head softmax gather (online softmax) ----------
__global__ void k_gat_head(const u16* __restrict__ h2t, const int* __restrict__ offs,
                           const int* __restrict__ csr, const float* __restrict__ als,
                           const float* __restrict__ ald, const float* __restrict__ bg,
                           int head, int n, u16* __restrict__ O2){
  int nd = blockIdx.x*4 + (threadIdx.x>>6);
  if (nd>=n) return;
  int lane = threadIdx.x&63;
  float aldn = ald[nd*4+head];
  float m = leaky(als[nd*4+head] + aldn, 0.2f);
  float denom = 1.f;
  float acc = b2f(h2t[(size_t)nd*64+lane]);
  int e = offs[nd], end = offs[nd+1];
  for (; e+4<=end; e+=4){
    int s0=csr[e], s1=csr[e+1], s2=csr[e+2], s3=csr[e+3];
    float l0=als[s0*4+head], l1=als[s1*4+head], l2=als[s2*4+head], l3=als[s3*4+head];
    float p0=b2f(h2t[(size_t)s0*64+lane]);
    float p1=b2f(h2t[(size_t)s1*64+lane]);
    float p2=b2f(h2t[(size_t)s2*64+lane]);
    float p3=b2f(h2t[(size_t)s3*64+lane]);
    float g0=leaky(l0+aldn,0.2f), g1=leaky(l1+aldn,0.2f);
    float g2=leaky(l2+aldn,0.2f), g3=leaky(l3+aldn,0.2f);
    float mc = fmaxf(fmaxf(g0,g1), fmaxf(g2,g3));
    float mn = fmaxf(m, mc);
    float sc = __expf(m - mn);
    float w0 = __expf(g0-mn), w1 = __expf(g1-mn), w2 = __expf(g2-mn), w3 = __expf(g3-mn);
    denom = denom*sc + (w0+w1+w2+w3);
    acc   = acc*sc   + (w0*p0 + w1*p1 + w2*p2 + w3*p3);
    m = mn;
  }
  for (; e<end; ++e){
    int s = csr[e];
    float g = leaky(als[s*4+head]+aldn, 0.2f);
    float p = b2f(h2t[(size_t)s*64+lane]);
    float mn = fmaxf(m, g);
    float sc = __expf(m - mn);
    float w = __expf(g - mn);
    denom = denom*sc + w;
    acc   = acc*sc   + w*p;
    m = mn;
  }
  float v = 0.25f * acc / fmaxf(denom, 1e-20f);
  size_t oi = (size_t)nd*64+lane;
  if (head==0) O2[oi] = f2b(v + bg[lane]);
  else         O2[oi] = f2b(b2f(O2[oi]) + v);
}

// ---------- GAT big path: fused, distributed weights via intra-wave LDS ----------
__global__ void k_gat_all(const u16* __restrict__ h2i, const int* __restrict__ offs,
                          const int* __restrict__ csr, const float* __restrict__ als,
                          const float* __restrict__ ald, const float* __restrict__ bg,
                          int n, u16* __restrict__ O2){
  alignas(16) __shared__ float shm[4][80];  // per wave: [0..3] denoms, [4..7] self-w, [8..71] edge wts
  int wv = threadIdx.x>>6;
  int nd = blockIdx.x*4 + wv;
  if (nd>=n) return;
  int lane = threadIdx.x&63;
  int eg = lane>>2, hh = lane&3;
  float4 alv = ((const float4*)als)[nd];
  float4 adv = ((const float4*)ald)[nd];
  float adh = (hh&2) ? ((hh&1)?adv.w:adv.z) : ((hh&1)?adv.y:adv.x);
  float alh = (hh&2) ? ((hh&1)?alv.w:alv.z) : ((hh&1)?alv.y:alv.x);
  float gsh = leaky(alh+adh, 0.2f);
  int beg=offs[nd], end=offs[nd+1];
  // pass 1: distributed per-head max (incl. self)
  float m = gsh;
  for (int e=beg+eg; e<end; e+=16){
    int s = csr[e];
    m = fmaxf(m, leaky(als[s*4+hh]+adh, 0.2f));
  }
  #pragma unroll
  for (int off=4; off<64; off<<=1) m = fmaxf(m, __shfl_xor(m, off, 64));
  float wsh = __expf(gsh - m);
  if (eg==0) shm[wv][4+hh] = wsh;
  float4 ws4 = *(const float4*)&shm[wv][4];
  uint2 pv = ((const uint2*)h2i)[(size_t)nd*64+lane];
  float a0 = ws4.x*__uint_as_float(pv.x<<16);
  float a1 = ws4.y*__uint_as_float(pv.x&0xffff0000u);
  float a2 = ws4.z*__uint_as_float(pv.y<<16);
  float a3 = ws4.w*__uint_as_float(pv.y&0xffff0000u);
  float dpart = 0.f;
  const uint2* H = (const uint2*)h2i;
  // pass 2: chunks of 16 edges; phase A computes 64 weights (1 exp/lane),
  // phase B does the all-lane weighted gather with LDS-broadcast weights
  for (int e0=beg; e0<end; e0+=16){
    int e = e0+eg;
    int sA = 0; float wE = 0.f;
    if (e<end){
      sA = csr[e];
      wE = __expf(leaky(als[sA*4+hh]+adh, 0.2f) - m);
    }
    dpart += wE;
    shm[wv][8+lane] = wE;
    int cnt = min(16, end-e0);
    int k=0;
    for (; k+4<=cnt; k+=4){
      int sa=__shfl(sA,(k  )*4,64), sb=__shfl(sA,(k+1)*4,64);
      int sc=__shfl(sA,(k+2)*4,64), sd=__shfl(sA,(k+3)*4,64);
      float4 wa=*(const float4*)&shm[wv][8+(k  )*4];
      float4 wb=*(const float4*)&shm[wv][8+(k+1)*4];
      float4 wc=*(const float4*)&shm[wv][8+(k+2)*4];
      float4 wd=*(const float4*)&shm[wv][8+(k+3)*4];
      uint2 qa=H[(size_t)sa*64+lane], qb=H[(size_t)sb*64+lane];
      uint2 qc=H[(size_t)sc*64+lane], qd=H[(size_t)sd*64+lane];
      a0 += wa.x*__uint_as_float(qa.x<<16) + wb.x*__uint_as_float(qb.x<<16)
          + wc.x*__uint_as_float(qc.x<<16) + wd.x*__uint_as_float(qd.x<<16);
      a1 += wa.y*__uint_as_float(qa.x&0xffff0000u) + wb.y*__uint_as_float(qb.x&0xffff0000u)
          + wc.y*__uint_as_float(qc.x&0xffff0000u) + wd.y*__uint_as_float(qd.x&0xffff0000u);
      a2 += wa.z*__uint_as_float(qa.y<<16) + wb.z*__uint_as_float(qb.y<<16)
          + wc.z*__uint_as_float(qc.y<<16) + wd.z*__uint_as_float(qd.y<<16);
      a3 += wa.w*__uint_as_float(qa.y&0xffff0000u) + wb.w*__uint_as_float(qb.y&0xffff0000u)
          + wc.w*__uint_as_float(qc.y&0xffff0000u) + wd.w*__uint_as_float(qd.y&0xffff0000u);
    }
    for (; k<cnt; ++k){
      int s = __shfl(sA, k*4, 64);
      float4 w4 = *(const float4*)&shm[wv][8+k*4];
      uint2 q = H[(size_t)s*64+lane];
      a0 += w4.x*__uint_as_float(q.x<<16);
      a1 += w4.y*__uint_as_float(q.x&0xffff0000u);
      a2 += w4.z*__uint_as_float(q.y<<16);
      a3 += w4.w*__uint_as_float(q.y&0xffff0000u);
    }
  }
  #pragma unroll
  for (int off=4; off<64; off<<=1) dpart += __shfl_xor(dpart, off, 64);
  float dh = dpart + wsh;
  if (eg==0) shm[wv][hh] = dh;
  float4 d4 = *(const float4*)&shm[wv][0];
  float v = 0.25f*(a0/d4.x + a1/d4.y + a2/d4.z + a3/d4.w);
  O2[(size_t)nd*64+lane] = f2b(v + bg[lane]);
}

// ---------- GCN aggregation, C=16, f32 (h pre-scaled by dinv) ----------
__global__ void k_gcn_agg16(const float* __restrict__ h, const int* __restrict__ offs,
                            const int* __restrict__ csr, const float* __restrict__ dinv,
                            const float* __restrict__ bias, float* __restrict__ out, int n){
  int t = threadIdx.x;
  int nd = blockIdx.x*16 + (t>>4);
  if (nd>=n) return;
  int c = t&15;
  float dn = dinv[nd];
  float acc = h[(size_t)nd*16+c];          // self term: h'[d]
  int e=offs[nd], end=offs[nd+1];
  for (; e+4<=end; e+=4){
    int s0=csr[e], s1=csr[e+1], s2=csr[e+2], s3=csr[e+3];
    acc += h[(size_t)s0*16+c] + h[(size_t)s1*16+c]
         + h[(size_t)s2*16+c] + h[(size_t)s3*16+c];
  }
  for (; e<end; ++e){
    int s = csr[e];
    acc += h[(size_t)s*16+c];
  }
  out[(size_t)nd*16+c] = dn*acc + bias[c];
}

// ---------- GCN aggregation, C=64, f32 (h pre-scaled by dinv; 4-deep) ----------
__global__ void k_gcn_agg64f(const float* __restrict__ h, const int* __restrict__ offs,
                             const int* __restrict__ csr, const float* __restrict__ dinv,
                             const float* __restrict__ bias, float* __restrict__ out, int n){
  int nd = blockIdx.x*4 + (threadIdx.x>>6);
  if (nd>=n) return;
  int lane = threadIdx.x&63;
  float dn = dinv[nd];
  float acc = h[(size_t)nd*64+lane];       // self term: h'[d]
  int e=offs[nd], end=offs[nd+1];
  for (; e+4<=end; e+=4){
    int s0=csr[e], s1=csr[e+1], s2=csr[e+2], s3=csr[e+3];
    acc += h[(size_t)s0*64+lane] + h[(size_t)s1*64+lane]
         + h[(size_t)s2*64+lane] + h[(size_t)s3*64+lane];
  }
  for (; e<end; ++e){
    int s=csr[e];
    acc += h[(size_t)s*64+lane];
  }
  out[(size_t)nd*64+lane] = dn*acc + bias[lane];
}

// ---------- small VALU GEMMs ----------
// o1 (h3) is pre-scaled by dinv for the downstream aggregation; o2 (r3) is not.
__global__ void k_gemm64_16x2(const u16* __restrict__ x, const float* __restrict__ W1_,
                              const float* __restrict__ W2_, const float* __restrict__ b2_,
                              const float* __restrict__ dinv,
                              int n, float* __restrict__ o1, float* __restrict__ o2){
  __shared__ float w1[64*16], w2[64*16];
  int t = threadIdx.x;
  for (int i=t; i<1024; i+=256){ w1[i]=W1_[i]; w2[i]=W2_[i]; }
  __syncthreads();
  int nd = blockIdx.x*8 + (t>>5);
  if (nd>=n) return;
  int j = t & 31;
  const u16* xr = x + (size_t)nd*64;
  if (j<16){
    float s=0.f;
    #pragma unroll 8
    for (int k=0;k<64;k++) s += b2f(xr[k])*w1[k*16+j];
    o1[(size_t)nd*16+j]=s*dinv[nd];
  } else {
    int jj=j-16;
    float s = b2_[jj];
    #pragma unroll 8
    for (int k=0;k<64;k++) s += b2f(xr[k])*w2[k*16+jj];
    o2[(size_t)nd*16+jj]=s;
  }
}

// h4 output pre-scaled by dinv for the downstream aggregation
__global__ void k_gemm16_64(const float* __restrict__ x, const float* __restrict__ W,
                            const float* __restrict__ dinv,
                            int n, float* __restrict__ o){
  __shared__ float w[16*64];
  int t = threadIdx.x;
  for (int i=t;i<1024;i+=256) w[i]=W[i];
  __syncthreads();
  int nd = blockIdx.x*4 + (t>>6);
  if (nd>=n) return;
  int j = t&63;
  const float* xr = x + (size_t)nd*16;
  float s=0.f;
  #pragma unroll
  for (int k=0;k<16;k++) s += xr[k]*w[k*64+j];
  o[(size_t)nd*64+j]=s*dinv[nd];
}

// out(N,64) = x(N,64)@pW + pb, f32 out (safe in-place per-wave)
__global__ void k_final(const float* __restrict__ x, const float* __restrict__ W,
                        const float* __restrict__ b, int n, float* __restrict__ out){
  __shared__ float w[64*64];
  int t=threadIdx.x;
  for (int i=t;i<4096;i+=256) w[i]=W[i];
  __syncthreads();
  int nd = blockIdx.x*4 + (t>>6);
  if (nd>=n) return;
  int j=t&63;
  const float* xr = x + (size_t)nd*64;
  float s=b[j];
  #pragma unroll 8
  for (int k=0;k<64;k++) s += xr[k]*w[k*64+j];
  out[(size_t)nd*64+j]=s;
}

// =======================================================================
extern "C" void kernel_launch(void* const* d_in, const int* in_sizes, int n_in,
                              void* d_out, int out_size, void* d_ws, size_t ws_size,
                              hipStream_t stream) {
  const float* x   = (const float*)d_in[0];
  const int*   ei  = (const int*)d_in[1];
  const float* W1  = (const float*)d_in[2];
  const float* b1  = (const float*)d_in[3];
  const float* g1  = (const float*)d_in[4];
  const float* be1 = (const float*)d_in[5];
  const float* Wg  = (const float*)d_in[6];
  const float* a_s = (const float*)d_in[7];
  const float* a_d = (const float*)d_in[8];
  const float* bg  = (const float*)d_in[9];
  const float* g2  = (const float*)d_in[10];
  const float* be2 = (const float*)d_in[11];
  const float* W3  = (const float*)d_in[12];
  const float* b3  = (const float*)d_in[13];
  const float* g3  = (const float*)d_in[14];
  const float* be3 = (const float*)d_in[15];
  const float* W4  = (const float*)d_in[16];
  const float* b4  = (const float*)d_in[17];
  const float* r1W = (const float*)d_in[18];
  const float* r1b = (const float*)d_in[19];
  const float* r2W = (const float*)d_in[20];
  const float* r2b = (const float*)d_in[21];
  const float* r3W = (const float*)d_in[22];
  const float* r3b = (const float*)d_in[23];
  const float* pW  = (const float*)d_in[24];
  const float* pb  = (const float*)d_in[25];

  const int N = in_sizes[0] / 256;
  const int E = in_sizes[1] / 2;

  // ---- common misc carve-out ----
  char* w = (char*)d_ws;
  auto alloc = [&](size_t b)->void*{ void* p=(void*)w; w += (b+255)&~(size_t)255; return p; };
  u32*   flag   = (u32*)  alloc(4);
  float* part   = (float*)alloc(256*512*4);       // stats partials (256 blocks x 2C, C<=256)
  float* bnp1   = (float*)alloc(512*4);
  float* bnp2   = (float*)alloc(128*4);
  float* bnp3   = (float*)alloc(32*4);
  int*   bsum   = (int*)  alloc(256*4);
  int*   cur    = (int*)  alloc((size_t)N*4);
  int*   offs   = (int*)  alloc((size_t)(N+1)*4);
  float* dinv   = (float*)alloc((size_t)N*4);
  int*   csr    = (int*)  alloc((size_t)E*4);
  float* als    = (float*)alloc((size_t)N*16);
  float* ald    = (float*)alloc((size_t)N*16);
  float* asi    = (float*)alloc(256*4);
  float* adi    = (float*)alloc(256*4);
  u16*   W1t    = (u16*)  alloc(65536*2);
  u16*   r1Wt   = (u16*)  alloc(65536*2);
  u16*   Wgt    = (u16*)  alloc(65536*2);
  u16*   r2Wt   = (u16*)  alloc(16384*2);

  auto cdiv = [](int a, int b){ return (a+b-1)/b; };
  const int nb1024 = cdiv(N, 1024);
  const int statsGrid = 256;
  const int gemmGrid = cdiv(N,64);
  const int nodeGrid = cdiv(N,4);

  hipMemsetAsync(flag,   0, 4, stream);
  hipMemsetAsync(cur,    0, (size_t)N*4, stream);

  k_detect<<<64,256,0,stream>>>((const u32*)ei, E, flag);

  k_transpose<<<cdiv(65536,256),256,0,stream>>>(W1,  W1t,  256,256);
  k_transpose<<<cdiv(65536,256),256,0,stream>>>(r1W, r1Wt, 256,256);
  k_transpose<<<cdiv(65536,256),256,0,stream>>>(Wg,  Wgt,  256,256);
  k_transpose<<<cdiv(16384,256),256,0,stream>>>(r2W, r2Wt, 256,64);
  k_asdt<<<1,256,0,stream>>>(a_s, a_d, asi, adi);

  // ---- CSR build (edge_index fully consumed here) ----
  k_hist  <<<cdiv(E,256),256,0,stream>>>(ei, E, N, flag, cur);
  k_scan_a<<<nb1024,256,0,stream>>>(cur, N, bsum);
  k_scan_b<<<1,64,0,stream>>>(bsum, nb1024);
  k_scan_c<<<nb1024,256,0,stream>>>(cur, bsum, N, offs);
  k_dinv2 <<<cdiv(N,256),256,0,stream>>>(offs, N, dinv);
  hipMemsetAsync(cur, 0, (size_t)N*4, stream);
  k_scatter<<<cdiv(E,256),256,0,stream>>>(ei, E, N, flag, offs, cur, csr);

  size_t miscUsed = (size_t)(w - (char*)d_ws);
  size_t bigNeed  = miscUsed + 2*((size_t)N*512) + 1024;  // two N*256 bf16 regions

  if (ws_size >= bigNeed){
    // ================= BIG PATH (fused full-width) =================
    u16* RA = (u16*)alloc((size_t)N*512);   // H1' -> H2i ; then h3/r3/agg3/x4 (f32)
    u16* RB = (u16*)alloc((size_t)N*512);   // AGG1 -> X2 (fused in R1 gemm) ; then h4 (f32)
    u16* tAe = (u16*)d_in[1];               // edge buffer: O2 -> x3 (N*64 bf16)
    u16* r2d = (u16*)d_out;                 // r2 (N*64 bf16), later agg4 f32

    float* h3   = (float*)RA;
    float* r3   = (float*)(RA + (size_t)N*32);
    float* agg3 = (float*)(RA + (size_t)N*64);
    float* x4   = (float*)(RA + (size_t)N*96);
    float* h4   = (float*)RB;
    float* agg4 = (float*)d_out;

    // Layer 1: GCN(256->256); H1 rows pre-scaled by dinv (RS)
    k_gemm256<float,false,false,false,true><<<gemmGrid,256,0,stream>>>(
        x, x+64, x+128, x+192, 256, W1t, nullptr,
        nullptr, nullptr, nullptr, nullptr, nullptr, nullptr, dinv, RA, N);          // H1'
    k_gather256<<<nodeGrid,256,0,stream>>>(RA, offs, csr, dinv, b1, N, RB);          // AGG1
    k_stats_part<u16,256><<<statsGrid,256,0,stream>>>(RB, N, part);
    k_bnfin3<256><<<8,256,0,stream>>>(part, statsGrid, g1, be1, (float)N, bnp1);
    // R1 gemm with fused BN+leaky+residual: X2 = leaky(BN(AGG1)) + R1, in-place in RB
    k_gemm256<float,false,true,false,false><<<gemmGrid,256,0,stream>>>(
        x, x+64, x+128, x+192, 256, r1Wt, r1b,
        RB, bnp1, nullptr, nullptr, nullptr, nullptr, nullptr, RB, N);               // X2

    // Layer 2: GAT fused (H2 gemm also emits attention logit dots)
    k_gemm256<u16,true,false,true,false><<<gemmGrid,256,0,stream>>>(
        RB, RB+64, RB+128, RB+192, 256, Wgt, nullptr,
        nullptr, nullptr, asi, adi, als, ald, nullptr, RA, N);                       // H2i + als/ald
    k_gemm64<u16><<<gemmGrid,256,0,stream>>>(RB, RB+64, RB+128, RB+192, 256,
                                             r2Wt, r2b, r2d, N);                     // r2
    k_gat_all<<<nodeGrid,256,0,stream>>>(RA, offs, csr, als, ald, bg, N, tAe);       // O2
    k_stats_part<u16,64><<<statsGrid,256,0,stream>>>(tAe, N, part);
    k_bnfin3<64><<<2,256,0,stream>>>(part, statsGrid, g2, be2, (float)N, bnp2);
    k_ew_b16b16<<<cdiv(N*64,256),256,0,stream>>>(tAe, r2d, bnp2, 64, N*64, tAe);     // x3

    // Layer 3 (h3 pre-scaled by dinv in producer)
    k_gemm64_16x2<<<cdiv(N,8),256,0,stream>>>(tAe, W3, r3W, r3b, dinv, N, h3, r3);
    k_gcn_agg16<<<cdiv(N,16),256,0,stream>>>(h3, offs, csr, dinv, b3, agg3, N);
    k_stats_part<float,16><<<statsGrid,256,0,stream>>>(agg3, N, part);
    k_bnfin3<16><<<1,256,0,stream>>>(part, statsGrid, g3, be3, (float)N, bnp3);
    k_ew_f32f32<<<cdiv(N*16,256),256,0,stream>>>(agg3, r3, bnp3, 16, N*16, x4);

    // Layer 4 (h4 pre-scaled by dinv in producer)
    k_gemm16_64<<<nodeGrid,256,0,stream>>>(x4, W4, dinv, N, h4);
    k_gcn_agg64f<<<nodeGrid,256,0,stream>>>(h4, offs, csr, dinv, b4, agg4, N);
    k_final<<<nodeGrid,256,0,stream>>>(agg4, pW, pb, N, (float*)d_out);
  } else {
    // ================= FALLBACK (round-8 structure) =================
    u16* X0 = (u16*)alloc((size_t)N*64*2);
    u16* X1 = (u16*)alloc((size_t)N*64*2);
    u16* tA = (u16*)alloc((size_t)N*64*2);
    u16* tB = (u16*)alloc((size_t)N*64*2);
    u16* X2 = (u16*)d_in[1];
    u16* X3 = (u16*)d_out;
    const u16* XP[4] = {X0, X1, X2, X3};

    float* h3   = (float*)X1;
    float* r3   = (float*)(X1 + (size_t)N*32);
    float* agg3 = (float*)tA;
    float* x4   = (float*)(tA + (size_t)N*32);
    float* h4   = (float*)X0;
    float* agg4 = (float*)tA;

    for (int tau=0; tau<4; ++tau){
      u16* Xt = (u16*)XP[tau];
      k_gemm64<float><<<gemmGrid,256,0,stream>>>(x, x+64, x+128, x+192, 256,
                                                 W1t + (size_t)tau*64*256, nullptr, tA, N);
      k_gather64<<<nodeGrid,256,0,stream>>>(tA, offs, csr, dinv, b1 + tau*64, N, tB);
      k_stats_part<u16,64><<<statsGrid,256,0,stream>>>(tB, N, part);
      k_bnfin3<64><<<2,256,0,stream>>>(part, statsGrid, g1 + tau*64, be1 + tau*64, (float)N, bnp1 + tau*128);
      k_gemm64<float><<<gemmGrid,256,0,stream>>>(x, x+64, x+128, x+192, 256,
                                                 r1Wt + (size_t)tau*64*256, r1b + tau*64, tA, N);
      k_ew_b16b16<<<cdiv(N*64,256),256,0,stream>>>(tB, tA, bnp1 + tau*128, 64, N*64, Xt);
    }

    for (int head=0; head<4; ++head){
      k_gemm64<u16><<<gemmGrid,256,0,stream>>>(XP[0], XP[1], XP[2], XP[3], 64,
                                               Wgt + (size_t)head*64*256, nullptr, tA, N);
      k_dot64<<<nodeGrid,256,0,stream>>>(tA, a_s + head*64, a_d + head*64, head, N, als, ald);
      k_gat_head<<<nodeGrid,256,0,stream>>>(tA, offs, csr, als, ald, bg, head, N, tB);
    }
    k_gemm64<u16><<<gemmGrid,256,0,stream>>>(XP[0], XP[1], XP[2], XP[3], 64,
                                             r2Wt, r2b, tA, N);
    k_stats_part<u16,64><<<statsGrid,256,0,stream>>>(tB, N, part);
    k_bnfin3<64><<<2,256,0,stream>>>(part, statsGrid, g2, be2, (float)N, bnp2);
    k_ew_b16b16<<<cdiv(N*64,256),256,0,stream>>>(tB, tA, bnp2, 64, N*64, X0);

    k_gemm64_16x2<<<cdiv(N,8),256,0,stream>>>(X0, W3, r3W, r3b, dinv, N, h3, r3);
    k_gcn_agg16<<<cdiv(N,16),256,0,stream>>>(h3, offs, csr, dinv, b3, agg3, N);
    k_stats_part<float,16><<<statsGrid,256,0,stream>>>(agg3, N, part);
    k_bnfin3<16><<<1,256,0,stream>>>(part, statsGrid, g3, be3, (float)N, bnp3);
    k_ew_f32f32<<<cdiv(N*16,256),256,0,stream>>>(agg3, r3, bnp3, 16, N*16, x4);

    k_gemm16_64<<<nodeGrid,256,0,stream>>>(x4, W4, dinv, N, h4);
    k_gcn_agg64f<<<nodeGrid,256,0,stream>>>(h4, offs, csr, dinv, b4, agg4, N);
    k_final<<<nodeGrid,256,0,stream>>>(agg4, pW, pb, N, (float*)d_out);
  }
}

// Round 9
// 700.909 us; speedup vs baseline: 1.9892x; 1.0005x over previous
//
#include <hip/hip_runtime.h>

typedef unsigned short u16;
typedef unsigned int   u32;

// ---------- bf16 helpers ----------
__device__ __forceinline__ float b2f(u16 h){ return __uint_as_float(((u32)h)<<16); }
__device__ __forceinline__ u16 f2b(float f){
  u32 u = __float_as_uint(f);
  u32 r = (u + 0x7fffu + ((u>>16)&1u)) >> 16;   // RNE
  return (u16)r;
}
__device__ __forceinline__ float leaky(float x, float s){ return x >= 0.f ? x : s*x; }

typedef __bf16 bf16x8 __attribute__((ext_vector_type(8)));
typedef float  f32x4  __attribute__((ext_vector_type(4)));

__device__ __forceinline__ float ldval(const u16* p){ return b2f(*p); }
__device__ __forceinline__ float ldval(const float* p){ return *p; }

__device__ __forceinline__ void load8(const u16* p, u16* h){ *(uint4*)h = *(const uint4*)p; }
__device__ __forceinline__ void load8(const float* p, u16* h){
  float4 a = *(const float4*)p; float4 b = *(const float4*)(p+4);
  h[0]=f2b(a.x); h[1]=f2b(a.y); h[2]=f2b(a.z); h[3]=f2b(a.w);
  h[4]=f2b(b.x); h[5]=f2b(b.y); h[6]=f2b(b.z); h[7]=f2b(b.w);
}

// ---------- int64-vs-int32 detection ----------
__global__ void k_detect(const u32* __restrict__ w, int E, u32* __restrict__ flag){
  u32 acc = 0;
  for (int i = blockIdx.x*256 + threadIdx.x; i < E; i += 256*gridDim.x)
    acc |= w[2*i + 1];
  __shared__ u32 s[256];
  s[threadIdx.x] = acc; __syncthreads();
  for (int o=128;o>0;o>>=1){ if (threadIdx.x<o) s[threadIdx.x] |= s[threadIdx.x+o]; __syncthreads(); }
  if (threadIdx.x==0 && s[0]) atomicOr(flag, 1u);
}

__device__ __forceinline__ void edge_sd(const int* __restrict__ ei, int E, int e, u32 is32,
                                        int& s, int& d){
  if (is32){ s = ei[e];   d = ei[E + e]; }
  else     { s = ei[2*e]; d = ei[2*E + 2*e]; }
}

// ---------- CSR build ----------
__global__ void k_hist(const int* __restrict__ ei, int E, int nN,
                       const u32* __restrict__ flag, int* __restrict__ cnt){
  int e = blockIdx.x*256 + threadIdx.x;
  if (e < E){
    int s,d; edge_sd(ei, E, e, *flag, s, d);
    if ((u32)s < (u32)nN && (u32)d < (u32)nN) atomicAdd(&cnt[d], 1);
  }
}

__global__ void k_scan_a(const int* __restrict__ cnt, int n, int* __restrict__ bsum){
  __shared__ int s[256];
  int base = blockIdx.x*1024, t = threadIdx.x, sum = 0;
  for (int j=0;j<4;j++){ int i = base + t*4 + j; if (i<n) sum += cnt[i]; }
  s[t] = sum; __syncthreads();
  for (int off=128; off>0; off>>=1){ if (t<off) s[t]+=s[t+off]; __syncthreads(); }
  if (t==0) bsum[blockIdx.x] = s[0];
}

__global__ void k_scan_b(int* bsum, int nb){
  if (threadIdx.x==0 && blockIdx.x==0){
    int acc = 0;
    for (int i=0;i<nb;i++){ int v = bsum[i]; bsum[i] = acc; acc += v; }
  }
}

__global__ void k_scan_c(const int* __restrict__ cnt, const int* __restrict__ bsum,
                         int n, int* __restrict__ offs){
  __shared__ int s[256];
  int base = blockIdx.x*1024, t = threadIdx.x;
  int v[4]; int sum=0;
  for (int j=0;j<4;j++){ int i=base+t*4+j; v[j] = (i<n)?cnt[i]:0; sum += v[j]; }
  s[t]=sum; __syncthreads();
  for (int off=1; off<256; off<<=1){
    int add = (t>=off)? s[t-off] : 0;
    __syncthreads();
    s[t] += add;
    __syncthreads();
  }
  int excl = (t ? s[t-1] : 0) + bsum[blockIdx.x];
  for (int j=0;j<4;j++){
    int i = base+t*4+j;
    if (i<n){ offs[i] = excl; excl += v[j]; if (i==n-1) offs[n] = excl; }
  }
}

__global__ void k_dinv2(const int* __restrict__ offs, int n, float* __restrict__ dinv){
  int i = blockIdx.x*256+threadIdx.x;
  if (i<n) dinv[i] = rsqrtf((float)(offs[i+1]-offs[i]) + 1.0f);
}

__global__ void k_scatter(const int* __restrict__ ei, int E, int nN,
                          const u32* __restrict__ flag, const int* __restrict__ offs,
                          int* __restrict__ cursor, int* __restrict__ csr){
  int e = blockIdx.x*256+threadIdx.x;
  if (e<E){
    int s,d; edge_sd(ei, E, e, *flag, s, d);
    if ((u32)s < (u32)nN && (u32)d < (u32)nN){
      int pos = offs[d] + atomicAdd(&cursor[d], 1);
      csr[pos] = s;
    }
  }
}

// ---------- transpose+convert: f32 (K x M) -> bf16 (M x K) ----------
__global__ void k_transpose(const float* __restrict__ in, u16* __restrict__ out, int K, int M){
  int i = blockIdx.x*256 + threadIdx.x;
  if (i < K*M){ int k = i / M, m = i % M; out[m*K + k] = f2b(in[i]); }
}

// interleave attention vectors: asi[c*4+h] = a_s[h*64+c]
__global__ void k_asdt(const float* __restrict__ a_s, const float* __restrict__ a_d,
                       float* __restrict__ asi, float* __restrict__ adi){
  int i = threadIdx.x;
  int h = i>>6, c = i&63;
  asi[c*4+h] = a_s[i];
  adi[c*4+h] = a_d[i];
}

// ---------- MFMA GEMM, M=64 (col-sliced waves: B read ONCE per block) ----------
template<typename AT>
__global__ __launch_bounds__(256) void k_gemm64(
  const AT* __restrict__ A0, const AT* __restrict__ A1,
  const AT* __restrict__ A2, const AT* __restrict__ A3,
  int rsA, const u16* __restrict__ Bt, const float* __restrict__ bias,
  u16* __restrict__ out, int nRows)
{
  alignas(16) __shared__ u16 Al[64*264];   // A staging, then reused as output tile
  const int t = threadIdx.x;
  const int r0 = blockIdx.x*64;
  for (int it=0; it<8; ++it){
    int c = t + it*256;
    int row = c>>5, seg = c&31;
    int gr = r0+row;
    u16 hv[8] = {0,0,0,0,0,0,0,0};
    if (gr < nRows){
      const AT* p = (seg<8)?A0 : (seg<16)?A1 : (seg<24)?A2 : A3;
      load8(p + (size_t)gr*rsA + (seg&7)*8, hv);
    }
    *(uint4*)&Al[row*264 + seg*8] = *(uint4*)hv;
  }
  const int lane=t&63, wid=t>>6, quad=lane>>4, l15=lane&15;
  __syncthreads();
  const int col = wid*16 + l15;
  const u16* Bp = Bt + (size_t)col*256 + quad*8;
  bf16x8 b[8];
  #pragma unroll
  for (int ks=0;ks<8;++ks) b[ks] = *(const bf16x8*)(Bp + ks*32);
  f32x4 acc[4] = {{0.f,0.f,0.f,0.f},{0.f,0.f,0.f,0.f},{0.f,0.f,0.f,0.f},{0.f,0.f,0.f,0.f}};
  #pragma unroll
  for (int rt=0; rt<4; ++rt){
    const int abase = (rt*16 + l15)*264 + quad*8;
    #pragma unroll
    for (int ks=0;ks<8;++ks){
      bf16x8 av = *(const bf16x8*)&Al[abase + ks*32];
      acc[rt] = __builtin_amdgcn_mfma_f32_16x16x32_bf16(av, b[ks], acc[rt], 0,0,0);
    }
  }
  __syncthreads();
  float bv = bias ? bias[col] : 0.f;
  #pragma unroll
  for (int rt=0; rt<4; ++rt){
    #pragma unroll
    for (int reg=0;reg<4;++reg)
      Al[(rt*16 + quad*4 + reg)*264 + col] = f2b(acc[rt][reg]+bv);
  }
  __syncthreads();
  #pragma unroll
  for (int it=0; it<2; ++it){
    int idx = it*256 + t;
    int row = idx>>3, cu = idx&7;
    if (r0+row < nRows)
      *(uint4*)(out + (size_t)(r0+row)*64 + cu*8) = *(const uint4*)&Al[row*264 + cu*8];
  }
}

// ---------- MFMA GEMM, M=256 (512 thr, 8 waves x 32 cols; low-VGPR; fused EW/DOT/RS) ----------
// EW:  out = leaky(agg*bnp_sc + bnp_sh) + (acc+bias)
// DOT: after epilogue, compute per-node attention dots from the interleaved LDS tile
// RS:  scale output rows by rowscale[r] (pre-applied dinv for downstream gathers)
template<typename AT, bool PERM, bool EW, bool DOT, bool RS>
__global__ __launch_bounds__(512) void k_gemm256(
  const AT* __restrict__ A0, const AT* __restrict__ A1,
  const AT* __restrict__ A2, const AT* __restrict__ A3,
  int rsA, const u16* __restrict__ Bt, const float* __restrict__ bias,
  const u16* __restrict__ agg, const float* __restrict__ bnp,
  const float* __restrict__ asi, const float* __restrict__ adi,
  float* __restrict__ als, float* __restrict__ ald,
  const float* __restrict__ rowscale,
  u16* __restrict__ out, int nRows)
{
  alignas(16) __shared__ u16 Al[64*264];   // A staging, then reused as output tile
  const int t = threadIdx.x;
  const int r0 = blockIdx.x*64;
  for (int it=0; it<4; ++it){
    int c = t + it*512;
    int row = c>>5, seg = c&31;
    int gr = r0+row;
    u16 hv[8] = {0,0,0,0,0,0,0,0};
    if (gr < nRows){
      const AT* p = (seg<8)?A0 : (seg<16)?A1 : (seg<24)?A2 : A3;
      load8(p + (size_t)gr*rsA + (seg&7)*8, hv);
    }
    *(uint4*)&Al[row*264 + seg*8] = *(uint4*)hv;
  }
  const int lane=t&63, wid=t>>6, quad=lane>>4, l15=lane&15;   // wid 0..7
  __syncthreads();
  f32x4 acc[2][4];   // [ct][rt] — 32 VGPRs
  #pragma unroll
  for (int ct=0; ct<2; ++ct)
    #pragma unroll
    for (int rt=0; rt<4; ++rt) acc[ct][rt] = {0.f,0.f,0.f,0.f};
  #pragma unroll
  for (int ct=0; ct<2; ++ct){
    const u16* Bp = Bt + (size_t)(wid*32 + ct*16 + l15)*256 + quad*8;
    #pragma unroll
    for (int ks=0;ks<8;++ks){
      bf16x8 b = *(const bf16x8*)(Bp + ks*32);   // streamed B fragment
      #pragma unroll
      for (int rt=0; rt<4; ++rt){
        bf16x8 av = *(const bf16x8*)&Al[(rt*16 + l15)*264 + quad*8 + ks*32];
        acc[ct][rt] = __builtin_amdgcn_mfma_f32_16x16x32_bf16(av, b, acc[ct][rt], 0,0,0);
      }
    }
  }
  __syncthreads();   // all waves done reading Al before epilogue overwrite
  #pragma unroll
  for (int ct=0; ct<2; ++ct){
    int col = wid*32 + ct*16 + l15;
    float bv = bias ? bias[col] : 0.f;
    int oc = PERM ? ((col&63)*4 + (col>>6)) : col;
    #pragma unroll
    for (int rt=0; rt<4; ++rt){
      #pragma unroll
      for (int reg=0;reg<4;++reg){
        float v = acc[ct][rt][reg] + bv;
        if constexpr (RS){
          int r = r0 + rt*16 + quad*4 + reg;
          v *= (r < nRows) ? rowscale[r] : 1.f;
        }
        Al[(rt*16 + quad*4 + reg)*264 + oc] = f2b(v);
      }
    }
  }
  __syncthreads();
  if constexpr (DOT){
    // 8 threads per row, 32 interleaved entries each; entry ii -> head ii&3
    int row = t>>3, q = t&7;
    int nd = r0 + row;
    if (nd < nRows){
      float s0=0.f,s1=0.f,s2=0.f,s3=0.f,d0=0.f,d1=0.f,d2=0.f,d3=0.f;
      const u16* ar = &Al[row*264 + q*32];
      const float* as = asi + q*32;
      const float* ad = adi + q*32;
      #pragma unroll 4
      for (int k=0;k<32;k+=4){
        uint2 wv = *(const uint2*)&ar[k];
        float v0=b2f((u16)(wv.x&0xffff)), v1=b2f((u16)(wv.x>>16));
        float v2=b2f((u16)(wv.y&0xffff)), v3=b2f((u16)(wv.y>>16));
        s0 += v0*as[k];   d0 += v0*ad[k];
        s1 += v1*as[k+1]; d1 += v1*ad[k+1];
        s2 += v2*as[k+2]; d2 += v2*ad[k+2];
        s3 += v3*as[k+3]; d3 += v3*ad[k+3];
      }
      s0 += __shfl_xor(s0,1,64); s0 += __shfl_xor(s0,2,64); s0 += __shfl_xor(s0,4,64);
      s1 += __shfl_xor(s1,1,64); s1 += __shfl_xor(s1,2,64); s1 += __shfl_xor(s1,4,64);
      s2 += __shfl_xor(s2,1,64); s2 += __shfl_xor(s2,2,64); s2 += __shfl_xor(s2,4,64);
      s3 += __shfl_xor(s3,1,64); s3 += __shfl_xor(s3,2,64); s3 += __shfl_xor(s3,4,64);
      d0 += __shfl_xor(d0,1,64); d0 += __shfl_xor(d0,2,64); d0 += __shfl_xor(d0,4,64);
      d1 += __shfl_xor(d1,1,64); d1 += __shfl_xor(d1,2,64); d1 += __shfl_xor(d1,4,64);
      d2 += __shfl_xor(d2,1,64); d2 += __shfl_xor(d2,2,64); d2 += __shfl_xor(d2,4,64);
      d3 += __shfl_xor(d3,1,64); d3 += __shfl_xor(d3,2,64); d3 += __shfl_xor(d3,4,64);
      if (q==0){
        float4 sv = {s0,s1,s2,s3}; float4 dv = {d0,d1,d2,d3};
        ((float4*)als)[nd] = sv;
        ((float4*)ald)[nd] = dv;
      }
    }
  }
  #pragma unroll
  for (int it=0; it<4; ++it){
    int idx = it*512 + t;
    int row = idx>>5, cu = idx&31;
    int r = r0+row;
    if (r < nRows){
      if constexpr (EW){
        uint4 hv = *(const uint4*)&Al[row*264 + cu*8];
        uint4 av = *(const uint4*)(agg + (size_t)r*256 + cu*8);
        const u16* hp = (const u16*)&hv; const u16* ap = (const u16*)&av;
        uint4 ov; u16* op = (u16*)&ov;
        #pragma unroll
        for (int j=0;j<8;++j){
          int c = cu*8+j;
          float v = b2f(ap[j])*bnp[c] + bnp[256+c];
          op[j] = f2b(leaky(v, 0.01f) + b2f(hp[j]));
        }
        *(uint4*)(out + (size_t)r*256 + cu*8) = ov;
      } else {
        *(uint4*)(out + (size_t)r*256 + cu*8) = *(const uint4*)&Al[row*264 + cu*8];
      }
    }
  }
}

// ---------- GCN gather, 64 channels (fallback path; h unscaled, uses dinv[s]) ----------
__global__ void k_gather64(const u16* __restrict__ h, const int* __restrict__ offs,
                           const int* __restrict__ csr, const float* __restrict__ dinv,
                           const float* __restrict__ bias, int n, u16* __restrict__ out){
  int nd = blockIdx.x*4 + (threadIdx.x>>6);
  if (nd>=n) return;
  int lane = threadIdx.x&63;
  float dn = dinv[nd];
  float acc = dn*b2f(h[(size_t)nd*64+lane]);
  int e = offs[nd], end = offs[nd+1];
  for (; e+4<=end; e+=4){
    int s0=csr[e], s1=csr[e+1], s2=csr[e+2], s3=csr[e+3];
    float w0=dinv[s0], w1=dinv[s1], w2=dinv[s2], w3=dinv[s3];
    float p0=b2f(h[(size_t)s0*64+lane]);
    float p1=b2f(h[(size_t)s1*64+lane]);
    float p2=b2f(h[(size_t)s2*64+lane]);
    float p3=b2f(h[(size_t)s3*64+lane]);
    acc += w0*p0 + w1*p1 + w2*p2 + w3*p3;
  }
  for (; e<end; ++e){
    int s=csr[e];
    acc += dinv[s]*b2f(h[(size_t)s*64+lane]);
  }
  out[(size_t)nd*64+lane] = f2b(dn*acc + bias[lane]);
}

// ---------- GCN gather, 256 channels (h pre-scaled by dinv; 4-deep unroll) ----------
__global__ void k_gather256(const u16* __restrict__ h, const int* __restrict__ offs,
                            const int* __restrict__ csr, const float* __restrict__ dinv,
                            const float* __restrict__ bias, int n, u16* __restrict__ out){
  int nd = blockIdx.x*4 + (threadIdx.x>>6);
  if (nd>=n) return;
  int lane = threadIdx.x&63;
  const uint2* H = (const uint2*)h;
  float dn = dinv[nd];
  uint2 pv = H[(size_t)nd*64 + lane];        // self term: h'[d] = dinv[d]*h[d]
  float a0=b2f(pv.x&0xffff), a1=b2f(pv.x>>16);
  float a2=b2f(pv.y&0xffff), a3=b2f(pv.y>>16);
  int e=offs[nd], end=offs[nd+1];
  for (; e+4<=end; e+=4){
    int s0=csr[e], s1=csr[e+1], s2=csr[e+2], s3=csr[e+3];
    uint2 q0=H[(size_t)s0*64+lane], q1=H[(size_t)s1*64+lane];
    uint2 q2=H[(size_t)s2*64+lane], q3=H[(size_t)s3*64+lane];
    a0 += b2f(q0.x&0xffff) + b2f(q1.x&0xffff) + b2f(q2.x&0xffff) + b2f(q3.x&0xffff);
    a1 += b2f(q0.x>>16)    + b2f(q1.x>>16)    + b2f(q2.x>>16)    + b2f(q3.x>>16);
    a2 += b2f(q0.y&0xffff) + b2f(q1.y&0xffff) + b2f(q2.y&0xffff) + b2f(q3.y&0xffff);
    a3 += b2f(q0.y>>16)    + b2f(q1.y>>16)    + b2f(q2.y>>16)    + b2f(q3.y>>16);
  }
  for (; e<end; ++e){
    int s=csr[e];
    uint2 q=H[(size_t)s*64+lane];
    a0 += b2f(q.x&0xffff); a1 += b2f(q.x>>16);
    a2 += b2f(q.y&0xffff); a3 += b2f(q.y>>16);
  }
  float4 bv = *(const float4*)(bias + lane*4);
  uint2 o;
  o.x = (u32)f2b(a0*dn + bv.x) | ((u32)f2b(a1*dn + bv.y)<<16);
  o.y = (u32)f2b(a2*dn + bv.z) | ((u32)f2b(a3*dn + bv.w)<<16);
  ((uint2*)out)[(size_t)nd*64 + lane] = o;
}

// ---------- BN stats partials, vectorized (16B loads, reg partials, LDS tree) ----------
template<typename T, int C>
__global__ __launch_bounds__(256) void k_stats_part(const T* __restrict__ x, int n,
                                                    float* __restrict__ part){
  constexpr int VE = 16/sizeof(T);   // elems per 16B load: 8 (bf16) / 4 (f32)
  constexpr int G  = C/VE;           // vec-groups per row
  constexpr int R  = 256/G;          // rows covered per block pass
  int t = threadIdx.x;
  int g = t % G, sub = t / G;
  int rpb = (n + gridDim.x - 1) / gridDim.x;
  int base = blockIdx.x * rpb;
  int lim  = min(base + rpb, n);
  float s[VE], s2[VE];
  #pragma unroll
  for (int j=0;j<VE;j++){ s[j]=0.f; s2[j]=0.f; }
  #pragma unroll 4
  for (int r = base + sub; r < lim; r += R){
    const T* p = x + (size_t)r*C + g*VE;
    if constexpr (sizeof(T)==2){
      uint4 v = *(const uint4*)p;
      u32 wq[4] = {v.x, v.y, v.z, v.w};
      #pragma unroll
      for (int q=0;q<4;q++){
        float lo = __uint_as_float(wq[q]<<16);
        float hi = __uint_as_float(wq[q]&0xffff0000u);
        s[2*q]  += lo; s2[2*q]  += lo*lo;
        s[2*q+1]+= hi; s2[2*q+1]+= hi*hi;
      }
    } else {
      float4 v = *(const float4*)p;
      float a[4] = {v.x, v.y, v.z, v.w};
      #pragma unroll
      for (int q=0;q<4;q++){ s[q]+=a[q]; s2[q]+=a[q]*a[q]; }
    }
  }
  __shared__ float red[VE][256];
  #pragma unroll
  for (int j=0;j<VE;j++) red[j][t] = s[j];
  __syncthreads();
  for (int off=R/2; off>0; off>>=1){
    if (sub < off){
      #pragma unroll
      for (int j=0;j<VE;j++) red[j][t] += red[j][t + off*G];
    }
    __syncthreads();
  }
  if (t < G){
    #pragma unroll
    for (int j=0;j<VE;j++) part[blockIdx.x*2*C + t*VE + j] = red[j][t];
  }
  __syncthreads();
  #pragma unroll
  for (int j=0;j<VE;j++) red[j][t] = s2[j];
  __syncthreads();
  for (int off=R/2; off>0; off>>=1){
    if (sub < off){
      #pragma unroll
      for (int j=0;j<VE;j++) red[j][t] += red[j][t + off*G];
    }
    __syncthreads();
  }
  if (t < G){
    #pragma unroll
    for (int j=0;j<VE;j++) part[blockIdx.x*2*C + C + t*VE + j] = red[j][t];
  }
}

// ---------- BN finalize: channel-parallel multi-block (32 ch/block, 8 thr/ch) ----------
template<int C>
__global__ __launch_bounds__(256) void k_bnfin3(const float* __restrict__ part, int B,
                         const float* __restrict__ g, const float* __restrict__ be,
                         float n, float* __restrict__ bnp){
  constexpr int CPB = (C < 32) ? C : 32;   // channels per block
  constexpr int TPC = 256 / CPB;           // threads per channel
  int t = threadIdx.x;
  int lc = t % CPB, sub = t / CPB;
  int c = blockIdx.x*CPB + lc;
  float s=0.f, s2=0.f;
  for (int b = sub; b < B; b += TPC){
    s  += part[(size_t)b*2*C + c];
    s2 += part[(size_t)b*2*C + C + c];
  }
  __shared__ float ls[256], lq[256];
  ls[t]=s; lq[t]=s2; __syncthreads();
  for (int off=TPC/2; off>0; off>>=1){
    if (sub < off){ ls[t]+=ls[t+off*CPB]; lq[t]+=lq[t+off*CPB]; }
    __syncthreads();
  }
  if (sub==0){
    float mu = ls[t]/n;
    float var = fmaxf(lq[t]/n - mu*mu, 0.f);
    float sc = g[c] * rsqrtf(var + 1e-5f);
    bnp[c] = sc;
    bnp[C+c] = be[c] - mu*sc;
  }
}

// ---------- elementwise BN+leaky+residual ----------
__global__ void k_ew_b16b16(const u16* __restrict__ agg, const u16* __restrict__ res,
                            const float* __restrict__ bnp, int C, int total, u16* __restrict__ out){
  int i = blockIdx.x*256+threadIdx.x;
  if (i < total){
    int c = i & (C-1);
    float v = b2f(agg[i])*bnp[c] + bnp[C+c];
    out[i] = f2b(leaky(v, 0.01f) + b2f(res[i]));
  }
}

__global__ void k_ew_f32f32(const float* __restrict__ agg, const float* __restrict__ res,
                            const float* __restrict__ bnp, int C, int total, float* __restrict__ out){
  int i = blockIdx.x*256+threadIdx.x;
  if (i < total){
    int c = i & (C-1);
    float v = agg[i]*bnp[c] + bnp[C+c];
    out[i] = leaky(v, 0.01f) + res[i];
  }
}

// ---------- GAT fallback: per-head logit dot ----------
__global__ void k_dot64(const u16* __restrict__ h2t, const float* __restrict__ asg,
                        const float* __restrict__ adg, int head, int n,
                        float* __restrict__ als, float* __restrict__ ald){
  int nd = blockIdx.x*4 + (threadIdx.x>>6);
  if (nd>=n) return;
  int lane = threadIdx.x&63;
  float p = b2f(h2t[(size_t)nd*64+lane]);
  float ss = p*asg[lane];
  float sd = p*adg[lane];
  for (int m=1;m<64;m<<=1){ ss += __shfl_xor(ss,m,64); sd += __shfl_xor(sd,m,64); }
  if (lane==0){ als[nd*4+head]=ss; ald[nd*4+head]=sd; }
}

// ---------- GAT fallback: per-head softmax gather (online softmax) ----------
__global__ void k_gat_head(const u16* __restrict__ h2t, const int* __restrict__ offs,
                           const int* __restrict__ csr, const float* __restrict__ als,
                           const float* __restrict__ ald, const float* __restrict__ bg,
                           int head, int n, u16* __restrict__ O2){
  int nd = blockIdx.x*4 + (threadIdx.x>>6);
  if (nd>=n) return;
  int lane = threadIdx.x&63;
  float aldn = ald[nd*4+head];
  float m = leaky(als[nd*4+head] + aldn, 0.2f);
  float denom = 1.f;
  float acc = b2f(h2t[(size_t)nd*64+lane]);
  int e = offs[nd], end = offs[nd+1];
  for (; e+4<=end; e+=4){
    int s0=csr[e], s1=csr[e+1], s2=csr[e+2], s3=csr[e+3];
    float l0=als[s0*4+head], l1=als[s1*4+head], l2=als[s2*4+head], l3=als[s3*4+head];
    float p0=b2f(h2t[(size_t)s0*64+lane]);
    float p1=b2f(h2t[(size_t)s1*64+lane]);
    float p2=b2f(h2t[(size_t)s2*64+lane]);
    float p3=b2f(h2t[(size_t)s3*64+lane]);
    float g0=leaky(l0+aldn,0.2f), g1=leaky(l1+aldn,0.2f);
    float g2=leaky(l2+aldn,0.2f), g3=leaky(l3+aldn,0.2f);
    float mc = fmaxf(fmaxf(g0,g1), fmaxf(g2,g3));
    float mn = fmaxf(m, mc);
    float sc = __expf(m - mn);
    float w0 = __expf(g0-mn), w1 = __expf(g1-mn), w2 = __expf(g2-mn), w3 = __expf(g3-mn);
    denom = denom*sc + (w0+w1+w2+w3);
    acc   = acc*sc   + (w0*p0 + w1*p1 + w2*p2 + w3*p3);
    m = mn;
  }
  for (; e<end; ++e){
    int s = csr[e];
    float g = leaky(als[s*4+head]+aldn, 0.2f);
    float p = b2f(h2t[(size_t)s*64+lane]);
    float mn = fmaxf(m, g);
    float sc = __expf(m - mn);
    float w = __expf(g - mn);
    denom = denom*sc + w;
    acc   = acc*sc   + w*p;
    m = mn;
  }
  float v = 0.25f * acc / fmaxf(denom, 1e-20f);
  size_t oi = (size_t)nd*64+lane;
  if (head==0) O2[oi] = f2b(v + bg[lane]);
  else         O2[oi] = f2b(b2f(O2[oi]) + v);
}

// ---------- GAT big path: fused, distributed weights via intra-wave LDS ----------
__global__ void k_gat_all(const u16* __restrict__ h2i, const int* __restrict__ offs,
                          const int* __restrict__ csr, const float* __restrict__ als,
                          const float* __restrict__ ald, const float* __restrict__ bg,
                          int n, u16* __restrict__ O2){
  alignas(16) __shared__ float shm[4][80];  // per wave: [0..3] denoms, [4..7] self-w, [8..71] edge wts
  int wv = threadIdx.x>>6;
  int nd = blockIdx.x*4 + wv;
  if (nd>=n) return;
  int lane = threadIdx.x&63;
  int eg = lane>>2, hh = lane&3;
  float4 alv = ((const float4*)als)[nd];
  float4 adv = ((const float4*)ald)[nd];
  float adh = (hh&2) ? ((hh&1)?adv.w:adv.z) : ((hh&1)?adv.y:adv.x);
  float alh = (hh&2) ? ((hh&1)?alv.w:alv.z) : ((hh&1)?alv.y:alv.x);
  float gsh = leaky(alh+adh, 0.2f);
  int beg=offs[nd], end=offs[nd+1];
  // pass 1: distributed per-head max (incl. self)
  float m = gsh;
  for (int e=beg+eg; e<end; e+=16){
    int s = csr[e];
    m = fmaxf(m, leaky(als[s*4+hh]+adh, 0.2f));
  }
  #pragma unroll
  for (int off=4; off<64; off<<=1) m = fmaxf(m, __shfl_xor(m, off, 64));
  float wsh = __expf(gsh - m);
  if (eg==0) shm[wv][4+hh] = wsh;
  float4 ws4 = *(const float4*)&shm[wv][4];
  uint2 pv = ((const uint2*)h2i)[(size_t)nd*64+lane];
  float a0 = ws4.x*__uint_as_float(pv.x<<16);
  float a1 = ws4.y*__uint_as_float(pv.x&0xffff0000u);
  float a2 = ws4.z*__uint_as_float(pv.y<<16);
  float a3 = ws4.w*__uint_as_float(pv.y&0xffff0000u);
  float dpart = 0.f;
  const uint2* H = (const uint2*)h2i;
  // pass 2: chunks of 16 edges; phase A computes 64 weights (1 exp/lane),
  // phase B does the all-lane weighted gather with LDS-broadcast weights
  for (int e0=beg; e0<end; e0+=16){
    int e = e0+eg;
    int sA = 0; float wE = 0.f;
    if (e<end){
      sA = csr[e];
      wE = __expf(leaky(als[sA*4+hh]+adh, 0.2f) - m);
    }
    dpart += wE;
    shm[wv][8+lane] = wE;
    int cnt = min(16, end-e0);
    int k=0;
    for (; k+4<=cnt; k+=4){
      int sa=__shfl(sA,(k  )*4,64), sb=__shfl(sA,(k+1)*4,64);
      int sc=__shfl(sA,(k+2)*4,64), sd=__shfl(sA,(k+3)*4,64);
      float4 wa=*(const float4*)&shm[wv][8+(k  )*4];
      float4 wb=*(const float4*)&shm[wv][8+(k+1)*4];
      float4 wc=*(const float4*)&shm[wv][8+(k+2)*4];
      float4 wd=*(const float4*)&shm[wv][8+(k+3)*4];
      uint2 qa=H[(size_t)sa*64+lane], qb=H[(size_t)sb*64+lane];
      uint2 qc=H[(size_t)sc*64+lane], qd=H[(size_t)sd*64+lane];
      a0 += wa.x*__uint_as_float(qa.x<<16) + wb.x*__uint_as_float(qb.x<<16)
          + wc.x*__uint_as_float(qc.x<<16) + wd.x*__uint_as_float(qd.x<<16);
      a1 += wa.y*__uint_as_float(qa.x&0xffff0000u) + wb.y*__uint_as_float(qb.x&0xffff0000u)
          + wc.y*__uint_as_float(qc.x&0xffff0000u) + wd.y*__uint_as_float(qd.x&0xffff0000u);
      a2 += wa.z*__uint_as_float(qa.y<<16) + wb.z*__uint_as_float(qb.y<<16)
          + wc.z*__uint_as_float(qc.y<<16) + wd.z*__uint_as_float(qd.y<<16);
      a3 += wa.w*__uint_as_float(qa.y&0xffff0000u) + wb.w*__uint_as_float(qb.y&0xffff0000u)
          + wc.w*__uint_as_float(qc.y&0xffff0000u) + wd.w*__uint_as_float(qd.y&0xffff0000u);
    }
    for (; k<cnt; ++k){
      int s = __shfl(sA, k*4, 64);
      float4 w4 = *(const float4*)&shm[wv][8+k*4];
      uint2 q = H[(size_t)s*64+lane];
      a0 += w4.x*__uint_as_float(q.x<<16);
      a1 += w4.y*__uint_as_float(q.x&0xffff0000u);
      a2 += w4.z*__uint_as_float(q.y<<16);
      a3 += w4.w*__uint_as_float(q.y&0xffff0000u);
    }
  }
  #pragma unroll
  for (int off=4; off<64; off<<=1) dpart += __shfl_xor(dpart, off, 64);
  float dh = dpart + wsh;
  if (eg==0) shm[wv][hh] = dh;
  float4 d4 = *(const float4*)&shm[wv][0];
  float v = 0.25f*(a0/d4.x + a1/d4.y + a2/d4.z + a3/d4.w);
  O2[(size_t)nd*64+lane] = f2b(v + bg[lane]);
}

// ---------- GCN aggregation, C=16, f32 (h pre-scaled by dinv) ----------
__global__ void k_gcn_agg16(const float* __restrict__ h, const int* __restrict__ offs,
                            const int* __restrict__ csr, const float* __restrict__ dinv,
                            const float* __restrict__ bias, float* __restrict__ out, int n){
  int t = threadIdx.x;
  int nd = blockIdx.x*16 + (t>>4);
  if (nd>=n) return;
  int c = t&15;
  float dn = dinv[nd];
  float acc = h[(size_t)nd*16+c];          // self term: h'[d]
  int e=offs[nd], end=offs[nd+1];
  for (; e+4<=end; e+=4){
    int s0=csr[e], s1=csr[e+1], s2=csr[e+2], s3=csr[e+3];
    acc += h[(size_t)s0*16+c] + h[(size_t)s1*16+c]
         + h[(size_t)s2*16+c] + h[(size_t)s3*16+c];
  }
  for (; e<end; ++e){
    int s = csr[e];
    acc += h[(size_t)s*16+c];
  }
  out[(size_t)nd*16+c] = dn*acc + bias[c];
}

// ---------- GCN aggregation, C=64, f32 (h pre-scaled by dinv; 4-deep) ----------
__global__ void k_gcn_agg64f(const float* __restrict__ h, const int* __restrict__ offs,
                             const int* __restrict__ csr, const float* __restrict__ dinv,
                             const float* __restrict__ bias, float* __restrict__ out, int n){
  int nd = blockIdx.x*4 + (threadIdx.x>>6);
  if (nd>=n) return;
  int lane = threadIdx.x&63;
  float dn = dinv[nd];
  float acc = h[(size_t)nd*64+lane];       // self term: h'[d]
  int e=offs[nd], end=offs[nd+1];
  for (; e+4<=end; e+=4){
    int s0=csr[e], s1=csr[e+1], s2=csr[e+2], s3=csr[e+3];
    acc += h[(size_t)s0*64+lane] + h[(size_t)s1*64+lane]
         + h[(size_t)s2*64+lane] + h[(size_t)s3*64+lane];
  }
  for (; e<end; ++e){
    int s=csr[e];
    acc += h[(size_t)s*64+lane];
  }
  out[(size_t)nd*64+lane] = dn*acc + bias[lane];
}

// ---------- small VALU GEMMs ----------
// o1 (h3) is pre-scaled by dinv for the downstream aggregation; o2 (r3) is not.
__global__ void k_gemm64_16x2(const u16* __restrict__ x, const float* __restrict__ W1_,
                              const float* __restrict__ W2_, const float* __restrict__ b2_,
                              const float* __restrict__ dinv,
                              int n, float* __restrict__ o1, float* __restrict__ o2){
  __shared__ float w1[64*16], w2[64*16];
  int t = threadIdx.x;
  for (int i=t; i<1024; i+=256){ w1[i]=W1_[i]; w2[i]=W2_[i]; }
  __syncthreads();
  int nd = blockIdx.x*8 + (t>>5);
  if (nd>=n) return;
  int j = t & 31;
  const u16* xr = x + (size_t)nd*64;
  if (j<16){
    float s=0.f;
    #pragma unroll 8
    for (int k=0;k<64;k++) s += b2f(xr[k])*w1[k*16+j];
    o1[(size_t)nd*16+j]=s*dinv[nd];
  } else {
    int jj=j-16;
    float s = b2_[jj];
    #pragma unroll 8
    for (int k=0;k<64;k++) s += b2f(xr[k])*w2[k*16+jj];
    o2[(size_t)nd*16+jj]=s;
  }
}

// h4 output pre-scaled by dinv for the downstream aggregation
__global__ void k_gemm16_64(const float* __restrict__ x, const float* __restrict__ W,
                            const float* __restrict__ dinv,
                            int n, float* __restrict__ o){
  __shared__ float w[16*64];
  int t = threadIdx.x;
  for (int i=t;i<1024;i+=256) w[i]=W[i];
  __syncthreads();
  int nd = blockIdx.x*4 + (t>>6);
  if (nd>=n) return;
  int j = t&63;
  const float* xr = x + (size_t)nd*16;
  float s=0.f;
  #pragma unroll
  for (int k=0;k<16;k++) s += xr[k]*w[k*64+j];
  o[(size_t)nd*64+j]=s*dinv[nd];
}

// out(N,64) = x(N,64)@pW + pb, f32 out (safe in-place per-wave)
__global__ void k_final(const float* __restrict__ x, const float* __restrict__ W,
                        const float* __restrict__ b, int n, float* __restrict__ out){
  __shared__ float w[64*64];
  int t=threadIdx.x;
  for (int i=t;i<4096;i+=256) w[i]=W[i];
  __syncthreads();
  int nd = blockIdx.x*4 + (t>>6);
  if (nd>=n) return;
  int j=t&63;
  const float* xr = x + (size_t)nd*64;
  float s=b[j];
  #pragma unroll 8
  for (int k=0;k<64;k++) s += xr[k]*w[k*64+j];
  out[(size_t)nd*64+j]=s;
}

// =======================================================================
extern "C" void kernel_launch(void* const* d_in, const int* in_sizes, int n_in,
                              void* d_out, int out_size, void* d_ws, size_t ws_size,
                              hipStream_t stream) {
  const float* x   = (const float*)d_in[0];
  const int*   ei  = (const int*)d_in[1];
  const float* W1  = (const float*)d_in[2];
  const float* b1  = (const float*)d_in[3];
  const float* g1  = (const float*)d_in[4];
  const float* be1 = (const float*)d_in[5];
  const float* Wg  = (const float*)d_in[6];
  const float* a_s = (const float*)d_in[7];
  const float* a_d = (const float*)d_in[8];
  const float* bg  = (const float*)d_in[9];
  const float* g2  = (const float*)d_in[10];
  const float* be2 = (const float*)d_in[11];
  const float* W3  = (const float*)d_in[12];
  const float* b3  = (const float*)d_in[13];
  const float* g3  = (const float*)d_in[14];
  const float* be3 = (const float*)d_in[15];
  const float* W4  = (const float*)d_in[16];
  const float* b4  = (const float*)d_in[17];
  const float* r1W = (const float*)d_in[18];
  const float* r1b = (const float*)d_in[19];
  const float* r2W = (const float*)d_in[20];
  const float* r2b = (const float*)d_in[21];
  const float* r3W = (const float*)d_in[22];
  const float* r3b = (const float*)d_in[23];
  const float* pW  = (const float*)d_in[24];
  const float* pb  = (const float*)d_in[25];

  const int N = in_sizes[0] / 256;
  const int E = in_sizes[1] / 2;

  // ---- common misc carve-out ----
  char* w = (char*)d_ws;
  auto alloc = [&](size_t b)->void*{ void* p=(void*)w; w += (b+255)&~(size_t)255; return p; };
  u32*   flag   = (u32*)  alloc(4);
  float* part   = (float*)alloc(256*512*4);       // stats partials (256 blocks x 2C, C<=256)
  float* bnp1   = (float*)alloc(512*4);
  float* bnp2   = (float*)alloc(128*4);
  float* bnp3   = (float*)alloc(32*4);
  int*   bsum   = (int*)  alloc(256*4);
  int*   cur    = (int*)  alloc((size_t)N*4);
  int*   offs   = (int*)  alloc((size_t)(N+1)*4);
  float* dinv   = (float*)alloc((size_t)N*4);
  int*   csr    = (int*)  alloc((size_t)E*4);
  float* als    = (float*)alloc((size_t)N*16);
  float* ald    = (float*)alloc((size_t)N*16);
  float* asi    = (float*)alloc(256*4);
  float* adi    = (float*)alloc(256*4);
  u16*   W1t    = (u16*)  alloc(65536*2);
  u16*   r1Wt   = (u16*)  alloc(65536*2);
  u16*   Wgt    = (u16*)  alloc(65536*2);
  u16*   r2Wt   = (u16*)  alloc(16384*2);

  auto cdiv = [](int a, int b){ return (a+b-1)/b; };
  const int nb1024 = cdiv(N, 1024);
  const int statsGrid = 256;
  const int gemmGrid = cdiv(N,64);
  const int nodeGrid = cdiv(N,4);

  hipMemsetAsync(flag,   0, 4, stream);
  hipMemsetAsync(cur,    0, (size_t)N*4, stream);

  k_detect<<<64,256,0,stream>>>((const u32*)ei, E, flag);

  k_transpose<<<cdiv(65536,256),256,0,stream>>>(W1,  W1t,  256,256);
  k_transpose<<<cdiv(65536,256),256,0,stream>>>(r1W, r1Wt, 256,256);
  k_transpose<<<cdiv(65536,256),256,0,stream>>>(Wg,  Wgt,  256,256);
  k_transpose<<<cdiv(16384,256),256,0,stream>>>(r2W, r2Wt, 256,64);
  k_asdt<<<1,256,0,stream>>>(a_s, a_d, asi, adi);

  // ---- CSR build (edge_index fully consumed here) ----
  k_hist  <<<cdiv(E,256),256,0,stream>>>(ei, E, N, flag, cur);
  k_scan_a<<<nb1024,256,0,stream>>>(cur, N, bsum);
  k_scan_b<<<1,64,0,stream>>>(bsum, nb1024);
  k_scan_c<<<nb1024,256,0,stream>>>(cur, bsum, N, offs);
  k_dinv2 <<<cdiv(N,256),256,0,stream>>>(offs, N, dinv);
  hipMemsetAsync(cur, 0, (size_t)N*4, stream);
  k_scatter<<<cdiv(E,256),256,0,stream>>>(ei, E, N, flag, offs, cur, csr);

  size_t miscUsed = (size_t)(w - (char*)d_ws);
  size_t bigNeed  = miscUsed + 2*((size_t)N*512) + 1024;  // two N*256 bf16 regions

  if (ws_size >= bigNeed){
    // ================= BIG PATH (fused full-width) =================
    u16* RA = (u16*)alloc((size_t)N*512);   // H1' -> H2i ; then h3/r3/agg3/x4 (f32)
    u16* RB = (u16*)alloc((size_t)N*512);   // AGG1 -> X2 (fused in R1 gemm) ; then h4 (f32)
    u16* tAe = (u16*)d_in[1];               // edge buffer: O2 -> x3 (N*64 bf16)
    u16* r2d = (u16*)d_out;                 // r2 (N*64 bf16), later agg4 f32

    float* h3   = (float*)RA;
    float* r3   = (float*)(RA + (size_t)N*32);
    float* agg3 = (float*)(RA + (size_t)N*64);
    float* x4   = (float*)(RA + (size_t)N*96);
    float* h4   = (float*)RB;
    float* agg4 = (float*)d_out;

    // Layer 1: GCN(256->256); H1 rows pre-scaled by dinv (RS)
    k_gemm256<float,false,false,false,true><<<gemmGrid,512,0,stream>>>(
        x, x+64, x+128, x+192, 256, W1t, nullptr,
        nullptr, nullptr, nullptr, nullptr, nullptr, nullptr, dinv, RA, N);          // H1'
    k_gather256<<<nodeGrid,256,0,stream>>>(RA, offs, csr, dinv, b1, N, RB);          // AGG1
    k_stats_part<u16,256><<<statsGrid,256,0,stream>>>(RB, N, part);
    k_bnfin3<256><<<8,256,0,stream>>>(part, statsGrid, g1, be1, (float)N, bnp1);
    // R1 gemm with fused BN+leaky+residual: X2 = leaky(BN(AGG1)) + R1, in-place in RB
    k_gemm256<float,false,true,false,false><<<gemmGrid,512,0,stream>>>(
        x, x+64, x+128, x+192, 256, r1Wt, r1b,
        RB, bnp1, nullptr, nullptr, nullptr, nullptr, nullptr, RB, N);               // X2

    // Layer 2: GAT fused (H2 gemm also emits attention logit dots)
    k_gemm256<u16,true,false,true,false><<<gemmGrid,512,0,stream>>>(
        RB, RB+64, RB+128, RB+192, 256, Wgt, nullptr,
        nullptr, nullptr, asi, adi, als, ald, nullptr, RA, N);                       // H2i + als/ald
    k_gemm64<u16><<<gemmGrid,256,0,stream>>>(RB, RB+64, RB+128, RB+192, 256,
                                             r2Wt, r2b, r2d, N);                     // r2
    k_gat_all<<<nodeGrid,256,0,stream>>>(RA, offs, csr, als, ald, bg, N, tAe);       // O2
    k_stats_part<u16,64><<<statsGrid,256,0,stream>>>(tAe, N, part);
    k_bnfin3<64><<<2,256,0,stream>>>(part, statsGrid, g2, be2, (float)N, bnp2);
    k_ew_b16b16<<<cdiv(N*64,256),256,0,stream>>>(tAe, r2d, bnp2, 64, N*64, tAe);     // x3

    // Layer 3 (h3 pre-scaled by dinv in producer)
    k_gemm64_16x2<<<cdiv(N,8),256,0,stream>>>(tAe, W3, r3W, r3b, dinv, N, h3, r3);
    k_gcn_agg16<<<cdiv(N,16),256,0,stream>>>(h3, offs, csr, dinv, b3, agg3, N);
    k_stats_part<float,16><<<statsGrid,256,0,stream>>>(agg3, N, part);
    k_bnfin3<16><<<1,256,0,stream>>>(part, statsGrid, g3, be3, (float)N, bnp3);
    k_ew_f32f32<<<cdiv(N*16,256),256,0,stream>>>(agg3, r3, bnp3, 16, N*16, x4);

    // Layer 4 (h4 pre-scaled by dinv in producer)
    k_gemm16_64<<<nodeGrid,256,0,stream>>>(x4, W4, dinv, N, h4);
    k_gcn_agg64f<<<nodeGrid,256,0,stream>>>(h4, offs, csr, dinv, b4, agg4, N);
    k_final<<<nodeGrid,256,0,stream>>>(agg4, pW, pb, N, (float*)d_out);
  } else {
    // ================= FALLBACK (round-8 structure) =================
    u16* X0 = (u16*)alloc((size_t)N*64*2);
    u16* X1 = (u16*)alloc((size_t)N*64*2);
    u16* tA = (u16*)alloc((size_t)N*64*2);
    u16* tB = (u16*)alloc((size_t)N*64*2);
    u16* X2 = (u16*)d_in[1];
    u16* X3 = (u16*)d_out;
    const u16* XP[4] = {X0, X1, X2, X3};

    float* h3   = (float*)X1;
    float* r3   = (float*)(X1 + (size_t)N*32);
    float* agg3 = (float*)tA;
    float* x4   = (float*)(tA + (size_t)N*32);
    float* h4   = (float*)X0;
    float* agg4 = (float*)tA;

    for (int tau=0; tau<4; ++tau){
      u16* Xt = (u16*)XP[tau];
      k_gemm64<float><<<gemmGrid,256,0,stream>>>(x, x+64, x+128, x+192, 256,
                                                 W1t + (size_t)tau*64*256, nullptr, tA, N);
      k_gather64<<<nodeGrid,256,0,stream>>>(tA, offs, csr, dinv, b1 + tau*64, N, tB);
      k_stats_part<u16,64><<<statsGrid,256,0,stream>>>(tB, N, part);
      k_bnfin3<64><<<2,256,0,stream>>>(part, statsGrid, g1 + tau*64, be1 + tau*64, (float)N, bnp1 + tau*128);
      k_gemm64<float><<<gemmGrid,256,0,stream>>>(x, x+64, x+128, x+192, 256,
                                                 r1Wt + (size_t)tau*64*256, r1b + tau*64, tA, N);
      k_ew_b16b16<<<cdiv(N*64,256),256,0,stream>>>(tB, tA, bnp1 + tau*128, 64, N*64, Xt);
    }

    for (int head=0; head<4; ++head){
      k_gemm64<u16><<<gemmGrid,256,0,stream>>>(XP[0], XP[1], XP[2], XP[3], 64,
                                               Wgt + (size_t)head*64*256, nullptr, tA, N);
      k_dot64<<<nodeGrid,256,0,stream>>>(tA, a_s + head*64, a_d + head*64, head, N, als, ald);
      k_gat_head<<<nodeGrid,256,0,stream>>>(tA, offs, csr, als, ald, bg, head, N, tB);
    }
    k_gemm64<u16><<<gemmGrid,256,0,stream>>>(XP[0], XP[1], XP[2], XP[3], 64,
                                             r2Wt, r2b, tA, N);
    k_stats_part<u16,64><<<statsGrid,256,0,stream>>>(tB, N, part);
    k_bnfin3<64><<<2,256,0,stream>>>(part, statsGrid, g2, be2, (float)N, bnp2);
    k_ew_b16b16<<<cdiv(N*64,256),256,0,stream>>>(tB, tA, bnp2, 64, N*64, X0);

    k_gemm64_16x2<<<cdiv(N,8),256,0,stream>>>(X0, W3, r3W, r3b, dinv, N, h3, r3);
    k_gcn_agg16<<<cdiv(N,16),256,0,stream>>>(h3, offs, csr, dinv, b3, agg3, N);
    k_stats_part<float,16><<<statsGrid,256,0,stream>>>(agg3, N, part);
    k_bnfin3<16><<<1,256,0,stream>>>(part, statsGrid, g3, be3, (float)N, bnp3);
    k_ew_f32f32<<<cdiv(N*16,256),256,0,stream>>>(agg3, r3, bnp3, 16, N*16, x4);

    k_gemm16_64<<<nodeGrid,256,0,stream>>>(x4, W4, dinv, N, h4);
    k_gcn_agg64f<<<nodeGrid,256,0,stream>>>(h4, offs, csr, dinv, b4, agg4, N);
    k_final<<<nodeGrid,256,0,stream>>>(agg4, pW, pb, N, (float*)d_out);
  }
}